// Round 1
// baseline (4941.429 us; speedup 1.0000x reference)
//
#include <hip/hip_runtime.h>
#include <math.h>

constexpr int R_ = 128, C_ = 64, S_ = 3, NL_ = 2, NH_ = 4, B_ = 2, V_ = 4;
constexpr int N_ = R_ * R_;          // 16384
constexpr int T_ = 2 * S_;           // 6

// ---------- helpers ----------
__device__ inline float wsum(float v) {
#pragma unroll
    for (int m = 1; m < 64; m <<= 1) v += __shfl_xor(v, m, 64);
    return v;
}

__device__ inline void atomicAddF(float* p, float v) {
    __hip_atomic_fetch_add(p, v, __ATOMIC_RELAXED, __HIP_MEMORY_SCOPE_AGENT);
}

// ---------- zero workspace region ----------
__global__ __launch_bounds__(256) void zero_kernel(float4* __restrict__ p, int n4) {
    int i = blockIdx.x * 256 + threadIdx.x;
    if (i < n4) p[i] = make_float4(0.f, 0.f, 0.f, 0.f);
}

// ---------- init plane feats with query tensors (both batches) ----------
__global__ __launch_bounds__(256) void init_feats(const float* __restrict__ q,
                                                  float* __restrict__ f0) {
    int idx = blockIdx.x * 256 + threadIdx.x;     // over 3*N*C
    if (idx >= 3 * N_ * C_) return;
    int p = idx / (N_ * C_);
    int rem = idx - p * (N_ * C_);
    float val = q[idx];
    f0[(size_t)(p * B_ + 0) * N_ * C_ + rem] = val;
    f0[(size_t)(p * B_ + 1) * N_ * C_ + rem] = val;
}

// ---------- splat one view v: scatter-add into acc/wacc ----------
__global__ __launch_bounds__(256) void splat_kernel(const float* __restrict__ img_feats,
                                                    const float* __restrict__ pts,
                                                    float* __restrict__ acc,
                                                    float* __restrict__ wacc, int v) {
    int gwave = (blockIdx.x * 256 + threadIdx.x) >> 6;  // [0, B*N)
    int lane = threadIdx.x & 63;
    int b = gwave >> 14;
    int n = gwave & (N_ - 1);
    int bv = b * V_ + v;

    const float* p = pts + ((size_t)bv * N_ + n) * 3;
    float px = p[0], py = p[1], pz = p[2];
    float f = img_feats[((size_t)bv * C_ + lane) * N_ + n];

    const float HI = (float)(127.0 - 1e-5);
    float gx = fminf(fmaxf((px + 1.0f) * 127.0f / 2.0f, 0.0f), HI);
    float gy = fminf(fmaxf((py + 1.0f) * 127.0f / 2.0f, 0.0f), HI);
    float gz = fminf(fmaxf((pz + 1.0f) * 127.0f / 2.0f, 0.0f), HI);
    int x0 = (int)gx, y0 = (int)gy, z0 = (int)gz;
    float wx = gx - (float)x0, wy = gy - (float)y0, wz = gz - (float)z0;
    int x1 = x0 + 1 < 128 ? x0 + 1 : 127;
    int y1 = y0 + 1 < 128 ? y0 + 1 : 127;
    int z1 = z0 + 1 < 128 ? z0 + 1 : 127;
    float ax = 1.0f - wx, ay = 1.0f - wy, az = 1.0f - wz;
    float w000 = ax * ay * az;
    float w001 = ax * ay * wz;
    float w010 = ax * wy * az;
    float w100 = wx * ay * az;
    float w110 = wx * wy * az;
    float w111 = wx * wy * wz;

    float* a0 = acc + (size_t)(b * 3 + 0) * N_ * C_;
    float* a1 = acc + (size_t)(b * 3 + 1) * N_ * C_;
    float* a2 = acc + (size_t)(b * 3 + 2) * N_ * C_;
    float* wa0 = wacc + (size_t)(b * 3 + 0) * N_;
    float* wa1 = wacc + (size_t)(b * 3 + 1) * N_;
    float* wa2 = wacc + (size_t)(b * 3 + 2) * N_;

#define SPLAT_ADD(A, WA, IA, IB, W)                                   \
    do {                                                              \
        int cell = (IA) * R_ + (IB);                                  \
        atomicAddF((A) + (size_t)cell * C_ + lane, (W)*f);            \
        if (lane == 0) atomicAddF((WA) + cell, (W));                  \
    } while (0)

    SPLAT_ADD(a0, wa0, x0, y0, w000);
    SPLAT_ADD(a0, wa0, x0, y1, w010);
    SPLAT_ADD(a0, wa0, x1, y0, w100);
    SPLAT_ADD(a0, wa0, x1, y1, w110);

    SPLAT_ADD(a1, wa1, x0, z0, w000);
    SPLAT_ADD(a1, wa1, x0, z1, w001);
    SPLAT_ADD(a1, wa1, x1, z0, w100);
    SPLAT_ADD(a1, wa1, x1, z1, w111);

    SPLAT_ADD(a2, wa2, y0, z0, w000);
    SPLAT_ADD(a2, wa2, y0, z1, w001);
    SPLAT_ADD(a2, wa2, y1, z0, w010);
    SPLAT_ADD(a2, wa2, y1, z1, w111);
#undef SPLAT_ADD
}

// ---------- normalize view contribution, add 1/V into feats0 ----------
__global__ __launch_bounds__(256) void norm_add(const float* __restrict__ acc,
                                                const float* __restrict__ wacc,
                                                float* __restrict__ f0) {
    int idx = blockIdx.x * 256 + threadIdx.x;     // over B*3*N*C
    if (idx >= B_ * 3 * N_ * C_) return;
    int c = idx & 63;
    int cell = (idx >> 6) & (N_ - 1);
    int bp = idx >> 20;                            // b*3+p
    int b = bp / 3, p = bp - b * 3;
    float w = wacc[(size_t)bp * N_ + cell];
    float val = acc[idx] / fmaxf(w, 1e-8f);
    f0[((size_t)(p * B_ + b) * N_ + cell) * C_ + c] += 0.25f * val;
}

// ---------- fused per-plane transformer layer ----------
__global__ __launch_bounds__(256) void plane_kernel(
    const float* __restrict__ fin, float* __restrict__ fout, int pi,
    const float* __restrict__ ln1g, const float* __restrict__ ln1b,
    const float* __restrict__ ln2g, const float* __restrict__ ln2b,
    const float* __restrict__ inw, const float* __restrict__ inb,
    const float* __restrict__ outw, const float* __restrict__ outb,
    const float* __restrict__ f_w1, const float* __restrict__ f_b1,
    const float* __restrict__ f_w2, const float* __restrict__ f_b2) {
    __shared__ float s_x[4][C_];
    __shared__ float s_cn[4][T_][C_];
    __shared__ float s_h[4][4 * C_];

    int wid = threadIdx.x >> 6, lane = threadIdx.x & 63;
    int row = blockIdx.x * 4 + wid;                // [0, B*N)
    int b = row >> 14;
    int n = row & (N_ - 1);
    int i = n >> 7, j = n & 127;

    float g1 = ln1g[lane], bb1 = ln1b[lane];
    float x = fin[((size_t)(pi * B_ + b) * N_ + n) * C_ + lane];
    {
        float m = wsum(x) * (1.f / 64.f);
        float d = x - m;
        float var = wsum(d * d) * (1.f / 64.f);
        s_x[wid][lane] = d / sqrtf(var + 1e-5f) * g1 + bb1;
    }

    float lin_i = -1.0f + (2.0f * (float)i) / 127.0f;
    float lin_j = -1.0f + (2.0f * (float)j) / 127.0f;

    for (int t = 0; t < T_; ++t) {
        int k = (t < 3) ? t : t - 3;
        float sk = (float)(k - 1);
        int io;
        float caf, cbf;
        if (pi == 0) {
            if (t < 3) { io = 1; caf = lin_j; cbf = sk; }
            else       { io = 2; caf = lin_i; cbf = sk; }
        } else if (pi == 1) {
            if (t < 3) { io = 0; caf = lin_j; cbf = sk; }
            else       { io = 2; caf = sk;    cbf = lin_i; }
        } else {
            if (t < 3) { io = 0; caf = sk;    cbf = lin_j; }
            else       { io = 1; caf = sk;    cbf = lin_i; }
        }
        // reference's double transform (gc in [0,127] fed through [-1,1]->pixel again)
        float ua = fminf(fmaxf((caf * 0.5f + 0.5f) * 127.0f, 0.0f), 127.0f);
        float ub = fminf(fmaxf((cbf * 0.5f + 0.5f) * 127.0f, 0.0f), 127.0f);
        float gxp = fminf(fmaxf(((ua + 1.0f) * 0.5f) * 127.0f, 0.0f), 127.0f);
        float gyp = fminf(fmaxf(((ub + 1.0f) * 0.5f) * 127.0f, 0.0f), 127.0f);
        int xx0 = (int)gxp, yy0 = (int)gyp;
        int xx1 = xx0 + 1 < 128 ? xx0 + 1 : 127;
        int yy1 = yy0 + 1 < 128 ? yy0 + 1 : 127;
        float wx = gxp - (float)xx0, wyv = gyp - (float)yy0;
        const float* Fp = fin + (size_t)(io * B_ + b) * N_ * C_ + lane;
        float v00 = Fp[(size_t)(yy0 * R_ + xx0) * C_];
        float v01 = Fp[(size_t)(yy0 * R_ + xx1) * C_];
        float v10 = Fp[(size_t)(yy1 * R_ + xx0) * C_];
        float v11 = Fp[(size_t)(yy1 * R_ + xx1) * C_];
        float cv = (1.0f - wyv) * ((1.0f - wx) * v00 + wx * v01) +
                   wyv * ((1.0f - wx) * v10 + wx * v11);
        float m = wsum(cv) * (1.f / 64.f);
        float d = cv - m;
        float var = wsum(d * d) * (1.f / 64.f);
        s_cn[wid][t][lane] = d / sqrtf(var + 1e-5f) * g1 + bb1;
    }
    __syncthreads();

    // q/k/v projections (per-lane output channel)
    float q = inb[lane];
    float bk = inb[64 + lane], bvv = inb[128 + lane];
    float kk[T_], vv[T_];
#pragma unroll
    for (int t = 0; t < T_; ++t) { kk[t] = bk; vv[t] = bvv; }
    const float* Wq = inw + (size_t)lane * 64;
    const float* Wk = inw + (size_t)(64 + lane) * 64;
    const float* Wv = inw + (size_t)(128 + lane) * 64;
    for (int u = 0; u < 64; ++u) q = fmaf(s_x[wid][u], Wq[u], q);
    for (int u = 0; u < 64; ++u) {
        float wk_ = Wk[u], wv_ = Wv[u];
#pragma unroll
        for (int t = 0; t < T_; ++t) {
            float cu = s_cn[wid][t][u];
            kk[t] = fmaf(cu, wk_, kk[t]);
            vv[t] = fmaf(cu, wv_, vv[t]);
        }
    }

    // attention: per-head (16-lane group) reduce, softmax over T
    float att[T_];
#pragma unroll
    for (int t = 0; t < T_; ++t) {
        float d = q * kk[t];
#pragma unroll
        for (int m = 1; m < 16; m <<= 1) d += __shfl_xor(d, m, 64);
        att[t] = d * 0.25f;   // 1/sqrt(16)
    }
    float mx = att[0];
#pragma unroll
    for (int t = 1; t < T_; ++t) mx = fmaxf(mx, att[t]);
    float den = 0.f;
#pragma unroll
    for (int t = 0; t < T_; ++t) { att[t] = expf(att[t] - mx); den += att[t]; }
    float inv = 1.0f / den;
    float o = 0.f;
#pragma unroll
    for (int t = 0; t < T_; ++t) o = fmaf(att[t] * inv, vv[t], o);

    __syncthreads();
    s_x[wid][lane] = o;
    __syncthreads();

    float ao = outb[lane];
    const float* Wo = outw + (size_t)lane * 64;
    for (int u = 0; u < 64; ++u) ao = fmaf(s_x[wid][u], Wo[u], ao);
    float x2 = x + ao;

    // LN2
    float g2 = ln2g[lane], bb2 = ln2b[lane];
    float m2 = wsum(x2) * (1.f / 64.f);
    float d2 = x2 - m2;
    float var2 = wsum(d2 * d2) * (1.f / 64.f);
    float xn2 = d2 / sqrtf(var2 + 1e-5f) * g2 + bb2;

    __syncthreads();
    s_x[wid][lane] = xn2;
    __syncthreads();

    // FFN up + exact GELU
#pragma unroll
    for (int r = 0; r < 4; ++r) {
        int jj = r * 64 + lane;
        float h = f_b1[jj];
        const float* W1 = f_w1 + (size_t)jj * 64;
        for (int u = 0; u < 64; ++u) h = fmaf(s_x[wid][u], W1[u], h);
        h = 0.5f * h * (1.0f + erff(h * 0.70710678118654752f));
        s_h[wid][jj] = h;
    }
    __syncthreads();

    float hv = f_b2[lane];
    const float* W2 = f_w2 + (size_t)lane * 256;
    for (int u = 0; u < 256; ++u) hv = fmaf(s_h[wid][u], W2[u], hv);

    fout[((size_t)(pi * B_ + b) * N_ + n) * C_ + lane] = x2 + hv;
}

// ---------- output transpose: feats (p,b,n,c) -> out (b,p,c,n) ----------
__global__ __launch_bounds__(256) void output_kernel(const float* __restrict__ f,
                                                     float* __restrict__ out) {
    __shared__ float tile[64][65];
    int blk = blockIdx.x;                 // B*3*(N/64) = 1536
    int ntile = blk & 255;                // N/64 = 256
    int bp = blk >> 8;                    // b*3+p
    int b = bp / 3, p = bp - b * 3;
    int n0 = ntile * 64;
    int tr = threadIdx.x >> 6, tc = threadIdx.x & 63;

    const float* src = f + ((size_t)(p * B_ + b) * N_ + n0) * C_;
#pragma unroll
    for (int it = 0; it < 16; ++it) {
        int r = it * 4 + tr;
        tile[r][tc] = src[(size_t)r * C_ + tc];
    }
    __syncthreads();
    float* dst = out + (size_t)(b * 3 + p) * C_ * N_ + n0;
#pragma unroll
    for (int it = 0; it < 16; ++it) {
        int cidx = it * 4 + tr;
        dst[(size_t)cidx * N_ + tc] = tile[tc][cidx];
    }
}

extern "C" void kernel_launch(void* const* d_in, const int* in_sizes, int n_in,
                              void* d_out, int out_size, void* d_ws, size_t ws_size,
                              hipStream_t stream) {
    const float* img_feats = (const float*)d_in[0];
    const float* pts       = (const float*)d_in[1];
    const float* query     = (const float*)d_in[2];
    const float* ln1_g     = (const float*)d_in[3];
    const float* ln1_b     = (const float*)d_in[4];
    const float* ln2_g     = (const float*)d_in[5];
    const float* ln2_b     = (const float*)d_in[6];
    const float* in_w      = (const float*)d_in[7];
    const float* in_b      = (const float*)d_in[8];
    const float* out_w     = (const float*)d_in[9];
    const float* out_b     = (const float*)d_in[10];
    const float* ffn_w1    = (const float*)d_in[11];
    const float* ffn_b1    = (const float*)d_in[12];
    const float* ffn_w2    = (const float*)d_in[13];
    const float* ffn_b2    = (const float*)d_in[14];

    float* ws = (float*)d_ws;
    const size_t ACC_SZ = (size_t)B_ * 3 * N_ * C_;   // 6,291,456
    const size_t WACC_SZ = (size_t)B_ * 3 * N_;       //    98,304
    const size_t FEAT_SZ = (size_t)3 * B_ * N_ * C_;  // 6,291,456
    float* acc  = ws;
    float* wacc = acc + ACC_SZ;
    float* fA   = wacc + WACC_SZ;
    float* fB   = fA + FEAT_SZ;

    // init plane feats with query tensors
    init_feats<<<(3 * N_ * C_ + 255) / 256, 256, 0, stream>>>(query, fA);

    // splat per view, normalize, accumulate mean
    int zero_n4 = (int)((ACC_SZ + WACC_SZ) / 4);
    for (int v = 0; v < V_; ++v) {
        zero_kernel<<<(zero_n4 + 255) / 256, 256, 0, stream>>>((float4*)acc, zero_n4);
        splat_kernel<<<(B_ * N_) / 4, 256, 0, stream>>>(img_feats, pts, acc, wacc, v);
        norm_add<<<(int)((ACC_SZ + 255) / 256), 256, 0, stream>>>(acc, wacc, fA);
    }

    // transformer: 2 layers x 3 planes
    for (int l = 0; l < NL_; ++l) {
        const float* fin = (l == 0) ? fA : fB;
        float* fout      = (l == 0) ? fB : fA;
        for (int pi = 0; pi < 3; ++pi) {
            plane_kernel<<<(B_ * N_) / 4, 256, 0, stream>>>(
                fin, fout, pi,
                ln1_g + l * C_, ln1_b + l * C_,
                ln2_g + l * C_, ln2_b + l * C_,
                in_w + (size_t)l * 3 * C_ * C_, in_b + l * 3 * C_,
                out_w + (size_t)l * C_ * C_, out_b + l * C_,
                ffn_w1 + (size_t)l * 4 * C_ * C_, ffn_b1 + l * 4 * C_,
                ffn_w2 + (size_t)l * C_ * 4 * C_, ffn_b2 + l * C_);
        }
    }

    // final feats live in fA (layer1 wrote fA)
    output_kernel<<<B_ * 3 * (N_ / 64), 256, 0, stream>>>(fA, (float*)d_out);
}

// Round 2
// 1991.050 us; speedup vs baseline: 2.4818x; 2.4818x over previous
//
#include <hip/hip_runtime.h>
#include <math.h>

constexpr int R_ = 128, C_ = 64, NL_ = 2, B_ = 2, V_ = 4;
constexpr int N_ = R_ * R_;          // 16384
constexpr int T_ = 6;
constexpr int RB = 32;               // rows per block
constexpr int RPW = 8;               // rows per wave (4 waves)

// ---------- helpers ----------
__device__ inline float wsum(float v) {
#pragma unroll
    for (int m = 1; m < 64; m <<= 1) v += __shfl_xor(v, m, 64);
    return v;
}

__device__ inline float lnorm(float v, float g, float b) {
    float m = wsum(v) * (1.f / 64.f);
    float d = v - m;
    float var = wsum(d * d) * (1.f / 64.f);
    return d / sqrtf(var + 1e-5f) * g + b;
}

__device__ inline void atomicAddF(float* p, float v) {
    __hip_atomic_fetch_add(p, v, __ATOMIC_RELAXED, __HIP_MEMORY_SCOPE_AGENT);
}

// stage a 64x64 row-major matrix into LDS buf[c*68 + u]
__device__ inline void stageW(const float* __restrict__ W, float* buf, int tid) {
#pragma unroll
    for (int it = 0; it < 4; ++it) {
        int idx4 = it * 256 + tid;          // [0,1024) float4s
        int r = idx4 >> 4, u4 = idx4 & 15;
        float4 v = ((const float4*)W)[idx4];
        *(float4*)&buf[r * 68 + u4 * 4] = v;
    }
}

// stage 64 rows x 64 cols from a matrix with row stride `rs`
__device__ inline void stageWs(const float* __restrict__ W, int rs, float* buf, int tid) {
#pragma unroll
    for (int it = 0; it < 4; ++it) {
        int idx4 = it * 256 + tid;
        int r = idx4 >> 4, u4 = idx4 & 15;
        float4 v = *(const float4*)(W + (size_t)r * rs + u4 * 4);
        *(float4*)&buf[r * 68 + u4 * 4] = v;
    }
}

// ---------- zero workspace region ----------
__global__ __launch_bounds__(256) void zero_kernel(float4* __restrict__ p, int n4) {
    int i = blockIdx.x * 256 + threadIdx.x;
    if (i < n4) p[i] = make_float4(0.f, 0.f, 0.f, 0.f);
}

// ---------- init plane feats with query tensors ----------
__global__ __launch_bounds__(256) void init_feats(const float* __restrict__ q,
                                                  float* __restrict__ f0) {
    int idx = blockIdx.x * 256 + threadIdx.x;
    if (idx >= 3 * N_ * C_) return;
    int p = idx / (N_ * C_);
    int rem = idx - p * (N_ * C_);
    float val = q[idx];
    f0[(size_t)(p * B_ + 0) * N_ * C_ + rem] = val;
    f0[(size_t)(p * B_ + 1) * N_ * C_ + rem] = val;
}

// ---------- splat one view ----------
__global__ __launch_bounds__(256) void splat_kernel(const float* __restrict__ img_feats,
                                                    const float* __restrict__ pts,
                                                    float* __restrict__ acc,
                                                    float* __restrict__ wacc, int v) {
    int gwave = (blockIdx.x * 256 + threadIdx.x) >> 6;
    int lane = threadIdx.x & 63;
    int b = gwave >> 14;
    int n = gwave & (N_ - 1);
    int bv = b * V_ + v;

    const float* p = pts + ((size_t)bv * N_ + n) * 3;
    float px = p[0], py = p[1], pz = p[2];
    float f = img_feats[((size_t)bv * C_ + lane) * N_ + n];

    const float HI = (float)(127.0 - 1e-5);
    float gx = fminf(fmaxf((px + 1.0f) * 127.0f / 2.0f, 0.0f), HI);
    float gy = fminf(fmaxf((py + 1.0f) * 127.0f / 2.0f, 0.0f), HI);
    float gz = fminf(fmaxf((pz + 1.0f) * 127.0f / 2.0f, 0.0f), HI);
    int x0 = (int)gx, y0 = (int)gy, z0 = (int)gz;
    float wx = gx - (float)x0, wy = gy - (float)y0, wz = gz - (float)z0;
    int x1 = x0 + 1 < 128 ? x0 + 1 : 127;
    int y1 = y0 + 1 < 128 ? y0 + 1 : 127;
    int z1 = z0 + 1 < 128 ? z0 + 1 : 127;
    float ax = 1.0f - wx, ay = 1.0f - wy, az = 1.0f - wz;
    float w000 = ax * ay * az;
    float w001 = ax * ay * wz;
    float w010 = ax * wy * az;
    float w100 = wx * ay * az;
    float w110 = wx * wy * az;
    float w111 = wx * wy * wz;

    float* a0 = acc + (size_t)(b * 3 + 0) * N_ * C_;
    float* a1 = acc + (size_t)(b * 3 + 1) * N_ * C_;
    float* a2 = acc + (size_t)(b * 3 + 2) * N_ * C_;
    float* wa0 = wacc + (size_t)(b * 3 + 0) * N_;
    float* wa1 = wacc + (size_t)(b * 3 + 1) * N_;
    float* wa2 = wacc + (size_t)(b * 3 + 2) * N_;

#define SPLAT_ADD(A, WA, IA, IB, W)                                   \
    do {                                                              \
        int cell = (IA) * R_ + (IB);                                  \
        atomicAddF((A) + (size_t)cell * C_ + lane, (W)*f);            \
        if (lane == 0) atomicAddF((WA) + cell, (W));                  \
    } while (0)

    SPLAT_ADD(a0, wa0, x0, y0, w000);
    SPLAT_ADD(a0, wa0, x0, y1, w010);
    SPLAT_ADD(a0, wa0, x1, y0, w100);
    SPLAT_ADD(a0, wa0, x1, y1, w110);

    SPLAT_ADD(a1, wa1, x0, z0, w000);
    SPLAT_ADD(a1, wa1, x0, z1, w001);
    SPLAT_ADD(a1, wa1, x1, z0, w100);
    SPLAT_ADD(a1, wa1, x1, z1, w111);

    SPLAT_ADD(a2, wa2, y0, z0, w000);
    SPLAT_ADD(a2, wa2, y0, z1, w001);
    SPLAT_ADD(a2, wa2, y1, z0, w010);
    SPLAT_ADD(a2, wa2, y1, z1, w111);
#undef SPLAT_ADD
}

// ---------- normalize view contribution, add 1/V ----------
__global__ __launch_bounds__(256) void norm_add(const float* __restrict__ acc,
                                                const float* __restrict__ wacc,
                                                float* __restrict__ f0) {
    int idx = blockIdx.x * 256 + threadIdx.x;
    if (idx >= B_ * 3 * N_ * C_) return;
    int c = idx & 63;
    int cell = (idx >> 6) & (N_ - 1);
    int bp = idx >> 20;
    int b = bp / 3, p = bp - b * 3;
    float w = wacc[(size_t)bp * N_ + cell];
    float val = acc[idx] / fmaxf(w, 1e-8f);
    f0[((size_t)(p * B_ + b) * N_ + cell) * C_ + c] += 0.25f * val;
}

// ---------- fused per-plane transformer layer (LDS-staged weights) ----------
__global__ __launch_bounds__(256) void plane_kernel(
    const float* __restrict__ fin, float* __restrict__ fout,
    const float* __restrict__ ln1g, const float* __restrict__ ln1b,
    const float* __restrict__ ln2g, const float* __restrict__ ln2b,
    const float* __restrict__ inw, const float* __restrict__ inb,
    const float* __restrict__ outw, const float* __restrict__ outb,
    const float* __restrict__ f_w1, const float* __restrict__ f_b1,
    const float* __restrict__ f_w2, const float* __restrict__ f_b2) {
    __shared__ float s_w0[64 * 68];
    __shared__ float s_w1[64 * 68];
    __shared__ float s_act[RB * 68];
    __shared__ float s_h[RB * 68];

    const int tid = threadIdx.x;
    const int wid = tid >> 6, lane = tid & 63;
    const int pi = blockIdx.y;
    const int rw = wid * RPW;                   // wave's first local row
    const int rbase = blockIdx.x * RB + rw;     // wave's first global row

    const float g1 = ln1g[lane], b1v = ln1b[lane];

    float x[RPW], lin_i[RPW], lin_j[RPW];
    int bb[RPW], nn[RPW];

    // ---- Phase A: load x, LN1 -> s_act
#pragma unroll
    for (int rr = 0; rr < RPW; ++rr) {
        int row = rbase + rr;
        bb[rr] = row >> 14;
        nn[rr] = row & (N_ - 1);
        int i = nn[rr] >> 7, j = nn[rr] & 127;
        lin_i[rr] = -1.0f + (2.0f * (float)i) / 127.0f;
        lin_j[rr] = -1.0f + (2.0f * (float)j) / 127.0f;
        x[rr] = fin[((size_t)(pi * B_ + bb[rr]) * N_ + nn[rr]) * C_ + lane];
        s_act[(rw + rr) * 68 + lane] = lnorm(x[rr], g1, b1v);
    }
    stageW(inw, s_w0, tid);                     // Wq
    __syncthreads();

    // ---- Phase B: q projection
    float q[RPW];
#pragma unroll
    for (int rr = 0; rr < RPW; ++rr) q[rr] = inb[lane];
    {
        const float* wrow = s_w0 + lane * 68;
#pragma unroll 4
        for (int g = 0; g < 16; ++g) {
            float4 w = *(const float4*)(wrow + g * 4);
#pragma unroll
            for (int rr = 0; rr < RPW; ++rr) {
                float4 xv = *(const float4*)(s_act + (rw + rr) * 68 + g * 4);
                q[rr] = fmaf(xv.x, w.x, fmaf(xv.y, w.y, fmaf(xv.z, w.z, fmaf(xv.w, w.w, q[rr]))));
            }
        }
    }
    __syncthreads();

    // ---- Phase C: per-t ctx gather + LN + k/v projection + att
    float vv[RPW][T_], att[RPW][T_];
    const float bk = inb[64 + lane], bvv = inb[128 + lane];

    for (int t = 0; t < T_; ++t) {
        if (t == 0) {
            stageW(inw + 4096, s_w0, tid);      // Wk
            stageW(inw + 8192, s_w1, tid);      // Wv
        }
        int k = (t < 3) ? t : t - 3;
        float sk = (float)(k - 1);
#pragma unroll
        for (int rr = 0; rr < RPW; ++rr) {
            int io;
            float caf, cbf;
            if (pi == 0) {
                if (t < 3) { io = 1; caf = lin_j[rr]; cbf = sk; }
                else       { io = 2; caf = lin_i[rr]; cbf = sk; }
            } else if (pi == 1) {
                if (t < 3) { io = 0; caf = lin_j[rr]; cbf = sk; }
                else       { io = 2; caf = sk;        cbf = lin_i[rr]; }
            } else {
                if (t < 3) { io = 0; caf = sk;        cbf = lin_j[rr]; }
                else       { io = 1; caf = sk;        cbf = lin_i[rr]; }
            }
            float ua = fminf(fmaxf((caf * 0.5f + 0.5f) * 127.0f, 0.0f), 127.0f);
            float ub = fminf(fmaxf((cbf * 0.5f + 0.5f) * 127.0f, 0.0f), 127.0f);
            float gxp = fminf(fmaxf(((ua + 1.0f) * 0.5f) * 127.0f, 0.0f), 127.0f);
            float gyp = fminf(fmaxf(((ub + 1.0f) * 0.5f) * 127.0f, 0.0f), 127.0f);
            int xx0 = (int)gxp, yy0 = (int)gyp;
            int xx1 = xx0 + 1 < 128 ? xx0 + 1 : 127;
            int yy1 = yy0 + 1 < 128 ? yy0 + 1 : 127;
            float wx = gxp - (float)xx0, wyv = gyp - (float)yy0;
            const float* Fp = fin + (size_t)(io * B_ + bb[rr]) * N_ * C_ + lane;
            float v00 = Fp[(size_t)(yy0 * R_ + xx0) * C_];
            float v01 = Fp[(size_t)(yy0 * R_ + xx1) * C_];
            float v10 = Fp[(size_t)(yy1 * R_ + xx0) * C_];
            float v11 = Fp[(size_t)(yy1 * R_ + xx1) * C_];
            float cv = (1.0f - wyv) * ((1.0f - wx) * v00 + wx * v01) +
                       wyv * ((1.0f - wx) * v10 + wx * v11);
            s_act[(rw + rr) * 68 + lane] = lnorm(cv, g1, b1v);
        }
        __syncthreads();

        float kk[RPW], vt[RPW];
#pragma unroll
        for (int rr = 0; rr < RPW; ++rr) { kk[rr] = bk; vt[rr] = bvv; }
        {
            const float* wr0 = s_w0 + lane * 68;
            const float* wr1 = s_w1 + lane * 68;
#pragma unroll 4
            for (int g = 0; g < 16; ++g) {
                float4 w0 = *(const float4*)(wr0 + g * 4);
                float4 w1 = *(const float4*)(wr1 + g * 4);
#pragma unroll
                for (int rr = 0; rr < RPW; ++rr) {
                    float4 xv = *(const float4*)(s_act + (rw + rr) * 68 + g * 4);
                    kk[rr] = fmaf(xv.x, w0.x, fmaf(xv.y, w0.y, fmaf(xv.z, w0.z, fmaf(xv.w, w0.w, kk[rr]))));
                    vt[rr] = fmaf(xv.x, w1.x, fmaf(xv.y, w1.y, fmaf(xv.z, w1.z, fmaf(xv.w, w1.w, vt[rr]))));
                }
            }
        }
#pragma unroll
        for (int rr = 0; rr < RPW; ++rr) {
            float d = q[rr] * kk[rr];
#pragma unroll
            for (int m = 1; m < 16; m <<= 1) d += __shfl_xor(d, m, 64);
            att[rr][t] = d * 0.25f;
            vv[rr][t] = vt[rr];
        }
        __syncthreads();
    }

    // ---- Phase D: softmax + weighted sum -> o -> s_act
#pragma unroll
    for (int rr = 0; rr < RPW; ++rr) {
        float mx = att[rr][0];
#pragma unroll
        for (int t = 1; t < T_; ++t) mx = fmaxf(mx, att[rr][t]);
        float den = 0.f;
#pragma unroll
        for (int t = 0; t < T_; ++t) { att[rr][t] = expf(att[rr][t] - mx); den += att[rr][t]; }
        float inv = 1.0f / den;
        float o = 0.f;
#pragma unroll
        for (int t = 0; t < T_; ++t) o = fmaf(att[rr][t] * inv, vv[rr][t], o);
        s_act[(rw + rr) * 68 + lane] = o;
    }
    stageW(outw, s_w0, tid);                    // Wo
    __syncthreads();

    // ---- Phase E: out projection + residual + LN2
    float x2[RPW], xn2[RPW];
    {
        float ao[RPW];
#pragma unroll
        for (int rr = 0; rr < RPW; ++rr) ao[rr] = outb[lane];
        const float* wrow = s_w0 + lane * 68;
#pragma unroll 4
        for (int g = 0; g < 16; ++g) {
            float4 w = *(const float4*)(wrow + g * 4);
#pragma unroll
            for (int rr = 0; rr < RPW; ++rr) {
                float4 xv = *(const float4*)(s_act + (rw + rr) * 68 + g * 4);
                ao[rr] = fmaf(xv.x, w.x, fmaf(xv.y, w.y, fmaf(xv.z, w.z, fmaf(xv.w, w.w, ao[rr]))));
            }
        }
        const float g2 = ln2g[lane], b2v = ln2b[lane];
#pragma unroll
        for (int rr = 0; rr < RPW; ++rr) {
            x2[rr] = x[rr] + ao[rr];
            xn2[rr] = lnorm(x2[rr], g2, b2v);
        }
    }
    __syncthreads();
#pragma unroll
    for (int rr = 0; rr < RPW; ++rr) s_act[(rw + rr) * 68 + lane] = xn2[rr];

    // ---- Phase F: FFN in 4 chunks of 64 hidden units
    float hv[RPW];
#pragma unroll
    for (int rr = 0; rr < RPW; ++rr) hv[rr] = f_b2[lane];

    for (int cc = 0; cc < 4; ++cc) {
        stageW(f_w1 + cc * 4096, s_w0, tid);        // W1 chunk rows
        stageWs(f_w2 + cc * 64, 256, s_w1, tid);    // W2 columns for this chunk
        __syncthreads();

        float h[RPW];
        float hb = f_b1[cc * 64 + lane];
#pragma unroll
        for (int rr = 0; rr < RPW; ++rr) h[rr] = hb;
        {
            const float* wrow = s_w0 + lane * 68;
#pragma unroll 4
            for (int g = 0; g < 16; ++g) {
                float4 w = *(const float4*)(wrow + g * 4);
#pragma unroll
                for (int rr = 0; rr < RPW; ++rr) {
                    float4 xv = *(const float4*)(s_act + (rw + rr) * 68 + g * 4);
                    h[rr] = fmaf(xv.x, w.x, fmaf(xv.y, w.y, fmaf(xv.z, w.z, fmaf(xv.w, w.w, h[rr]))));
                }
            }
        }
#pragma unroll
        for (int rr = 0; rr < RPW; ++rr) {
            h[rr] = 0.5f * h[rr] * (1.0f + erff(h[rr] * 0.70710678118654752f));
            s_h[(rw + rr) * 68 + lane] = h[rr];
        }
        __syncthreads();
        {
            const float* wrow = s_w1 + lane * 68;
#pragma unroll 4
            for (int g = 0; g < 16; ++g) {
                float4 w = *(const float4*)(wrow + g * 4);
#pragma unroll
                for (int rr = 0; rr < RPW; ++rr) {
                    float4 xv = *(const float4*)(s_h + (rw + rr) * 68 + g * 4);
                    hv[rr] = fmaf(xv.x, w.x, fmaf(xv.y, w.y, fmaf(xv.z, w.z, fmaf(xv.w, w.w, hv[rr]))));
                }
            }
        }
        __syncthreads();
    }

#pragma unroll
    for (int rr = 0; rr < RPW; ++rr)
        fout[((size_t)(pi * B_ + bb[rr]) * N_ + nn[rr]) * C_ + lane] = x2[rr] + hv[rr];
}

// ---------- output transpose ----------
__global__ __launch_bounds__(256) void output_kernel(const float* __restrict__ f,
                                                     float* __restrict__ out) {
    __shared__ float tile[64][65];
    int blk = blockIdx.x;
    int ntile = blk & 255;
    int bp = blk >> 8;
    int b = bp / 3, p = bp - b * 3;
    int n0 = ntile * 64;
    int tr = threadIdx.x >> 6, tc = threadIdx.x & 63;

    const float* src = f + ((size_t)(p * B_ + b) * N_ + n0) * C_;
#pragma unroll
    for (int it = 0; it < 16; ++it) {
        int r = it * 4 + tr;
        tile[r][tc] = src[(size_t)r * C_ + tc];
    }
    __syncthreads();
    float* dst = out + (size_t)(b * 3 + p) * C_ * N_ + n0;
#pragma unroll
    for (int it = 0; it < 16; ++it) {
        int cidx = it * 4 + tr;
        dst[(size_t)cidx * N_ + tc] = tile[tc][cidx];
    }
}

extern "C" void kernel_launch(void* const* d_in, const int* in_sizes, int n_in,
                              void* d_out, int out_size, void* d_ws, size_t ws_size,
                              hipStream_t stream) {
    const float* img_feats = (const float*)d_in[0];
    const float* pts       = (const float*)d_in[1];
    const float* query     = (const float*)d_in[2];
    const float* ln1_g     = (const float*)d_in[3];
    const float* ln1_b     = (const float*)d_in[4];
    const float* ln2_g     = (const float*)d_in[5];
    const float* ln2_b     = (const float*)d_in[6];
    const float* in_w      = (const float*)d_in[7];
    const float* in_b      = (const float*)d_in[8];
    const float* out_w     = (const float*)d_in[9];
    const float* out_b     = (const float*)d_in[10];
    const float* ffn_w1    = (const float*)d_in[11];
    const float* ffn_b1    = (const float*)d_in[12];
    const float* ffn_w2    = (const float*)d_in[13];
    const float* ffn_b2    = (const float*)d_in[14];

    float* ws = (float*)d_ws;
    const size_t ACC_SZ = (size_t)B_ * 3 * N_ * C_;
    const size_t WACC_SZ = (size_t)B_ * 3 * N_;
    const size_t FEAT_SZ = (size_t)3 * B_ * N_ * C_;
    float* acc  = ws;
    float* wacc = acc + ACC_SZ;
    float* fA   = wacc + WACC_SZ;
    float* fB   = fA + FEAT_SZ;

    init_feats<<<(3 * N_ * C_ + 255) / 256, 256, 0, stream>>>(query, fA);

    int zero_n4 = (int)((ACC_SZ + WACC_SZ) / 4);
    for (int v = 0; v < V_; ++v) {
        zero_kernel<<<(zero_n4 + 255) / 256, 256, 0, stream>>>((float4*)acc, zero_n4);
        splat_kernel<<<(B_ * N_) / 4, 256, 0, stream>>>(img_feats, pts, acc, wacc, v);
        norm_add<<<(int)((ACC_SZ + 255) / 256), 256, 0, stream>>>(acc, wacc, fA);
    }

    dim3 grid((B_ * N_) / RB, 3);
    for (int l = 0; l < NL_; ++l) {
        const float* fin = (l == 0) ? fA : fB;
        float* fout      = (l == 0) ? fB : fA;
        plane_kernel<<<grid, 256, 0, stream>>>(
            fin, fout,
            ln1_g + l * C_, ln1_b + l * C_,
            ln2_g + l * C_, ln2_b + l * C_,
            in_w + (size_t)l * 3 * C_ * C_, in_b + l * 3 * C_,
            out_w + (size_t)l * C_ * C_, out_b + l * C_,
            ffn_w1 + (size_t)l * 4 * C_ * C_, ffn_b1 + l * 4 * C_,
            ffn_w2 + (size_t)l * C_ * 4 * C_, ffn_b2 + l * C_);
    }

    output_kernel<<<B_ * 3 * (N_ / 64), 256, 0, stream>>>(fA, (float*)d_out);
}

// Round 3
// 1574.254 us; speedup vs baseline: 3.1389x; 1.2648x over previous
//
#include <hip/hip_runtime.h>
#include <math.h>

constexpr int R_ = 128, C_ = 64, NL_ = 2, B_ = 2, V_ = 4;
constexpr int N_ = R_ * R_;          // 16384
constexpr int T_ = 6;
constexpr int RB = 32;               // rows per block
constexpr int RPW = 8;               // rows per wave (4 waves)

// ---------- helpers ----------
__device__ inline float wsum(float v) {
#pragma unroll
    for (int m = 1; m < 64; m <<= 1) v += __shfl_xor(v, m, 64);
    return v;
}

__device__ inline float lnorm(float v, float g, float b) {
    float m = wsum(v) * (1.f / 64.f);
    float d = v - m;
    float var = wsum(d * d) * (1.f / 64.f);
    return d * rsqrtf(var + 1e-5f) * g + b;
}

__device__ inline void atomicAddF(float* p, float v) {
    __hip_atomic_fetch_add(p, v, __ATOMIC_RELAXED, __HIP_MEMORY_SCOPE_AGENT);
}

// stage a 64x64 row-major matrix into LDS buf[c*68 + u]
__device__ inline void stageW(const float* __restrict__ W, float* buf, int tid) {
#pragma unroll
    for (int it = 0; it < 4; ++it) {
        int idx4 = it * 256 + tid;          // [0,1024) float4s
        int r = idx4 >> 4, u4 = idx4 & 15;
        float4 v = ((const float4*)W)[idx4];
        *(float4*)&buf[r * 68 + u4 * 4] = v;
    }
}

// stage 64 rows x 64 cols from a matrix with row stride `rs`
__device__ inline void stageWs(const float* __restrict__ W, int rs, float* buf, int tid) {
#pragma unroll
    for (int it = 0; it < 4; ++it) {
        int idx4 = it * 256 + tid;
        int r = idx4 >> 4, u4 = idx4 & 15;
        float4 v = *(const float4*)(W + (size_t)r * rs + u4 * 4);
        *(float4*)&buf[r * 68 + u4 * 4] = v;
    }
}

// ---------- zero workspace region ----------
__global__ __launch_bounds__(256) void zero_kernel(float4* __restrict__ p, int n4) {
    int i = blockIdx.x * 256 + threadIdx.x;
    if (i < n4) p[i] = make_float4(0.f, 0.f, 0.f, 0.f);
}

// ---------- init plane feats with query tensors ----------
__global__ __launch_bounds__(256) void init_feats(const float* __restrict__ q,
                                                  float* __restrict__ f0) {
    int idx = blockIdx.x * 256 + threadIdx.x;
    if (idx >= 3 * N_ * C_) return;
    int p = idx / (N_ * C_);
    int rem = idx - p * (N_ * C_);
    float val = q[idx];
    f0[(size_t)(p * B_ + 0) * N_ * C_ + rem] = val;
    f0[(size_t)(p * B_ + 1) * N_ * C_ + rem] = val;
}

// ---------- splat one view ----------
__global__ __launch_bounds__(256) void splat_kernel(const float* __restrict__ img_feats,
                                                    const float* __restrict__ pts,
                                                    float* __restrict__ acc,
                                                    float* __restrict__ wacc, int v) {
    int gwave = (blockIdx.x * 256 + threadIdx.x) >> 6;
    int lane = threadIdx.x & 63;
    int b = gwave >> 14;
    int n = gwave & (N_ - 1);
    int bv = b * V_ + v;

    const float* p = pts + ((size_t)bv * N_ + n) * 3;
    float px = p[0], py = p[1], pz = p[2];
    float f = img_feats[((size_t)bv * C_ + lane) * N_ + n];

    const float HI = (float)(127.0 - 1e-5);
    float gx = fminf(fmaxf((px + 1.0f) * 127.0f / 2.0f, 0.0f), HI);
    float gy = fminf(fmaxf((py + 1.0f) * 127.0f / 2.0f, 0.0f), HI);
    float gz = fminf(fmaxf((pz + 1.0f) * 127.0f / 2.0f, 0.0f), HI);
    int x0 = (int)gx, y0 = (int)gy, z0 = (int)gz;
    float wx = gx - (float)x0, wy = gy - (float)y0, wz = gz - (float)z0;
    int x1 = x0 + 1 < 128 ? x0 + 1 : 127;
    int y1 = y0 + 1 < 128 ? y0 + 1 : 127;
    int z1 = z0 + 1 < 128 ? z0 + 1 : 127;
    float ax = 1.0f - wx, ay = 1.0f - wy, az = 1.0f - wz;
    float w000 = ax * ay * az;
    float w001 = ax * ay * wz;
    float w010 = ax * wy * az;
    float w100 = wx * ay * az;
    float w110 = wx * wy * az;
    float w111 = wx * wy * wz;

    float* a0 = acc + (size_t)(b * 3 + 0) * N_ * C_;
    float* a1 = acc + (size_t)(b * 3 + 1) * N_ * C_;
    float* a2 = acc + (size_t)(b * 3 + 2) * N_ * C_;
    float* wa0 = wacc + (size_t)(b * 3 + 0) * N_;
    float* wa1 = wacc + (size_t)(b * 3 + 1) * N_;
    float* wa2 = wacc + (size_t)(b * 3 + 2) * N_;

#define SPLAT_ADD(A, WA, IA, IB, W)                                   \
    do {                                                              \
        int cell = (IA) * R_ + (IB);                                  \
        atomicAddF((A) + (size_t)cell * C_ + lane, (W)*f);            \
        if (lane == 0) atomicAddF((WA) + cell, (W));                  \
    } while (0)

    SPLAT_ADD(a0, wa0, x0, y0, w000);
    SPLAT_ADD(a0, wa0, x0, y1, w010);
    SPLAT_ADD(a0, wa0, x1, y0, w100);
    SPLAT_ADD(a0, wa0, x1, y1, w110);

    SPLAT_ADD(a1, wa1, x0, z0, w000);
    SPLAT_ADD(a1, wa1, x0, z1, w001);
    SPLAT_ADD(a1, wa1, x1, z0, w100);
    SPLAT_ADD(a1, wa1, x1, z1, w111);

    SPLAT_ADD(a2, wa2, y0, z0, w000);
    SPLAT_ADD(a2, wa2, y0, z1, w001);
    SPLAT_ADD(a2, wa2, y1, z0, w010);
    SPLAT_ADD(a2, wa2, y1, z1, w111);
#undef SPLAT_ADD
}

// ---------- normalize view contribution, add 1/V ----------
__global__ __launch_bounds__(256) void norm_add(const float* __restrict__ acc,
                                                const float* __restrict__ wacc,
                                                float* __restrict__ f0) {
    int idx = blockIdx.x * 256 + threadIdx.x;
    if (idx >= B_ * 3 * N_ * C_) return;
    int c = idx & 63;
    int cell = (idx >> 6) & (N_ - 1);
    int bp = idx >> 20;
    int b = bp / 3, p = bp - b * 3;
    float w = wacc[(size_t)bp * N_ + cell];
    float val = acc[idx] / fmaxf(w, 1e-8f);
    f0[((size_t)(p * B_ + b) * N_ + cell) * C_ + c] += 0.25f * val;
}

// ---------- fused per-plane transformer layer ----------
__global__ __launch_bounds__(256) void plane_kernel(
    const float* __restrict__ fin, float* __restrict__ fout,
    const float* __restrict__ ln1g, const float* __restrict__ ln1b,
    const float* __restrict__ ln2g, const float* __restrict__ ln2b,
    const float* __restrict__ inw, const float* __restrict__ inb,
    const float* __restrict__ outw, const float* __restrict__ outb,
    const float* __restrict__ f_w1, const float* __restrict__ f_b1,
    const float* __restrict__ f_w2, const float* __restrict__ f_b2) {
    __shared__ float s_w0[64 * 68];
    __shared__ float s_w1[64 * 68];
    __shared__ float s_act[RB * 68];
    __shared__ float s_h[RB * 68];

    const int tid = threadIdx.x;
    const int wid = tid >> 6, lane = tid & 63;
    const int pi = blockIdx.y;
    const int rw = wid * RPW;                   // wave's first local row
    const int rbase = blockIdx.x * RB + rw;     // wave's first global row (mult of 8)

    // wave-uniform decomposition: all 8 rows share b and i; j = jbase + rr
    const int b = rbase >> 14;
    const int nn0 = rbase & (N_ - 1);
    const int i0 = nn0 >> 7, jbase = nn0 & 127;
    const float lin_i = -1.0f + (2.0f * (float)i0) / 127.0f;

    const float g1 = ln1g[lane], b1v = ln1b[lane];

    float x[RPW];

    // ---- Phase A: load x, LN1 -> s_act; stage Wq, Wk
#pragma unroll
    for (int rr = 0; rr < RPW; ++rr) {
        x[rr] = fin[((size_t)(pi * B_ + b) * N_ + nn0 + rr) * C_ + lane];
        s_act[(rw + rr) * 68 + lane] = lnorm(x[rr], g1, b1v);
    }
    stageW(inw, s_w0, tid);                     // Wq
    stageW(inw + 4096, s_w1, tid);              // Wk
    __syncthreads();

    // ---- Phase B: q projection (reads s_w0=Wq)
    float q[RPW];
#pragma unroll
    for (int rr = 0; rr < RPW; ++rr) q[rr] = inb[lane];
    {
        const float* wrow = s_w0 + lane * 68;
#pragma unroll 4
        for (int g = 0; g < 16; ++g) {
            float4 w = *(const float4*)(wrow + g * 4);
#pragma unroll
            for (int rr = 0; rr < RPW; ++rr) {
                float4 xv = *(const float4*)(s_act + (rw + rr) * 68 + g * 4);
                q[rr] = fmaf(xv.x, w.x, fmaf(xv.y, w.y, fmaf(xv.z, w.z, fmaf(xv.w, w.w, q[rr]))));
            }
        }
    }
    __syncthreads();
    stageW(inw + 8192, s_w0, tid);              // Wv (overwrites Wq)
    __syncthreads();

    // ---- Phase C: barrier-free T-loop with online softmax
    // s_act rows are wave-private; only weights are cross-wave (already staged).
    float m_[RPW], den_[RPW], o_[RPW];
#pragma unroll
    for (int rr = 0; rr < RPW; ++rr) { m_[rr] = -1e30f; den_[rr] = 0.f; o_[rr] = 0.f; }
    const float bk = inb[64 + lane], bvv = inb[128 + lane];

    for (int t = 0; t < T_; ++t) {
        int k = (t < 3) ? t : t - 3;
        float sk = (float)(k - 1);
#pragma unroll
        for (int rr = 0; rr < RPW; ++rr) {
            float lin_j = -1.0f + (2.0f * (float)(jbase + rr)) / 127.0f;
            int io;
            float caf, cbf;
            if (pi == 0) {
                if (t < 3) { io = 1; caf = lin_j; cbf = sk; }
                else       { io = 2; caf = lin_i; cbf = sk; }
            } else if (pi == 1) {
                if (t < 3) { io = 0; caf = lin_j; cbf = sk; }
                else       { io = 2; caf = sk;    cbf = lin_i; }
            } else {
                if (t < 3) { io = 0; caf = sk;    cbf = lin_j; }
                else       { io = 1; caf = sk;    cbf = lin_i; }
            }
            float ua = fminf(fmaxf((caf * 0.5f + 0.5f) * 127.0f, 0.0f), 127.0f);
            float ub = fminf(fmaxf((cbf * 0.5f + 0.5f) * 127.0f, 0.0f), 127.0f);
            float gxp = fminf(fmaxf(((ua + 1.0f) * 0.5f) * 127.0f, 0.0f), 127.0f);
            float gyp = fminf(fmaxf(((ub + 1.0f) * 0.5f) * 127.0f, 0.0f), 127.0f);
            int xx0 = (int)gxp, yy0 = (int)gyp;
            int xx1 = xx0 + 1 < 128 ? xx0 + 1 : 127;
            int yy1 = yy0 + 1 < 128 ? yy0 + 1 : 127;
            float wx = gxp - (float)xx0, wyv = gyp - (float)yy0;
            const float* Fp = fin + (size_t)(io * B_ + b) * N_ * C_ + lane;
            float v00 = Fp[(size_t)(yy0 * R_ + xx0) * C_];
            float v01 = Fp[(size_t)(yy0 * R_ + xx1) * C_];
            float v10 = Fp[(size_t)(yy1 * R_ + xx0) * C_];
            float v11 = Fp[(size_t)(yy1 * R_ + xx1) * C_];
            float cv = (1.0f - wyv) * ((1.0f - wx) * v00 + wx * v01) +
                       wyv * ((1.0f - wx) * v10 + wx * v11);
            s_act[(rw + rr) * 68 + lane] = lnorm(cv, g1, b1v);
        }

        float kk[RPW], vt[RPW];
#pragma unroll
        for (int rr = 0; rr < RPW; ++rr) { kk[rr] = bk; vt[rr] = bvv; }
        {
            const float* wrk = s_w1 + lane * 68;   // Wk
            const float* wrv = s_w0 + lane * 68;   // Wv
#pragma unroll 4
            for (int g = 0; g < 16; ++g) {
                float4 w0 = *(const float4*)(wrk + g * 4);
                float4 w1 = *(const float4*)(wrv + g * 4);
#pragma unroll
                for (int rr = 0; rr < RPW; ++rr) {
                    float4 xv = *(const float4*)(s_act + (rw + rr) * 68 + g * 4);
                    kk[rr] = fmaf(xv.x, w0.x, fmaf(xv.y, w0.y, fmaf(xv.z, w0.z, fmaf(xv.w, w0.w, kk[rr]))));
                    vt[rr] = fmaf(xv.x, w1.x, fmaf(xv.y, w1.y, fmaf(xv.z, w1.z, fmaf(xv.w, w1.w, vt[rr]))));
                }
            }
        }
#pragma unroll
        for (int rr = 0; rr < RPW; ++rr) {
            float d = q[rr] * kk[rr];
#pragma unroll
            for (int m = 1; m < 16; m <<= 1) d += __shfl_xor(d, m, 64);
            float at = d * 0.25f;                   // 1/sqrt(16)
            float mn = fmaxf(m_[rr], at);
            float sc = __expf(m_[rr] - mn);
            float e = __expf(at - mn);
            den_[rr] = den_[rr] * sc + e;
            o_[rr] = o_[rr] * sc + e * vt[rr];
            m_[rr] = mn;
        }
    }

    __syncthreads();
    stageW(outw, s_w0, tid);                    // Wo
#pragma unroll
    for (int rr = 0; rr < RPW; ++rr)
        s_act[(rw + rr) * 68 + lane] = o_[rr] / den_[rr];
    __syncthreads();

    // ---- Phase E: out projection + residual + LN2
    float x2[RPW], xn2[RPW];
    {
        float ao[RPW];
#pragma unroll
        for (int rr = 0; rr < RPW; ++rr) ao[rr] = outb[lane];
        const float* wrow = s_w0 + lane * 68;
#pragma unroll 4
        for (int g = 0; g < 16; ++g) {
            float4 w = *(const float4*)(wrow + g * 4);
#pragma unroll
            for (int rr = 0; rr < RPW; ++rr) {
                float4 xv = *(const float4*)(s_act + (rw + rr) * 68 + g * 4);
                ao[rr] = fmaf(xv.x, w.x, fmaf(xv.y, w.y, fmaf(xv.z, w.z, fmaf(xv.w, w.w, ao[rr]))));
            }
        }
        const float g2 = ln2g[lane], b2v = ln2b[lane];
#pragma unroll
        for (int rr = 0; rr < RPW; ++rr) {
            x2[rr] = x[rr] + ao[rr];
            xn2[rr] = lnorm(x2[rr], g2, b2v);
        }
    }

    // ---- Phase F: FFN in 4 chunks of 64 hidden units
    float hv[RPW];
#pragma unroll
    for (int rr = 0; rr < RPW; ++rr) hv[rr] = f_b2[lane];

    for (int cc = 0; cc < 4; ++cc) {
        __syncthreads();                            // prev chunk weights (and Wo) free
        stageW(f_w1 + cc * 4096, s_w0, tid);        // W1 chunk rows
        stageWs(f_w2 + cc * 64, 256, s_w1, tid);    // W2 columns for this chunk
        if (cc == 0) {
#pragma unroll
            for (int rr = 0; rr < RPW; ++rr) s_act[(rw + rr) * 68 + lane] = xn2[rr];
        }
        __syncthreads();

        float h[RPW];
        float hb = f_b1[cc * 64 + lane];
#pragma unroll
        for (int rr = 0; rr < RPW; ++rr) h[rr] = hb;
        {
            const float* wrow = s_w0 + lane * 68;
#pragma unroll 4
            for (int g = 0; g < 16; ++g) {
                float4 w = *(const float4*)(wrow + g * 4);
#pragma unroll
                for (int rr = 0; rr < RPW; ++rr) {
                    float4 xv = *(const float4*)(s_act + (rw + rr) * 68 + g * 4);
                    h[rr] = fmaf(xv.x, w.x, fmaf(xv.y, w.y, fmaf(xv.z, w.z, fmaf(xv.w, w.w, h[rr]))));
                }
            }
        }
#pragma unroll
        for (int rr = 0; rr < RPW; ++rr) {
            h[rr] = 0.5f * h[rr] * (1.0f + erff(h[rr] * 0.70710678118654752f));
            s_h[(rw + rr) * 68 + lane] = h[rr];     // wave-private rows
        }
        {
            const float* wrow = s_w1 + lane * 68;
#pragma unroll 4
            for (int g = 0; g < 16; ++g) {
                float4 w = *(const float4*)(wrow + g * 4);
#pragma unroll
                for (int rr = 0; rr < RPW; ++rr) {
                    float4 xv = *(const float4*)(s_h + (rw + rr) * 68 + g * 4);
                    hv[rr] = fmaf(xv.x, w.x, fmaf(xv.y, w.y, fmaf(xv.z, w.z, fmaf(xv.w, w.w, hv[rr]))));
                }
            }
        }
    }

#pragma unroll
    for (int rr = 0; rr < RPW; ++rr)
        fout[((size_t)(pi * B_ + b) * N_ + nn0 + rr) * C_ + lane] = x2[rr] + hv[rr];
}

// ---------- output transpose ----------
__global__ __launch_bounds__(256) void output_kernel(const float* __restrict__ f,
                                                     float* __restrict__ out) {
    __shared__ float tile[64][65];
    int blk = blockIdx.x;
    int ntile = blk & 255;
    int bp = blk >> 8;
    int b = bp / 3, p = bp - b * 3;
    int n0 = ntile * 64;
    int tr = threadIdx.x >> 6, tc = threadIdx.x & 63;

    const float* src = f + ((size_t)(p * B_ + b) * N_ + n0) * C_;
#pragma unroll
    for (int it = 0; it < 16; ++it) {
        int r = it * 4 + tr;
        tile[r][tc] = src[(size_t)r * C_ + tc];
    }
    __syncthreads();
    float* dst = out + (size_t)(b * 3 + p) * C_ * N_ + n0;
#pragma unroll
    for (int it = 0; it < 16; ++it) {
        int cidx = it * 4 + tr;
        dst[(size_t)cidx * N_ + tc] = tile[tc][cidx];
    }
}

extern "C" void kernel_launch(void* const* d_in, const int* in_sizes, int n_in,
                              void* d_out, int out_size, void* d_ws, size_t ws_size,
                              hipStream_t stream) {
    const float* img_feats = (const float*)d_in[0];
    const float* pts       = (const float*)d_in[1];
    const float* query     = (const float*)d_in[2];
    const float* ln1_g     = (const float*)d_in[3];
    const float* ln1_b     = (const float*)d_in[4];
    const float* ln2_g     = (const float*)d_in[5];
    const float* ln2_b     = (const float*)d_in[6];
    const float* in_w      = (const float*)d_in[7];
    const float* in_b      = (const float*)d_in[8];
    const float* out_w     = (const float*)d_in[9];
    const float* out_b     = (const float*)d_in[10];
    const float* ffn_w1    = (const float*)d_in[11];
    const float* ffn_b1    = (const float*)d_in[12];
    const float* ffn_w2    = (const float*)d_in[13];
    const float* ffn_b2    = (const float*)d_in[14];

    float* ws = (float*)d_ws;
    const size_t ACC_SZ = (size_t)B_ * 3 * N_ * C_;
    const size_t WACC_SZ = (size_t)B_ * 3 * N_;
    const size_t FEAT_SZ = (size_t)3 * B_ * N_ * C_;
    float* acc  = ws;
    float* wacc = acc + ACC_SZ;
    float* fA   = wacc + WACC_SZ;
    float* fB   = fA + FEAT_SZ;

    init_feats<<<(3 * N_ * C_ + 255) / 256, 256, 0, stream>>>(query, fA);

    int zero_n4 = (int)((ACC_SZ + WACC_SZ) / 4);
    for (int v = 0; v < V_; ++v) {
        zero_kernel<<<(zero_n4 + 255) / 256, 256, 0, stream>>>((float4*)acc, zero_n4);
        splat_kernel<<<(B_ * N_) / 4, 256, 0, stream>>>(img_feats, pts, acc, wacc, v);
        norm_add<<<(int)((ACC_SZ + 255) / 256), 256, 0, stream>>>(acc, wacc, fA);
    }

    dim3 grid((B_ * N_) / RB, 3);
    for (int l = 0; l < NL_; ++l) {
        const float* fin = (l == 0) ? fA : fB;
        float* fout      = (l == 0) ? fB : fA;
        plane_kernel<<<grid, 256, 0, stream>>>(
            fin, fout,
            ln1_g + l * C_, ln1_b + l * C_,
            ln2_g + l * C_, ln2_b + l * C_,
            in_w + (size_t)l * 3 * C_ * C_, in_b + l * 3 * C_,
            out_w + (size_t)l * C_ * C_, out_b + l * C_,
            ffn_w1 + (size_t)l * 4 * C_ * C_, ffn_b1 + l * 4 * C_,
            ffn_w2 + (size_t)l * C_ * 4 * C_, ffn_b2 + l * C_);
    }

    output_kernel<<<B_ * 3 * (N_ / 64), 256, 0, stream>>>(fA, (float*)d_out);
}

// Round 4
// 1191.727 us; speedup vs baseline: 4.1464x; 1.3210x over previous
//
#include <hip/hip_runtime.h>
#include <math.h>

constexpr int R_ = 128, C_ = 64, NL_ = 2, B_ = 2, V_ = 4;
constexpr int N_ = R_ * R_;          // 16384
constexpr int T_ = 6;

typedef __attribute__((ext_vector_type(8))) short bf16x8;
typedef __attribute__((ext_vector_type(4))) float f32x4;

#define MFMA_B16(a, b, c) __builtin_amdgcn_mfma_f32_16x16x32_bf16((a), (b), (c), 0, 0, 0)

// packed-weight element offsets (per layer, in elements)
constexpr int OFF_Q = 0, OFF_K = 4096, OFF_V = 8192, OFF_O = 12288;
constexpr int OFF_W1 = 16384, OFF_W2 = 32768;
constexpr int LAYER_PK = 2 * 49152;   // ushorts per layer (hi+lo)

// ---------- helpers ----------
__device__ inline void atomicAddF(float* p, float v) {
    __hip_atomic_fetch_add(p, v, __ATOMIC_RELAXED, __HIP_MEMORY_SCOPE_AGENT);
}

__device__ inline unsigned rne16(float x) {
    unsigned b = __float_as_uint(x);
    return (b + 0x7fffu + ((b >> 16) & 1u)) >> 16;
}

// read A-fragment (16x32 bf16) for wave's M-tile from swizzled LDS
__device__ inline bf16x8 readFrag(const unsigned short* base, int rowBase, int lane,
                                  int ks, int rowStrideB, int swzMask) {
    int rowloc = rowBase + (lane & 15);
    int off = rowloc * rowStrideB + ks * 64 + ((lane >> 4) & 3) * 16;
    off ^= ((rowloc & swzMask) << 4);
    return *(const bf16x8*)((const char*)base + off);
}

// split fp32 -> (hi,lo) bf16, store to swizzled LDS
__device__ inline void storeSplit(unsigned short* hiB, unsigned short* loB, int byteOff, float v) {
    unsigned hb = rne16(v);
    float hf = __uint_as_float(hb << 16);
    unsigned lb = rne16(v - hf);
    *(unsigned short*)((char*)hiB + byteOff) = (unsigned short)hb;
    *(unsigned short*)((char*)loB + byteOff) = (unsigned short)lb;
}

// load B-fragment pair (hi,lo) from packed weights
__device__ inline void readB(const unsigned short* matHi, int E, int NTm, int ks, int nt,
                             int lane, bf16x8& bh, bf16x8& bl) {
    int off = (((ks * NTm + nt) << 6) + lane) << 3;
    bh = *(const bf16x8*)(matHi + off);
    bl = *(const bf16x8*)(matHi + E + off);
}

// ---------- pack weights into B-fragment order, split bf16 ----------
__global__ __launch_bounds__(256) void pack_w(const float* __restrict__ W, int O, int K,
                                              unsigned short* __restrict__ dhi,
                                              unsigned short* __restrict__ dlo) {
    int idx = blockIdx.x * 256 + threadIdx.x;
    if (idx >= O * K) return;
    int j = idx & 7, l = (idx >> 3) & 63, rem = idx >> 9;
    int NTm = O >> 4;
    int nt = rem & (NTm - 1), ks = rem / NTm;
    int o = nt * 16 + (l & 15);
    int k = ks * 32 + ((l >> 4) & 3) * 8 + j;
    float w = W[(size_t)o * K + k];
    unsigned hb = rne16(w);
    float hf = __uint_as_float(hb << 16);
    unsigned lb = rne16(w - hf);
    dhi[idx] = (unsigned short)hb;
    dlo[idx] = (unsigned short)lb;
}

// ---------- zero workspace region ----------
__global__ __launch_bounds__(256) void zero_kernel(float4* __restrict__ p, int n4) {
    int i = blockIdx.x * 256 + threadIdx.x;
    if (i < n4) p[i] = make_float4(0.f, 0.f, 0.f, 0.f);
}

// ---------- init plane feats with query tensors ----------
__global__ __launch_bounds__(256) void init_feats(const float* __restrict__ q,
                                                  float* __restrict__ f0) {
    int idx = blockIdx.x * 256 + threadIdx.x;
    if (idx >= 3 * N_ * C_) return;
    int p = idx / (N_ * C_);
    int rem = idx - p * (N_ * C_);
    float val = q[idx];
    f0[(size_t)(p * B_ + 0) * N_ * C_ + rem] = val;
    f0[(size_t)(p * B_ + 1) * N_ * C_ + rem] = val;
}

// ---------- splat one view ----------
__global__ __launch_bounds__(256) void splat_kernel(const float* __restrict__ img_feats,
                                                    const float* __restrict__ pts,
                                                    float* __restrict__ acc,
                                                    float* __restrict__ wacc, int v) {
    int gwave = (blockIdx.x * 256 + threadIdx.x) >> 6;
    int lane = threadIdx.x & 63;
    int b = gwave >> 14;
    int n = gwave & (N_ - 1);
    int bv = b * V_ + v;

    const float* p = pts + ((size_t)bv * N_ + n) * 3;
    float px = p[0], py = p[1], pz = p[2];
    float f = img_feats[((size_t)bv * C_ + lane) * N_ + n];

    const float HI = (float)(127.0 - 1e-5);
    float gx = fminf(fmaxf((px + 1.0f) * 127.0f / 2.0f, 0.0f), HI);
    float gy = fminf(fmaxf((py + 1.0f) * 127.0f / 2.0f, 0.0f), HI);
    float gz = fminf(fmaxf((pz + 1.0f) * 127.0f / 2.0f, 0.0f), HI);
    int x0 = (int)gx, y0 = (int)gy, z0 = (int)gz;
    float wx = gx - (float)x0, wy = gy - (float)y0, wz = gz - (float)z0;
    int x1 = x0 + 1 < 128 ? x0 + 1 : 127;
    int y1 = y0 + 1 < 128 ? y0 + 1 : 127;
    int z1 = z0 + 1 < 128 ? z0 + 1 : 127;
    float ax = 1.0f - wx, ay = 1.0f - wy, az = 1.0f - wz;
    float w000 = ax * ay * az;
    float w001 = ax * ay * wz;
    float w010 = ax * wy * az;
    float w100 = wx * ay * az;
    float w110 = wx * wy * az;
    float w111 = wx * wy * wz;

    float* a0 = acc + (size_t)(b * 3 + 0) * N_ * C_;
    float* a1 = acc + (size_t)(b * 3 + 1) * N_ * C_;
    float* a2 = acc + (size_t)(b * 3 + 2) * N_ * C_;
    float* wa0 = wacc + (size_t)(b * 3 + 0) * N_;
    float* wa1 = wacc + (size_t)(b * 3 + 1) * N_;
    float* wa2 = wacc + (size_t)(b * 3 + 2) * N_;

#define SPLAT_ADD(A, WA, IA, IB, W)                                   \
    do {                                                              \
        int cell = (IA) * R_ + (IB);                                  \
        atomicAddF((A) + (size_t)cell * C_ + lane, (W)*f);            \
        if (lane == 0) atomicAddF((WA) + cell, (W));                  \
    } while (0)

    SPLAT_ADD(a0, wa0, x0, y0, w000);
    SPLAT_ADD(a0, wa0, x0, y1, w010);
    SPLAT_ADD(a0, wa0, x1, y0, w100);
    SPLAT_ADD(a0, wa0, x1, y1, w110);

    SPLAT_ADD(a1, wa1, x0, z0, w000);
    SPLAT_ADD(a1, wa1, x0, z1, w001);
    SPLAT_ADD(a1, wa1, x1, z0, w100);
    SPLAT_ADD(a1, wa1, x1, z1, w111);

    SPLAT_ADD(a2, wa2, y0, z0, w000);
    SPLAT_ADD(a2, wa2, y0, z1, w001);
    SPLAT_ADD(a2, wa2, y1, z0, w010);
    SPLAT_ADD(a2, wa2, y1, z1, w111);
#undef SPLAT_ADD
}

// ---------- normalize view contribution, add 1/V ----------
__global__ __launch_bounds__(256) void norm_add(const float* __restrict__ acc,
                                                const float* __restrict__ wacc,
                                                float* __restrict__ f0) {
    int idx = blockIdx.x * 256 + threadIdx.x;
    if (idx >= B_ * 3 * N_ * C_) return;
    int c = idx & 63;
    int cell = (idx >> 6) & (N_ - 1);
    int bp = idx >> 20;
    int b = bp / 3, p = bp - b * 3;
    float w = wacc[(size_t)bp * N_ + cell];
    float val = acc[idx] / fmaxf(w, 1e-8f);
    f0[((size_t)(p * B_ + b) * N_ + cell) * C_ + c] += 0.25f * val;
}

// ---------- fused per-plane transformer layer (MFMA, split-bf16, barrier-free) ----------
__global__ __launch_bounds__(256) void plane_mfma(
    const float* __restrict__ fin, float* __restrict__ fout,
    const unsigned short* __restrict__ pk,
    const float* __restrict__ ln1g, const float* __restrict__ ln1b,
    const float* __restrict__ ln2g, const float* __restrict__ ln2b,
    const float* __restrict__ inb, const float* __restrict__ outb,
    const float* __restrict__ fb1, const float* __restrict__ fb2) {
    __shared__ unsigned short Ahi[64 * 64], Alo[64 * 64];     // 8 KB + 8 KB
    __shared__ unsigned short Hhi[64 * 128], Hlo[64 * 128];   // 16 KB + 16 KB

    const int tid = threadIdx.x;
    const int wid = tid >> 6, lane = tid & 63;
    const int cg = lane >> 4, cb = lane & 15;
    const int pi = blockIdx.y;
    const int R0 = wid * 16;                  // wave's first local row
    const int rowbase = blockIdx.x * 64;      // block's first global row
    const int b = rowbase >> 14;
    const int nn0 = rowbase & (N_ - 1);
    const int i0 = nn0 >> 7, j0 = nn0 & 127;
    const float lin_i = -1.0f + (2.0f * (float)i0) / 127.0f;

    // per-lane channel params: ch(nt) = nt*16+cb
    float g1[4], b1v[4];
#pragma unroll
    for (int nt = 0; nt < 4; ++nt) { g1[nt] = ln1g[nt * 16 + cb]; b1v[nt] = ln1b[nt * 16 + cb]; }

    // ---- Phase A: load x, LN1, split -> A-frags (wave-private LDS rows)
    float x[4][4];                            // [reg][nt]
    const float* finp = fin + ((size_t)(pi * B_ + b) * N_ + nn0) * 64;
#pragma unroll
    for (int reg = 0; reg < 4; ++reg) {
        int rloc = R0 + cg * 4 + reg;
#pragma unroll
        for (int nt = 0; nt < 4; ++nt) x[reg][nt] = finp[(size_t)rloc * 64 + nt * 16 + cb];
        float s = x[reg][0] + x[reg][1] + x[reg][2] + x[reg][3];
#pragma unroll
        for (int m = 1; m < 16; m <<= 1) s += __shfl_xor(s, m, 64);
        float mean = s * (1.0f / 64.0f);
        float d0 = x[reg][0] - mean, d1 = x[reg][1] - mean, d2 = x[reg][2] - mean, d3 = x[reg][3] - mean;
        float sq = d0 * d0 + d1 * d1 + d2 * d2 + d3 * d3;
#pragma unroll
        for (int m = 1; m < 16; m <<= 1) sq += __shfl_xor(sq, m, 64);
        float rr = rsqrtf(sq * (1.0f / 64.0f) + 1e-5f);
        int swz = (rloc & 7) << 4;
#pragma unroll
        for (int nt = 0; nt < 4; ++nt) {
            float xn = (x[reg][nt] - mean) * rr * g1[nt] + b1v[nt];
            int bo = (rloc * 128 + (nt * 16 + cb) * 2) ^ swz;
            storeSplit(Ahi, Alo, bo, xn);
        }
    }

    // ---- Phase B: q = xn @ Wq^T + bq
    f32x4 qa[4];
#pragma unroll
    for (int nt = 0; nt < 4; ++nt) { float bq = inb[nt * 16 + cb]; qa[nt] = {bq, bq, bq, bq}; }
    {
        const unsigned short* pQ = pk + 2 * OFF_Q;
#pragma unroll
        for (int ks = 0; ks < 2; ++ks) {
            bf16x8 ah = readFrag(Ahi, R0, lane, ks, 128, 7);
            bf16x8 al = readFrag(Alo, R0, lane, ks, 128, 7);
#pragma unroll
            for (int nt = 0; nt < 4; ++nt) {
                bf16x8 bh, bl;
                readB(pQ, 4096, 4, ks, nt, lane, bh, bl);
                qa[nt] = MFMA_B16(ah, bh, qa[nt]);
                qa[nt] = MFMA_B16(ah, bl, qa[nt]);
                qa[nt] = MFMA_B16(al, bh, qa[nt]);
            }
        }
    }

    // ---- Phase C: t-loop — gather ctx, LN, k/v MFMA, online softmax (no barriers)
    float kbias[4], vbias[4];
#pragma unroll
    for (int nt = 0; nt < 4; ++nt) { kbias[nt] = inb[64 + nt * 16 + cb]; vbias[nt] = inb[128 + nt * 16 + cb]; }
    float m_[4][4], den_[4][4];
    f32x4 oa[4];
#pragma unroll
    for (int nt = 0; nt < 4; ++nt) {
        oa[nt] = {0.f, 0.f, 0.f, 0.f};
#pragma unroll
        for (int reg = 0; reg < 4; ++reg) { m_[nt][reg] = -1e30f; den_[nt][reg] = 0.f; }
    }
    const unsigned short* pK = pk + 2 * OFF_K;
    const unsigned short* pV = pk + 2 * OFF_V;

    for (int t = 0; t < T_; ++t) {
        int khalf = (t < 3) ? t : t - 3;
        float sk = (float)(khalf - 1);
        bool tl = (t < 3);
        int io;
        if (pi == 0) io = tl ? 1 : 2;
        else if (pi == 1) io = tl ? 0 : 2;
        else io = tl ? 0 : 1;
        const float* Fio = fin + (size_t)(io * B_ + b) * N_ * 64;

#pragma unroll
        for (int reg = 0; reg < 4; ++reg) {
            int rloc = R0 + cg * 4 + reg;
            float lin_j = -1.0f + (2.0f * (float)(j0 + rloc)) / 127.0f;
            float caf, cbf;
            if (pi == 0) { caf = tl ? lin_j : lin_i; cbf = sk; }
            else if (pi == 1) { if (tl) { caf = lin_j; cbf = sk; } else { caf = sk; cbf = lin_i; } }
            else { caf = sk; cbf = tl ? lin_j : lin_i; }
            float ua = fminf(fmaxf((caf * 0.5f + 0.5f) * 127.0f, 0.0f), 127.0f);
            float ub = fminf(fmaxf((cbf * 0.5f + 0.5f) * 127.0f, 0.0f), 127.0f);
            float gxp = fminf(fmaxf(((ua + 1.0f) * 0.5f) * 127.0f, 0.0f), 127.0f);
            float gyp = fminf(fmaxf(((ub + 1.0f) * 0.5f) * 127.0f, 0.0f), 127.0f);
            int xx0 = (int)gxp, yy0 = (int)gyp;
            int xx1 = xx0 + 1 < 128 ? xx0 + 1 : 127;
            int yy1 = yy0 + 1 < 128 ? yy0 + 1 : 127;
            float wx = gxp - (float)xx0, wyv = gyp - (float)yy0;
            size_t c00 = (size_t)(yy0 * R_ + xx0) * 64, c01 = (size_t)(yy0 * R_ + xx1) * 64;
            size_t c10 = (size_t)(yy1 * R_ + xx0) * 64, c11 = (size_t)(yy1 * R_ + xx1) * 64;
            float cv[4];
#pragma unroll
            for (int nt = 0; nt < 4; ++nt) {
                int ch = nt * 16 + cb;
                float v00 = Fio[c00 + ch], v01 = Fio[c01 + ch];
                float v10 = Fio[c10 + ch], v11 = Fio[c11 + ch];
                cv[nt] = (1.0f - wyv) * ((1.0f - wx) * v00 + wx * v01) +
                         wyv * ((1.0f - wx) * v10 + wx * v11);
            }
            float s = cv[0] + cv[1] + cv[2] + cv[3];
#pragma unroll
            for (int m = 1; m < 16; m <<= 1) s += __shfl_xor(s, m, 64);
            float mean = s * (1.0f / 64.0f);
            float d0 = cv[0] - mean, d1 = cv[1] - mean, d2 = cv[2] - mean, d3 = cv[3] - mean;
            float sq = d0 * d0 + d1 * d1 + d2 * d2 + d3 * d3;
#pragma unroll
            for (int m = 1; m < 16; m <<= 1) sq += __shfl_xor(sq, m, 64);
            float rr = rsqrtf(sq * (1.0f / 64.0f) + 1e-5f);
            int swz = (rloc & 7) << 4;
#pragma unroll
            for (int nt = 0; nt < 4; ++nt) {
                float xn = (cv[nt] - mean) * rr * g1[nt] + b1v[nt];
                int bo = (rloc * 128 + (nt * 16 + cb) * 2) ^ swz;
                storeSplit(Ahi, Alo, bo, xn);
            }
        }

        // k,v projections via MFMA
        f32x4 ka[4], va[4];
#pragma unroll
        for (int nt = 0; nt < 4; ++nt) {
            ka[nt] = {kbias[nt], kbias[nt], kbias[nt], kbias[nt]};
            va[nt] = {vbias[nt], vbias[nt], vbias[nt], vbias[nt]};
        }
#pragma unroll
        for (int ks = 0; ks < 2; ++ks) {
            bf16x8 ah = readFrag(Ahi, R0, lane, ks, 128, 7);
            bf16x8 al = readFrag(Alo, R0, lane, ks, 128, 7);
#pragma unroll
            for (int nt = 0; nt < 4; ++nt) {
                bf16x8 bh, bl;
                readB(pK, 4096, 4, ks, nt, lane, bh, bl);
                ka[nt] = MFMA_B16(ah, bh, ka[nt]);
                ka[nt] = MFMA_B16(ah, bl, ka[nt]);
                ka[nt] = MFMA_B16(al, bh, ka[nt]);
                readB(pV, 4096, 4, ks, nt, lane, bh, bl);
                va[nt] = MFMA_B16(ah, bh, va[nt]);
                va[nt] = MFMA_B16(ah, bl, va[nt]);
                va[nt] = MFMA_B16(al, bh, va[nt]);
            }
        }

        // scores (head = nt) + online softmax
#pragma unroll
        for (int nt = 0; nt < 4; ++nt) {
            float d0 = qa[nt][0] * ka[nt][0];
            float d1 = qa[nt][1] * ka[nt][1];
            float d2 = qa[nt][2] * ka[nt][2];
            float d3 = qa[nt][3] * ka[nt][3];
#pragma unroll
            for (int m = 1; m < 16; m <<= 1) {
                d0 += __shfl_xor(d0, m, 64);
                d1 += __shfl_xor(d1, m, 64);
                d2 += __shfl_xor(d2, m, 64);
                d3 += __shfl_xor(d3, m, 64);
            }
            float dd[4] = {d0, d1, d2, d3};
#pragma unroll
            for (int reg = 0; reg < 4; ++reg) {
                float at = dd[reg] * 0.25f;        // 1/sqrt(16)
                float mn = fmaxf(m_[nt][reg], at);
                float sc = __expf(m_[nt][reg] - mn);
                float e = __expf(at - mn);
                den_[nt][reg] = den_[nt][reg] * sc + e;
                oa[nt][reg] = oa[nt][reg] * sc + e * va[nt][reg];
                m_[nt][reg] = mn;
            }
        }
    }

    // ---- Phase D: o/den -> A-frags; out-proj; residual; LN2
#pragma unroll
    for (int reg = 0; reg < 4; ++reg) {
        int rloc = R0 + cg * 4 + reg;
        int swz = (rloc & 7) << 4;
#pragma unroll
        for (int nt = 0; nt < 4; ++nt) {
            float ov = oa[nt][reg] / den_[nt][reg];
            int bo = (rloc * 128 + (nt * 16 + cb) * 2) ^ swz;
            storeSplit(Ahi, Alo, bo, ov);
        }
    }
    f32x4 ao[4];
#pragma unroll
    for (int nt = 0; nt < 4; ++nt) { float bo_ = outb[nt * 16 + cb]; ao[nt] = {bo_, bo_, bo_, bo_}; }
    {
        const unsigned short* pO = pk + 2 * OFF_O;
#pragma unroll
        for (int ks = 0; ks < 2; ++ks) {
            bf16x8 ah = readFrag(Ahi, R0, lane, ks, 128, 7);
            bf16x8 al = readFrag(Alo, R0, lane, ks, 128, 7);
#pragma unroll
            for (int nt = 0; nt < 4; ++nt) {
                bf16x8 bh, bl;
                readB(pO, 4096, 4, ks, nt, lane, bh, bl);
                ao[nt] = MFMA_B16(ah, bh, ao[nt]);
                ao[nt] = MFMA_B16(ah, bl, ao[nt]);
                ao[nt] = MFMA_B16(al, bh, ao[nt]);
            }
        }
    }
    float g2[4], b2v[4];
#pragma unroll
    for (int nt = 0; nt < 4; ++nt) { g2[nt] = ln2g[nt * 16 + cb]; b2v[nt] = ln2b[nt * 16 + cb]; }
    float x2[4][4];
#pragma unroll
    for (int reg = 0; reg < 4; ++reg) {
        int rloc = R0 + cg * 4 + reg;
#pragma unroll
        for (int nt = 0; nt < 4; ++nt) x2[reg][nt] = x[reg][nt] + ao[nt][reg];
        float s = x2[reg][0] + x2[reg][1] + x2[reg][2] + x2[reg][3];
#pragma unroll
        for (int m = 1; m < 16; m <<= 1) s += __shfl_xor(s, m, 64);
        float mean = s * (1.0f / 64.0f);
        float d0 = x2[reg][0] - mean, d1 = x2[reg][1] - mean, d2 = x2[reg][2] - mean, d3 = x2[reg][3] - mean;
        float sq = d0 * d0 + d1 * d1 + d2 * d2 + d3 * d3;
#pragma unroll
        for (int m = 1; m < 16; m <<= 1) sq += __shfl_xor(sq, m, 64);
        float rr = rsqrtf(sq * (1.0f / 64.0f) + 1e-5f);
        int swz = (rloc & 7) << 4;
#pragma unroll
        for (int nt = 0; nt < 4; ++nt) {
            float xn = (x2[reg][nt] - mean) * rr * g2[nt] + b2v[nt];
            int bo = (rloc * 128 + (nt * 16 + cb) * 2) ^ swz;
            storeSplit(Ahi, Alo, bo, xn);
        }
    }

    // ---- Phase E: FFN 64->256 (gelu) ->64, 2 chunks of 128 hidden
    const unsigned short* pW1 = pk + 2 * OFF_W1;   // E=16384, NTm=16
    const unsigned short* pW2 = pk + 2 * OFF_W2;   // E=16384, NTm=4, ks 0..7
    f32x4 ya[4];
#pragma unroll
    for (int nt = 0; nt < 4; ++nt) { float by = fb2[nt * 16 + cb]; ya[nt] = {by, by, by, by}; }

#pragma unroll
    for (int cc = 0; cc < 2; ++cc) {
        f32x4 ha[8];
#pragma unroll
        for (int n8 = 0; n8 < 8; ++n8) {
            float hb = fb1[(cc * 8 + n8) * 16 + cb];
            ha[n8] = {hb, hb, hb, hb};
        }
#pragma unroll
        for (int ks = 0; ks < 2; ++ks) {
            bf16x8 ah = readFrag(Ahi, R0, lane, ks, 128, 7);
            bf16x8 al = readFrag(Alo, R0, lane, ks, 128, 7);
#pragma unroll
            for (int n8 = 0; n8 < 8; ++n8) {
                bf16x8 bh, bl;
                readB(pW1, 16384, 16, ks, cc * 8 + n8, lane, bh, bl);
                ha[n8] = MFMA_B16(ah, bh, ha[n8]);
                ha[n8] = MFMA_B16(ah, bl, ha[n8]);
                ha[n8] = MFMA_B16(al, bh, ha[n8]);
            }
        }
        // gelu + split -> H frags (row stride 256 B, swz mask 15)
#pragma unroll
        for (int reg = 0; reg < 4; ++reg) {
            int rloc = R0 + cg * 4 + reg;
            int swz = (rloc & 15) << 4;
#pragma unroll
            for (int n8 = 0; n8 < 8; ++n8) {
                float h = ha[n8][reg];
                h = 0.5f * h * (1.0f + erff(h * 0.70710678118654752f));
                int bo = (rloc * 256 + (n8 * 16 + cb) * 2) ^ swz;
                storeSplit(Hhi, Hlo, bo, h);
            }
        }
        // W2 partial: K-chunk of 128
#pragma unroll
        for (int ks2 = 0; ks2 < 4; ++ks2) {
            bf16x8 ah = readFrag(Hhi, R0, lane, ks2, 256, 15);
            bf16x8 al = readFrag(Hlo, R0, lane, ks2, 256, 15);
            int ksg = cc * 4 + ks2;
#pragma unroll
            for (int nt = 0; nt < 4; ++nt) {
                bf16x8 bh, bl;
                readB(pW2, 16384, 4, ksg, nt, lane, bh, bl);
                ya[nt] = MFMA_B16(ah, bh, ya[nt]);
                ya[nt] = MFMA_B16(ah, bl, ya[nt]);
                ya[nt] = MFMA_B16(al, bh, ya[nt]);
            }
        }
    }

    // ---- final write: fout = x2 + ffn
    float* foutp = fout + ((size_t)(pi * B_ + b) * N_ + nn0) * 64;
#pragma unroll
    for (int reg = 0; reg < 4; ++reg) {
        int rloc = R0 + cg * 4 + reg;
#pragma unroll
        for (int nt = 0; nt < 4; ++nt)
            foutp[(size_t)rloc * 64 + nt * 16 + cb] = x2[reg][nt] + ya[nt][reg];
    }
}

// ---------- output transpose ----------
__global__ __launch_bounds__(256) void output_kernel(const float* __restrict__ f,
                                                     float* __restrict__ out) {
    __shared__ float tile[64][65];
    int blk = blockIdx.x;
    int ntile = blk & 255;
    int bp = blk >> 8;
    int b = bp / 3, p = bp - b * 3;
    int n0 = ntile * 64;
    int tr = threadIdx.x >> 6, tc = threadIdx.x & 63;

    const float* src = f + ((size_t)(p * B_ + b) * N_ + n0) * C_;
#pragma unroll
    for (int it = 0; it < 16; ++it) {
        int r = it * 4 + tr;
        tile[r][tc] = src[(size_t)r * C_ + tc];
    }
    __syncthreads();
    float* dst = out + (size_t)(b * 3 + p) * C_ * N_ + n0;
#pragma unroll
    for (int it = 0; it < 16; ++it) {
        int cidx = it * 4 + tr;
        dst[(size_t)cidx * N_ + tc] = tile[tc][cidx];
    }
}

extern "C" void kernel_launch(void* const* d_in, const int* in_sizes, int n_in,
                              void* d_out, int out_size, void* d_ws, size_t ws_size,
                              hipStream_t stream) {
    const float* img_feats = (const float*)d_in[0];
    const float* pts       = (const float*)d_in[1];
    const float* query     = (const float*)d_in[2];
    const float* ln1_g     = (const float*)d_in[3];
    const float* ln1_b     = (const float*)d_in[4];
    const float* ln2_g     = (const float*)d_in[5];
    const float* ln2_b     = (const float*)d_in[6];
    const float* in_w      = (const float*)d_in[7];
    const float* in_b      = (const float*)d_in[8];
    const float* out_w     = (const float*)d_in[9];
    const float* out_b     = (const float*)d_in[10];
    const float* ffn_w1    = (const float*)d_in[11];
    const float* ffn_b1    = (const float*)d_in[12];
    const float* ffn_w2    = (const float*)d_in[13];
    const float* ffn_b2    = (const float*)d_in[14];

    float* ws = (float*)d_ws;
    const size_t ACC_SZ = (size_t)B_ * 3 * N_ * C_;
    const size_t WACC_SZ = (size_t)B_ * 3 * N_;
    const size_t FEAT_SZ = (size_t)3 * B_ * N_ * C_;
    float* acc  = ws;
    float* wacc = acc + ACC_SZ;
    float* fA   = wacc + WACC_SZ;
    float* fB   = fA + FEAT_SZ;
    // packed weights live in the (dead after splat) acc region
    unsigned short* pk_base = (unsigned short*)acc;

    init_feats<<<(3 * N_ * C_ + 255) / 256, 256, 0, stream>>>(query, fA);

    int zero_n4 = (int)((ACC_SZ + WACC_SZ) / 4);
    for (int v = 0; v < V_; ++v) {
        zero_kernel<<<(zero_n4 + 255) / 256, 256, 0, stream>>>((float4*)acc, zero_n4);
        splat_kernel<<<(B_ * N_) / 4, 256, 0, stream>>>(img_feats, pts, acc, wacc, v);
        norm_add<<<(int)((ACC_SZ + 255) / 256), 256, 0, stream>>>(acc, wacc, fA);
    }

    // pack weights (after splat: acc region is free)
    for (int l = 0; l < NL_; ++l) {
        unsigned short* pkl = pk_base + (size_t)l * LAYER_PK;
        const float* iw = in_w + (size_t)l * 3 * C_ * C_;
        pack_w<<<16, 256, 0, stream>>>(iw,          64, 64,  pkl + 2 * OFF_Q,  pkl + 2 * OFF_Q + 4096);
        pack_w<<<16, 256, 0, stream>>>(iw + 4096,   64, 64,  pkl + 2 * OFF_K,  pkl + 2 * OFF_K + 4096);
        pack_w<<<16, 256, 0, stream>>>(iw + 8192,   64, 64,  pkl + 2 * OFF_V,  pkl + 2 * OFF_V + 4096);
        pack_w<<<16, 256, 0, stream>>>(out_w + (size_t)l * C_ * C_, 64, 64,
                                       pkl + 2 * OFF_O, pkl + 2 * OFF_O + 4096);
        pack_w<<<64, 256, 0, stream>>>(ffn_w1 + (size_t)l * 4 * C_ * C_, 256, 64,
                                       pkl + 2 * OFF_W1, pkl + 2 * OFF_W1 + 16384);
        pack_w<<<64, 256, 0, stream>>>(ffn_w2 + (size_t)l * C_ * 4 * C_, 64, 256,
                                       pkl + 2 * OFF_W2, pkl + 2 * OFF_W2 + 16384);
    }

    dim3 pgrid((B_ * N_) / 64, 3);
    for (int l = 0; l < NL_; ++l) {
        const float* fin = (l == 0) ? fA : fB;
        float* fout      = (l == 0) ? fB : fA;
        plane_mfma<<<pgrid, 256, 0, stream>>>(
            fin, fout, pk_base + (size_t)l * LAYER_PK,
            ln1_g + l * C_, ln1_b + l * C_,
            ln2_g + l * C_, ln2_b + l * C_,
            in_b + l * 3 * C_, out_b + l * C_,
            ffn_b1 + l * 4 * C_, ffn_b2 + l * C_);
    }

    output_kernel<<<B_ * 3 * (N_ / 64), 256, 0, stream>>>(fA, (float*)d_out);
}

// Round 5
// 1078.173 us; speedup vs baseline: 4.5832x; 1.1053x over previous
//
#include <hip/hip_runtime.h>
#include <math.h>

constexpr int R_ = 128, C_ = 64, NL_ = 2, B_ = 2, V_ = 4;
constexpr int N_ = R_ * R_;          // 16384
constexpr int T_ = 6;

typedef __attribute__((ext_vector_type(8))) short bf16x8;
typedef __attribute__((ext_vector_type(4))) float f32x4;
typedef __attribute__((ext_vector_type(4))) unsigned short u16x4;
typedef __attribute__((ext_vector_type(8))) unsigned short u16x8;

#define MFMA_B16(a, b, c) __builtin_amdgcn_mfma_f32_16x16x32_bf16((a), (b), (c), 0, 0, 0)

// packed-weight element offsets (per layer, in elements)
constexpr int OFF_O = 12288, OFF_W1 = 16384, OFF_W2 = 32768;
constexpr int PK_ELEMS = 49152;
constexpr int LAYER_PK = 2 * PK_ELEMS;   // ushorts per layer (hi+lo)

// ---------- helpers ----------
__device__ inline void atomicAddF(float* p, float v) {
    __hip_atomic_fetch_add(p, v, __ATOMIC_RELAXED, __HIP_MEMORY_SCOPE_AGENT);
}

__device__ inline unsigned rne16(float x) {
    unsigned b = __float_as_uint(x);
    return (b + 0x7fffu + ((b >> 16) & 1u)) >> 16;
}

// read A-fragment (16x32 bf16) for wave's M-tile from swizzled LDS
__device__ inline bf16x8 readFrag(const unsigned short* base, int rowBase, int lane,
                                  int ks, int rowStrideB, int swzMask) {
    int rowloc = rowBase + (lane & 15);
    int off = rowloc * rowStrideB + ks * 64 + ((lane >> 4) & 3) * 16;
    off ^= ((rowloc & swzMask) << 4);
    return *(const bf16x8*)((const char*)base + off);
}

// store 4 bf16-hi values (K-permuted: p = cb*4+nt) as one 8B write
__device__ inline void storeA4(unsigned short* base, int rloc, int cb,
                               float v0, float v1, float v2, float v3) {
    u16x4 u;
    u[0] = (unsigned short)rne16(v0);
    u[1] = (unsigned short)rne16(v1);
    u[2] = (unsigned short)rne16(v2);
    u[3] = (unsigned short)rne16(v3);
    int bo = (rloc * 128 + cb * 8) ^ ((rloc & 7) << 4);
    *(u16x4*)((char*)base + bo) = u;
}

// load B-fragment pair (hi,lo) from packed weights
__device__ inline void readB(const unsigned short* matHi, int E, int NTm, int ks, int nt,
                             int lane, bf16x8& bh, bf16x8& bl) {
    int off = (((ks * NTm + nt) << 6) + lane) << 3;
    bh = *(const bf16x8*)(matHi + off);
    bl = *(const bf16x8*)(matHi + E + off);
}

// ---------- pack all weights of one layer (K-permuted, split hi/lo) ----------
__global__ __launch_bounds__(256) void pack_layer(const float* __restrict__ iw,
                                                  const float* __restrict__ ow,
                                                  const float* __restrict__ w1,
                                                  const float* __restrict__ w2,
                                                  unsigned short* __restrict__ pk) {
    int idx = blockIdx.x * 256 + threadIdx.x;
    if (idx >= PK_ELEMS) return;
    const float* W;
    int O, K, base, mode, lidx;
    if (idx < 12288)      { int m = idx >> 12; lidx = idx & 4095; W = iw + m * 4096; O = 64;  K = 64;  base = m * 4096; mode = 0; }
    else if (idx < 16384) { lidx = idx - 12288; W = ow; O = 64;  K = 64;  base = OFF_O;  mode = 0; }
    else if (idx < 32768) { lidx = idx - 16384; W = w1; O = 256; K = 64;  base = OFF_W1; mode = 0; }
    else                  { lidx = idx - 32768; W = w2; O = 64;  K = 256; base = OFF_W2; mode = 1; }
    int j = lidx & 7, l = (lidx >> 3) & 63, rem = lidx >> 9;
    int NTm = O >> 4;
    int nt = rem & (NTm - 1), ks = rem / NTm;
    int kfrag = ks * 32 + ((l >> 4) & 3) * 8 + j;
    int k;
    if (mode == 0) { int p = kfrag & 63; k = (p & 3) * 16 + (p >> 2); }
    else { int cc = kfrag >> 7; int pl = kfrag & 127; k = (cc * 8 + (pl & 7)) * 16 + (pl >> 3); }
    int o = nt * 16 + (l & 15);
    float w = W[(size_t)o * K + k];
    unsigned hb = rne16(w);
    float hf = __uint_as_float(hb << 16);
    unsigned lb = rne16(w - hf);
    int E = O * K;
    pk[2 * base + lidx] = (unsigned short)hb;
    pk[2 * base + E + lidx] = (unsigned short)lb;
}

// ---------- zero workspace region ----------
__global__ __launch_bounds__(256) void zero_kernel(float4* __restrict__ p, int n4) {
    int i = blockIdx.x * 256 + threadIdx.x;
    if (i < n4) p[i] = make_float4(0.f, 0.f, 0.f, 0.f);
}

// ---------- init plane feats with query tensors ----------
__global__ __launch_bounds__(256) void init_feats(const float* __restrict__ q,
                                                  float* __restrict__ f0) {
    int idx = blockIdx.x * 256 + threadIdx.x;
    if (idx >= 3 * N_ * C_) return;
    int p = idx / (N_ * C_);
    int rem = idx - p * (N_ * C_);
    float val = q[idx];
    f0[(size_t)(p * B_ + 0) * N_ * C_ + rem] = val;
    f0[(size_t)(p * B_ + 1) * N_ * C_ + rem] = val;
}

// ---------- splat nv views starting at v0 ----------
__global__ __launch_bounds__(256) void splat_kernel(const float* __restrict__ img_feats,
                                                    const float* __restrict__ pts,
                                                    float* __restrict__ acc,
                                                    float* __restrict__ wacc,
                                                    int v0, size_t accStride, size_t waccStride) {
    int gwave = (blockIdx.x * 256 + threadIdx.x) >> 6;   // [0, nv*B*N)
    int lane = threadIdx.x & 63;
    int vl = gwave >> 15;
    int b = (gwave >> 14) & 1;
    int n = gwave & (N_ - 1);
    int bv = b * V_ + v0 + vl;
    acc += vl * accStride;
    wacc += vl * waccStride;

    const float* p = pts + ((size_t)bv * N_ + n) * 3;
    float px = p[0], py = p[1], pz = p[2];
    float f = img_feats[((size_t)bv * C_ + lane) * N_ + n];

    const float HI = (float)(127.0 - 1e-5);
    float gx = fminf(fmaxf((px + 1.0f) * 127.0f / 2.0f, 0.0f), HI);
    float gy = fminf(fmaxf((py + 1.0f) * 127.0f / 2.0f, 0.0f), HI);
    float gz = fminf(fmaxf((pz + 1.0f) * 127.0f / 2.0f, 0.0f), HI);
    int x0 = (int)gx, y0 = (int)gy, z0 = (int)gz;
    float wx = gx - (float)x0, wy = gy - (float)y0, wz = gz - (float)z0;
    int x1 = x0 + 1 < 128 ? x0 + 1 : 127;
    int y1 = y0 + 1 < 128 ? y0 + 1 : 127;
    int z1 = z0 + 1 < 128 ? z0 + 1 : 127;
    float ax = 1.0f - wx, ay = 1.0f - wy, az = 1.0f - wz;
    float w000 = ax * ay * az;
    float w001 = ax * ay * wz;
    float w010 = ax * wy * az;
    float w100 = wx * ay * az;
    float w110 = wx * wy * az;
    float w111 = wx * wy * wz;

    float* a0 = acc + (size_t)(b * 3 + 0) * N_ * C_;
    float* a1 = acc + (size_t)(b * 3 + 1) * N_ * C_;
    float* a2 = acc + (size_t)(b * 3 + 2) * N_ * C_;
    float* wa0 = wacc + (size_t)(b * 3 + 0) * N_;
    float* wa1 = wacc + (size_t)(b * 3 + 1) * N_;
    float* wa2 = wacc + (size_t)(b * 3 + 2) * N_;

#define SPLAT_ADD(A, WA, IA, IB, W)                                   \
    do {                                                              \
        int cell = (IA) * R_ + (IB);                                  \
        atomicAddF((A) + (size_t)cell * C_ + lane, (W)*f);            \
        if (lane == 0) atomicAddF((WA) + cell, (W));                  \
    } while (0)

    SPLAT_ADD(a0, wa0, x0, y0, w000);
    SPLAT_ADD(a0, wa0, x0, y1, w010);
    SPLAT_ADD(a0, wa0, x1, y0, w100);
    SPLAT_ADD(a0, wa0, x1, y1, w110);

    SPLAT_ADD(a1, wa1, x0, z0, w000);
    SPLAT_ADD(a1, wa1, x0, z1, w001);
    SPLAT_ADD(a1, wa1, x1, z0, w100);
    SPLAT_ADD(a1, wa1, x1, z1, w111);

    SPLAT_ADD(a2, wa2, y0, z0, w000);
    SPLAT_ADD(a2, wa2, y0, z1, w001);
    SPLAT_ADD(a2, wa2, y1, z0, w010);
    SPLAT_ADD(a2, wa2, y1, z1, w111);
#undef SPLAT_ADD
}

// ---------- normalize per-view, sum nv views, add 1/V into feats ----------
__global__ __launch_bounds__(256) void norm_add(const float* __restrict__ acc,
                                                const float* __restrict__ wacc,
                                                float* __restrict__ f0, int nv,
                                                size_t accStride, size_t waccStride) {
    int idx = blockIdx.x * 256 + threadIdx.x;
    if (idx >= B_ * 3 * N_ * C_) return;
    int c = idx & 63;
    int cell = (idx >> 6) & (N_ - 1);
    int bp = idx >> 20;
    int b = bp / 3, p = bp - b * 3;
    float sum = 0.f;
    for (int vl = 0; vl < nv; ++vl) {
        float w = wacc[vl * waccStride + (size_t)bp * N_ + cell];
        sum += acc[vl * accStride + idx] / fmaxf(w, 1e-8f);
    }
    f0[((size_t)(p * B_ + b) * N_ + cell) * C_ + c] += 0.25f * sum;
}

// ---------- fused per-plane transformer layer (MFMA, barrier-free) ----------
__global__ __launch_bounds__(256, 3) void plane_mfma(
    const float* __restrict__ fin, float* __restrict__ fout,
    const unsigned short* __restrict__ pk,
    const float* __restrict__ ln1g, const float* __restrict__ ln1b,
    const float* __restrict__ ln2g, const float* __restrict__ ln2b,
    const float* __restrict__ inb, const float* __restrict__ outb,
    const float* __restrict__ fb1, const float* __restrict__ fb2) {
    __shared__ unsigned short Ahi[64 * 64];      // 8 KB
    __shared__ unsigned short Hhi[64 * 128];     // 16 KB

    const int tid = threadIdx.x;
    const int wid = tid >> 6, lane = tid & 63;
    const int cg = lane >> 4, cb = lane & 15;
    const int pi = blockIdx.y;
    const int R0 = wid * 16;                  // wave's first local row
    const int rowbase = blockIdx.x * 64;      // block's first global row
    const int b = rowbase >> 14;
    const int nn0 = rowbase & (N_ - 1);
    const int i0 = nn0 >> 7, j0 = nn0 & 127;
    const float lin_i = -1.0f + (2.0f * (float)i0) / 127.0f;

    float g1[4], b1v[4];
#pragma unroll
    for (int nt = 0; nt < 4; ++nt) { g1[nt] = ln1g[nt * 16 + cb]; b1v[nt] = ln1b[nt * 16 + cb]; }

    // ---- Phase A: load x, LN1 -> A-frags (wave-private LDS rows)
    const float* finp = fin + ((size_t)(pi * B_ + b) * N_ + nn0) * 64;
#pragma unroll
    for (int reg = 0; reg < 4; ++reg) {
        int rloc = R0 + cg * 4 + reg;
        float x0v = finp[(size_t)rloc * 64 + cb];
        float x1v = finp[(size_t)rloc * 64 + 16 + cb];
        float x2v = finp[(size_t)rloc * 64 + 32 + cb];
        float x3v = finp[(size_t)rloc * 64 + 48 + cb];
        float s = x0v + x1v + x2v + x3v;
#pragma unroll
        for (int m = 1; m < 16; m <<= 1) s += __shfl_xor(s, m, 64);
        float mean = s * (1.0f / 64.0f);
        float d0 = x0v - mean, d1 = x1v - mean, d2 = x2v - mean, d3 = x3v - mean;
        float sq = d0 * d0 + d1 * d1 + d2 * d2 + d3 * d3;
#pragma unroll
        for (int m = 1; m < 16; m <<= 1) sq += __shfl_xor(sq, m, 64);
        float rr = rsqrtf(sq * (1.0f / 64.0f) + 1e-5f);
        storeA4(Ahi, rloc, cb,
                d0 * rr * g1[0] + b1v[0], d1 * rr * g1[1] + b1v[1],
                d2 * rr * g1[2] + b1v[2], d3 * rr * g1[3] + b1v[3]);
    }

    // ---- Phase B: q = xn @ Wq^T + bq
    f32x4 qa[4];
#pragma unroll
    for (int nt = 0; nt < 4; ++nt) { float bq = inb[nt * 16 + cb]; qa[nt] = {bq, bq, bq, bq}; }
    {
        const unsigned short* pQ = pk;
#pragma unroll
        for (int ks = 0; ks < 2; ++ks) {
            bf16x8 ah = readFrag(Ahi, R0, lane, ks, 128, 7);
#pragma unroll
            for (int nt = 0; nt < 4; ++nt) {
                bf16x8 bh, bl;
                readB(pQ, 4096, 4, ks, nt, lane, bh, bl);
                qa[nt] = MFMA_B16(ah, bh, qa[nt]);
                qa[nt] = MFMA_B16(ah, bl, qa[nt]);
            }
        }
    }

    // ---- Phase C: t-loop — gather ctx, LN, k/v MFMA, online softmax (no max, no barriers)
    float kbias[4], vbias[4];
#pragma unroll
    for (int nt = 0; nt < 4; ++nt) { kbias[nt] = inb[64 + nt * 16 + cb]; vbias[nt] = inb[128 + nt * 16 + cb]; }
    float den_[4][4];
    f32x4 oa[4];
#pragma unroll
    for (int nt = 0; nt < 4; ++nt) {
        oa[nt] = {0.f, 0.f, 0.f, 0.f};
#pragma unroll
        for (int reg = 0; reg < 4; ++reg) den_[nt][reg] = 0.f;
    }
    const unsigned short* pK = pk + 2 * 4096;
    const unsigned short* pV = pk + 2 * 8192;

    for (int t = 0; t < T_; ++t) {
        int khalf = (t < 3) ? t : t - 3;
        float sk = (float)(khalf - 1);
        bool tl = (t < 3);
        int io;
        if (pi == 0) io = tl ? 1 : 2;
        else if (pi == 1) io = tl ? 0 : 2;
        else io = tl ? 0 : 1;
        const float* Fio = fin + (size_t)(io * B_ + b) * N_ * 64;

#pragma unroll
        for (int reg = 0; reg < 4; ++reg) {
            int rloc = R0 + cg * 4 + reg;
            float lin_j = -1.0f + (2.0f * (float)(j0 + rloc)) / 127.0f;
            float caf, cbf;
            if (pi == 0) { caf = tl ? lin_j : lin_i; cbf = sk; }
            else if (pi == 1) { if (tl) { caf = lin_j; cbf = sk; } else { caf = sk; cbf = lin_i; } }
            else { caf = sk; cbf = tl ? lin_j : lin_i; }
            float ua = fminf(fmaxf((caf * 0.5f + 0.5f) * 127.0f, 0.0f), 127.0f);
            float ub = fminf(fmaxf((cbf * 0.5f + 0.5f) * 127.0f, 0.0f), 127.0f);
            float gxp = fminf(fmaxf(((ua + 1.0f) * 0.5f) * 127.0f, 0.0f), 127.0f);
            float gyp = fminf(fmaxf(((ub + 1.0f) * 0.5f) * 127.0f, 0.0f), 127.0f);
            int xx0 = (int)gxp, yy0 = (int)gyp;
            int xx1 = xx0 + 1 < 128 ? xx0 + 1 : 127;
            int yy1 = yy0 + 1 < 128 ? yy0 + 1 : 127;
            float wx = gxp - (float)xx0, wyv = gyp - (float)yy0;
            size_t c00 = (size_t)(yy0 * R_ + xx0) * 64, c01 = (size_t)(yy0 * R_ + xx1) * 64;
            size_t c10 = (size_t)(yy1 * R_ + xx0) * 64, c11 = (size_t)(yy1 * R_ + xx1) * 64;
            float cv[4];
#pragma unroll
            for (int nt = 0; nt < 4; ++nt) {
                int ch = nt * 16 + cb;
                float v00 = Fio[c00 + ch], v01 = Fio[c01 + ch];
                float v10 = Fio[c10 + ch], v11 = Fio[c11 + ch];
                cv[nt] = (1.0f - wyv) * ((1.0f - wx) * v00 + wx * v01) +
                         wyv * ((1.0f - wx) * v10 + wx * v11);
            }
            float s = cv[0] + cv[1] + cv[2] + cv[3];
#pragma unroll
            for (int m = 1; m < 16; m <<= 1) s += __shfl_xor(s, m, 64);
            float mean = s * (1.0f / 64.0f);
            float d0 = cv[0] - mean, d1 = cv[1] - mean, d2 = cv[2] - mean, d3 = cv[3] - mean;
            float sq = d0 * d0 + d1 * d1 + d2 * d2 + d3 * d3;
#pragma unroll
            for (int m = 1; m < 16; m <<= 1) sq += __shfl_xor(sq, m, 64);
            float rr = rsqrtf(sq * (1.0f / 64.0f) + 1e-5f);
            storeA4(Ahi, rloc, cb,
                    d0 * rr * g1[0] + b1v[0], d1 * rr * g1[1] + b1v[1],
                    d2 * rr * g1[2] + b1v[2], d3 * rr * g1[3] + b1v[3]);
        }

        // k,v projections via MFMA
        f32x4 ka[4], va[4];
#pragma unroll
        for (int nt = 0; nt < 4; ++nt) {
            ka[nt] = {kbias[nt], kbias[nt], kbias[nt], kbias[nt]};
            va[nt] = {vbias[nt], vbias[nt], vbias[nt], vbias[nt]};
        }
#pragma unroll
        for (int ks = 0; ks < 2; ++ks) {
            bf16x8 ah = readFrag(Ahi, R0, lane, ks, 128, 7);
#pragma unroll
            for (int nt = 0; nt < 4; ++nt) {
                bf16x8 bh, bl;
                readB(pK, 4096, 4, ks, nt, lane, bh, bl);
                ka[nt] = MFMA_B16(ah, bh, ka[nt]);
                ka[nt] = MFMA_B16(ah, bl, ka[nt]);
                readB(pV, 4096, 4, ks, nt, lane, bh, bl);
                va[nt] = MFMA_B16(ah, bh, va[nt]);
                va[nt] = MFMA_B16(ah, bl, va[nt]);
            }
        }

        // scores (head = nt) + online softmax accumulate (no max tracking)
#pragma unroll
        for (int nt = 0; nt < 4; ++nt) {
            float d0 = qa[nt][0] * ka[nt][0];
            float d1 = qa[nt][1] * ka[nt][1];
            float d2 = qa[nt][2] * ka[nt][2];
            float d3 = qa[nt][3] * ka[nt][3];
#pragma unroll
            for (int m = 1; m < 16; m <<= 1) {
                d0 += __shfl_xor(d0, m, 64);
                d1 += __shfl_xor(d1, m, 64);
                d2 += __shfl_xor(d2, m, 64);
                d3 += __shfl_xor(d3, m, 64);
            }
            float e0 = __expf(d0 * 0.25f), e1 = __expf(d1 * 0.25f);
            float e2 = __expf(d2 * 0.25f), e3 = __expf(d3 * 0.25f);
            den_[nt][0] += e0; den_[nt][1] += e1; den_[nt][2] += e2; den_[nt][3] += e3;
            oa[nt][0] += e0 * va[nt][0];
            oa[nt][1] += e1 * va[nt][1];
            oa[nt][2] += e2 * va[nt][2];
            oa[nt][3] += e3 * va[nt][3];
        }
    }

    // ---- Phase D: o/den -> A-frags; out-proj; residual (reload x); LN2
#pragma unroll
    for (int reg = 0; reg < 4; ++reg) {
        int rloc = R0 + cg * 4 + reg;
        storeA4(Ahi, rloc, cb,
                oa[0][reg] / den_[0][reg], oa[1][reg] / den_[1][reg],
                oa[2][reg] / den_[2][reg], oa[3][reg] / den_[3][reg]);
    }
    f32x4 ao[4];
#pragma unroll
    for (int nt = 0; nt < 4; ++nt) { float bo_ = outb[nt * 16 + cb]; ao[nt] = {bo_, bo_, bo_, bo_}; }
    {
        const unsigned short* pO = pk + 2 * OFF_O;
#pragma unroll
        for (int ks = 0; ks < 2; ++ks) {
            bf16x8 ah = readFrag(Ahi, R0, lane, ks, 128, 7);
#pragma unroll
            for (int nt = 0; nt < 4; ++nt) {
                bf16x8 bh, bl;
                readB(pO, 4096, 4, ks, nt, lane, bh, bl);
                ao[nt] = MFMA_B16(ah, bh, ao[nt]);
                ao[nt] = MFMA_B16(ah, bl, ao[nt]);
            }
        }
    }
    float g2[4], b2v[4];
#pragma unroll
    for (int nt = 0; nt < 4; ++nt) { g2[nt] = ln2g[nt * 16 + cb]; b2v[nt] = ln2b[nt * 16 + cb]; }
    float x2[4][4];
#pragma unroll
    for (int reg = 0; reg < 4; ++reg) {
        int rloc = R0 + cg * 4 + reg;
        x2[reg][0] = finp[(size_t)rloc * 64 + cb]       + ao[0][reg];
        x2[reg][1] = finp[(size_t)rloc * 64 + 16 + cb]  + ao[1][reg];
        x2[reg][2] = finp[(size_t)rloc * 64 + 32 + cb]  + ao[2][reg];
        x2[reg][3] = finp[(size_t)rloc * 64 + 48 + cb]  + ao[3][reg];
        float s = x2[reg][0] + x2[reg][1] + x2[reg][2] + x2[reg][3];
#pragma unroll
        for (int m = 1; m < 16; m <<= 1) s += __shfl_xor(s, m, 64);
        float mean = s * (1.0f / 64.0f);
        float d0 = x2[reg][0] - mean, d1 = x2[reg][1] - mean, d2 = x2[reg][2] - mean, d3 = x2[reg][3] - mean;
        float sq = d0 * d0 + d1 * d1 + d2 * d2 + d3 * d3;
#pragma unroll
        for (int m = 1; m < 16; m <<= 1) sq += __shfl_xor(sq, m, 64);
        float rr = rsqrtf(sq * (1.0f / 64.0f) + 1e-5f);
        storeA4(Ahi, rloc, cb,
                d0 * rr * g2[0] + b2v[0], d1 * rr * g2[1] + b2v[1],
                d2 * rr * g2[2] + b2v[2], d3 * rr * g2[3] + b2v[3]);
    }

    // ---- Phase E: FFN 64->256 (gelu) ->64, 2 chunks of 128 hidden
    const unsigned short* pW1 = pk + 2 * OFF_W1;   // E=16384, NTm=16
    const unsigned short* pW2 = pk + 2 * OFF_W2;   // E=16384, NTm=4
    f32x4 ya[4];
#pragma unroll
    for (int nt = 0; nt < 4; ++nt) { float by = fb2[nt * 16 + cb]; ya[nt] = {by, by, by, by}; }

#pragma unroll
    for (int cc = 0; cc < 2; ++cc) {
        f32x4 ha[8];
#pragma unroll
        for (int n8 = 0; n8 < 8; ++n8) {
            float hb = fb1[(cc * 8 + n8) * 16 + cb];
            ha[n8] = {hb, hb, hb, hb};
        }
#pragma unroll
        for (int ks = 0; ks < 2; ++ks) {
            bf16x8 ah = readFrag(Ahi, R0, lane, ks, 128, 7);
#pragma unroll
            for (int n8 = 0; n8 < 8; ++n8) {
                bf16x8 bh, bl;
                readB(pW1, 16384, 16, ks, cc * 8 + n8, lane, bh, bl);
                ha[n8] = MFMA_B16(ah, bh, ha[n8]);
                ha[n8] = MFMA_B16(ah, bl, ha[n8]);
            }
        }
        // gelu -> H frags (K-permuted: p = cb*8 + n8 => one b128 per reg)
#pragma unroll
        for (int reg = 0; reg < 4; ++reg) {
            int rloc = R0 + cg * 4 + reg;
            u16x8 u;
#pragma unroll
            for (int n8 = 0; n8 < 8; ++n8) {
                float h = ha[n8][reg];
                h = 0.5f * h * (1.0f + erff(h * 0.70710678118654752f));
                u[n8] = (unsigned short)rne16(h);
            }
            int bo = (rloc * 256 + cb * 16) ^ ((rloc & 15) << 4);
            *(u16x8*)((char*)Hhi + bo) = u;
        }
        // W2 partial: K-chunk of 128
#pragma unroll
        for (int ks2 = 0; ks2 < 4; ++ks2) {
            bf16x8 ah = readFrag(Hhi, R0, lane, ks2, 256, 15);
            int ksg = cc * 4 + ks2;
#pragma unroll
            for (int nt = 0; nt < 4; ++nt) {
                bf16x8 bh, bl;
                readB(pW2, 16384, 4, ksg, nt, lane, bh, bl);
                ya[nt] = MFMA_B16(ah, bh, ya[nt]);
                ya[nt] = MFMA_B16(ah, bl, ya[nt]);
            }
        }
    }

    // ---- final write: fout = x2 + ffn
    float* foutp = fout + ((size_t)(pi * B_ + b) * N_ + nn0) * 64;
#pragma unroll
    for (int reg = 0; reg < 4; ++reg) {
        int rloc = R0 + cg * 4 + reg;
#pragma unroll
        for (int nt = 0; nt < 4; ++nt)
            foutp[(size_t)rloc * 64 + nt * 16 + cb] = x2[reg][nt] + ya[nt][reg];
    }
}

// ---------- output transpose ----------
__global__ __launch_bounds__(256) void output_kernel(const float* __restrict__ f,
                                                     float* __restrict__ out) {
    __shared__ float tile[64][65];
    int blk = blockIdx.x;
    int ntile = blk & 255;
    int bp = blk >> 8;
    int b = bp / 3, p = bp - b * 3;
    int n0 = ntile * 64;
    int tr = threadIdx.x >> 6, tc = threadIdx.x & 63;

    const float* src = f + ((size_t)(p * B_ + b) * N_ + n0) * C_;
#pragma unroll
    for (int it = 0; it < 16; ++it) {
        int r = it * 4 + tr;
        tile[r][tc] = src[(size_t)r * C_ + tc];
    }
    __syncthreads();
    float* dst = out + (size_t)(b * 3 + p) * C_ * N_ + n0;
#pragma unroll
    for (int it = 0; it < 16; ++it) {
        int cidx = it * 4 + tr;
        dst[(size_t)cidx * N_ + tc] = tile[tc][cidx];
    }
}

extern "C" void kernel_launch(void* const* d_in, const int* in_sizes, int n_in,
                              void* d_out, int out_size, void* d_ws, size_t ws_size,
                              hipStream_t stream) {
    const float* img_feats = (const float*)d_in[0];
    const float* pts       = (const float*)d_in[1];
    const float* query     = (const float*)d_in[2];
    const float* ln1_g     = (const float*)d_in[3];
    const float* ln1_b     = (const float*)d_in[4];
    const float* ln2_g     = (const float*)d_in[5];
    const float* ln2_b     = (const float*)d_in[6];
    const float* in_w      = (const float*)d_in[7];
    const float* in_b      = (const float*)d_in[8];
    const float* out_w     = (const float*)d_in[9];
    const float* out_b     = (const float*)d_in[10];
    const float* ffn_w1    = (const float*)d_in[11];
    const float* ffn_b1    = (const float*)d_in[12];
    const float* ffn_w2    = (const float*)d_in[13];
    const float* ffn_b2    = (const float*)d_in[14];

    float* ws = (float*)d_ws;
    const size_t ACC_SZ = (size_t)B_ * 3 * N_ * C_;   // 6,291,456
    const size_t WACC_SZ = (size_t)B_ * 3 * N_;       //    98,304
    const size_t FEAT_SZ = (size_t)3 * B_ * N_ * C_;  // 6,291,456

    const size_t need_par = (4 * ACC_SZ + 4 * WACC_SZ + 2 * FEAT_SZ) * 4;
    bool par = ws_size >= need_par;
    int nv = par ? 4 : 1;

    float* acc  = ws;
    float* wacc = acc + (size_t)nv * ACC_SZ;
    float* fA   = wacc + (size_t)nv * WACC_SZ;
    float* fB   = fA + FEAT_SZ;
    unsigned short* pk_base = (unsigned short*)acc;   // reused after norm_add

    init_feats<<<(3 * N_ * C_ + 255) / 256, 256, 0, stream>>>(query, fA);

    int zero_n4 = (int)((nv * (ACC_SZ + WACC_SZ)) / 4);
    int zero_blocks = (zero_n4 + 255) / 256;
    int norm_blocks = (int)((B_ * 3 * N_ * (size_t)C_ + 255) / 256);
    if (par) {
        zero_kernel<<<zero_blocks, 256, 0, stream>>>((float4*)acc, zero_n4);
        splat_kernel<<<(4 * B_ * N_) / 4, 256, 0, stream>>>(img_feats, pts, acc, wacc,
                                                            0, ACC_SZ, WACC_SZ);
        norm_add<<<norm_blocks, 256, 0, stream>>>(acc, wacc, fA, 4, ACC_SZ, WACC_SZ);
    } else {
        for (int v = 0; v < V_; ++v) {
            zero_kernel<<<zero_blocks, 256, 0, stream>>>((float4*)acc, zero_n4);
            splat_kernel<<<(B_ * N_) / 4, 256, 0, stream>>>(img_feats, pts, acc, wacc,
                                                            v, 0, 0);
            norm_add<<<norm_blocks, 256, 0, stream>>>(acc, wacc, fA, 1, 0, 0);
        }
    }

    // pack weights (acc region is dead now)
    for (int l = 0; l < NL_; ++l) {
        pack_layer<<<(PK_ELEMS + 255) / 256, 256, 0, stream>>>(
            in_w + (size_t)l * 3 * C_ * C_, out_w + (size_t)l * C_ * C_,
            ffn_w1 + (size_t)l * 4 * C_ * C_, ffn_w2 + (size_t)l * C_ * 4 * C_,
            pk_base + (size_t)l * LAYER_PK);
    }

    dim3 pgrid((B_ * N_) / 64, 3);
    for (int l = 0; l < NL_; ++l) {
        const float* fin = (l == 0) ? fA : fB;
        float* fout      = (l == 0) ? fB : fA;
        plane_mfma<<<pgrid, 256, 0, stream>>>(
            fin, fout, pk_base + (size_t)l * LAYER_PK,
            ln1_g + l * C_, ln1_b + l * C_,
            ln2_g + l * C_, ln2_b + l * C_,
            in_b + l * 3 * C_, out_b + l * C_,
            ffn_b1 + l * 4 * C_, ffn_b2 + l * C_);
    }

    output_kernel<<<B_ * 3 * (N_ / 64), 256, 0, stream>>>(fA, (float*)d_out);
}

// Round 6
// 917.887 us; speedup vs baseline: 5.3835x; 1.1746x over previous
//
#include <hip/hip_runtime.h>
#include <math.h>

constexpr int R_ = 128, C_ = 64, NL_ = 2, B_ = 2, V_ = 4;
constexpr int N_ = R_ * R_;          // 16384
constexpr int T_ = 6;

typedef __attribute__((ext_vector_type(8))) short bf16x8;
typedef __attribute__((ext_vector_type(4))) float f32x4;
typedef __attribute__((ext_vector_type(4))) unsigned short u16x4;
typedef __attribute__((ext_vector_type(8))) unsigned short u16x8;

#define MFMA_B16(a, b, c) __builtin_amdgcn_mfma_f32_16x16x32_bf16((a), (b), (c), 0, 0, 0)

// packed-weight element offsets (per layer, in elements)
constexpr int OFF_O = 12288, OFF_W1 = 16384, OFF_W2 = 32768;
constexpr int PK_ELEMS = 49152;
constexpr int LAYER_PK = 2 * PK_ELEMS;   // ushorts per layer (hi+lo)

// splat-path sizes
constexpr int NBV = B_ * V_;                       // 8
constexpr size_t FTR_SZ = (size_t)NBV * N_ * C_;   // 8,388,608 floats
constexpr size_t REC_F  = (size_t)NBV * N_ * 4;    // 524,288 floats (float4 recs)
constexpr int NSEG = 3 * NBV;                      // 24 segments
constexpr size_t SEG_SZ = (size_t)NSEG * N_;       // 393,216 ints

// ---------- helpers ----------
__device__ inline unsigned rne16(float x) {
    unsigned b = __float_as_uint(x);
    return (b + 0x7fffu + ((b >> 16) & 1u)) >> 16;
}

// read A-fragment (16x32 bf16) for wave's M-tile from swizzled LDS
__device__ inline bf16x8 readFrag(const unsigned short* base, int rowBase, int lane,
                                  int ks, int rowStrideB, int swzMask) {
    int rowloc = rowBase + (lane & 15);
    int off = rowloc * rowStrideB + ks * 64 + ((lane >> 4) & 3) * 16;
    off ^= ((rowloc & swzMask) << 4);
    return *(const bf16x8*)((const char*)base + off);
}

// store 4 bf16-hi values (K-permuted: p = cb*4+nt) as one 8B write
__device__ inline void storeA4(unsigned short* base, int rloc, int cb,
                               float v0, float v1, float v2, float v3) {
    u16x4 u;
    u[0] = (unsigned short)rne16(v0);
    u[1] = (unsigned short)rne16(v1);
    u[2] = (unsigned short)rne16(v2);
    u[3] = (unsigned short)rne16(v3);
    int bo = (rloc * 128 + cb * 8) ^ ((rloc & 7) << 4);
    *(u16x4*)((char*)base + bo) = u;
}

// load B-fragment pair (hi,lo) from packed weights
__device__ inline void readB(const unsigned short* matHi, int E, int NTm, int ks, int nt,
                             int lane, bf16x8& bh, bf16x8& bl) {
    int off = (((ks * NTm + nt) << 6) + lane) << 3;
    bh = *(const bf16x8*)(matHi + off);
    bl = *(const bf16x8*)(matHi + E + off);
}

// ---------- pack all weights of one layer (K-permuted, split hi/lo) ----------
__global__ __launch_bounds__(256) void pack_layer(const float* __restrict__ iw,
                                                  const float* __restrict__ ow,
                                                  const float* __restrict__ w1,
                                                  const float* __restrict__ w2,
                                                  unsigned short* __restrict__ pk) {
    int idx = blockIdx.x * 256 + threadIdx.x;
    if (idx >= PK_ELEMS) return;
    const float* W;
    int O, K, base, mode, lidx;
    if (idx < 12288)      { int m = idx >> 12; lidx = idx & 4095; W = iw + m * 4096; O = 64;  K = 64;  base = m * 4096; mode = 0; }
    else if (idx < 16384) { lidx = idx - 12288; W = ow; O = 64;  K = 64;  base = OFF_O;  mode = 0; }
    else if (idx < 32768) { lidx = idx - 16384; W = w1; O = 256; K = 64;  base = OFF_W1; mode = 0; }
    else                  { lidx = idx - 32768; W = w2; O = 64;  K = 256; base = OFF_W2; mode = 1; }
    int j = lidx & 7, l = (lidx >> 3) & 63, rem = lidx >> 9;
    int NTm = O >> 4;
    int nt = rem & (NTm - 1), ks = rem / NTm;
    int kfrag = ks * 32 + ((l >> 4) & 3) * 8 + j;
    int k;
    if (mode == 0) { int p = kfrag & 63; k = (p & 3) * 16 + (p >> 2); }
    else { int cc = kfrag >> 7; int pl = kfrag & 127; k = (cc * 8 + (pl & 7)) * 16 + (pl >> 3); }
    int o = nt * 16 + (l & 15);
    float w = W[(size_t)o * K + k];
    unsigned hb = rne16(w);
    float hf = __uint_as_float(hb << 16);
    unsigned lb = rne16(w - hf);
    int E = O * K;
    pk[2 * base + lidx] = (unsigned short)hb;
    pk[2 * base + E + lidx] = (unsigned short)lb;
}

// ---------- init plane feats with query tensors ----------
__global__ __launch_bounds__(256) void init_feats(const float* __restrict__ q,
                                                  float* __restrict__ f0) {
    int idx = blockIdx.x * 256 + threadIdx.x;
    if (idx >= 3 * N_ * C_) return;
    int p = idx / (N_ * C_);
    int rem = idx - p * (N_ * C_);
    float val = q[idx];
    f0[(size_t)(p * B_ + 0) * N_ * C_ + rem] = val;
    f0[(size_t)(p * B_ + 1) * N_ * C_ + rem] = val;
}

// ---------- zero bin counts ----------
__global__ __launch_bounds__(256) void zero_counts(int4* __restrict__ p, int n4) {
    int i = blockIdx.x * 256 + threadIdx.x;
    if (i < n4) p[i] = make_int4(0, 0, 0, 0);
}

// ---------- transpose features: [bv][c][n] -> [bv][n][c] ----------
__global__ __launch_bounds__(256) void transpose_feats(const float* __restrict__ src,
                                                       float* __restrict__ dst) {
    __shared__ float tile[64][65];
    int blk = blockIdx.x;             // NBV * 256
    int ntile = blk & 255;
    int bv = blk >> 8;
    int n0 = ntile * 64;
    int tr = threadIdx.x >> 6, tc = threadIdx.x & 63;
    const float* s = src + (size_t)bv * C_ * N_;
#pragma unroll
    for (int it = 0; it < 16; ++it) {
        int c = it * 4 + tr;
        tile[c][tc] = s[(size_t)c * N_ + n0 + tc];
    }
    __syncthreads();
    float* d = dst + ((size_t)bv * N_ + n0) * C_;
#pragma unroll
    for (int it = 0; it < 16; ++it) {
        int r = it * 4 + tr;
        d[(size_t)r * C_ + tc] = tile[tc][r];
    }
}

// ---------- bin count + per-point record ----------
__global__ __launch_bounds__(256) void bin_count(const float* __restrict__ pts,
                                                 float4* __restrict__ recs,
                                                 int* __restrict__ counts) {
    int idx = blockIdx.x * 256 + threadIdx.x;     // [0, NBV*N)
    if (idx >= NBV * N_) return;
    int bv = idx >> 14;
    const float* p = pts + (size_t)idx * 3;
    float px = p[0], py = p[1], pz = p[2];
    const float HI = (float)(127.0 - 1e-5);
    float gx = fminf(fmaxf((px + 1.0f) * 127.0f / 2.0f, 0.0f), HI);
    float gy = fminf(fmaxf((py + 1.0f) * 127.0f / 2.0f, 0.0f), HI);
    float gz = fminf(fmaxf((pz + 1.0f) * 127.0f / 2.0f, 0.0f), HI);
    int x0 = (int)gx, y0 = (int)gy, z0 = (int)gz;
    float wx = gx - (float)x0, wy = gy - (float)y0, wz = gz - (float)z0;
    float4 r;
    r.x = __uint_as_float((unsigned)(x0 | (y0 << 8) | (z0 << 16)));
    r.y = wx; r.z = wy; r.w = wz;
    recs[idx] = r;
    atomicAdd(&counts[(0 * NBV + bv) * N_ + x0 * R_ + y0], 1);
    atomicAdd(&counts[(1 * NBV + bv) * N_ + x0 * R_ + z0], 1);
    atomicAdd(&counts[(2 * NBV + bv) * N_ + y0 * R_ + z0], 1);
}

// ---------- per-segment exclusive scan (16384 bins each) ----------
__global__ __launch_bounds__(256) void scan_bins(const int* __restrict__ counts,
                                                 int* __restrict__ offsets,
                                                 int* __restrict__ cursors) {
    __shared__ int part[256];
    int seg = blockIdx.x;             // 24
    int t = threadIdx.x;
    const int* c = counts + (size_t)seg * N_;
    int sum = 0;
    for (int i = 0; i < 64; ++i) sum += c[t * 64 + i];
    part[t] = sum;
    __syncthreads();
    if (t == 0) {
        int run = 0;
        for (int i = 0; i < 256; ++i) { int v = part[i]; part[i] = run; run += v; }
    }
    __syncthreads();
    int run = part[t];
    int* o = offsets + (size_t)seg * N_;
    int* cu = cursors + (size_t)seg * N_;
    for (int i = 0; i < 64; ++i) {
        o[t * 64 + i] = run;
        cu[t * 64 + i] = run;
        run += c[t * 64 + i];
    }
}

// ---------- scatter point indices into bins ----------
__global__ __launch_bounds__(256) void scatter_idx(const float4* __restrict__ recs,
                                                   int* __restrict__ cursors,
                                                   int* __restrict__ idxlist) {
    int idx = blockIdx.x * 256 + threadIdx.x;
    if (idx >= NBV * N_) return;
    int bv = idx >> 14, n = idx & (N_ - 1);
    unsigned pc = __float_as_uint(recs[idx].x);
    int x0 = pc & 255, y0 = (pc >> 8) & 255, z0 = (pc >> 16) & 255;
    int s0 = (0 * NBV + bv) * N_;
    int s1 = (1 * NBV + bv) * N_;
    int s2 = (2 * NBV + bv) * N_;
    int p0 = atomicAdd(&cursors[s0 + x0 * R_ + y0], 1);
    idxlist[s0 + p0] = n;
    int p1 = atomicAdd(&cursors[s1 + x0 * R_ + z0], 1);
    idxlist[s1 + p1] = n;
    int p2 = atomicAdd(&cursors[s2 + y0 * R_ + z0], 1);
    idxlist[s2 + p2] = n;
}

// ---------- gather splat: one wave per (plane, b, cell), all 4 views ----------
__global__ __launch_bounds__(256) void gather_splat(
    const float* __restrict__ ftr, const float4* __restrict__ recs,
    const int* __restrict__ counts, const int* __restrict__ offsets,
    const int* __restrict__ idxlist, float* __restrict__ f0) {
    int wid = threadIdx.x >> 6, lane = threadIdx.x & 63;
    int cell = blockIdx.x * 4 + wid;          // [0, N)
    int pi = blockIdx.y, b = blockIdx.z;
    int a = cell >> 7, c = cell & 127;

    float total = 0.f;
#pragma unroll
    for (int v = 0; v < V_; ++v) {
        int bv = b * V_ + v;
        int seg = pi * NBV + bv;
        const int* segoff = offsets + (size_t)seg * N_;
        const int* segcnt = counts + (size_t)seg * N_;
        const int* seglst = idxlist + (size_t)seg * N_;
        const float* fbase = ftr + (size_t)bv * N_ * C_;
        float facc = 0.f, wsum = 0.f;
#pragma unroll
        for (int d = 0; d < 4; ++d) {
            int ba = a - (d >> 1), bc = c - (d & 1);
            if (ba < 0 || bc < 0) continue;
            int bin = ba * R_ + bc;
            int off = segoff[bin], cnt = segcnt[bin];
            for (int i = 0; i < cnt; ++i) {
                int n = seglst[off + i];
                float4 r = recs[(size_t)bv * N_ + n];
                unsigned pc = __float_as_uint(r.x);
                int x0 = pc & 255, y0 = (pc >> 8) & 255, z0 = (pc >> 16) & 255;
                float wx = r.y, wy = r.z, wz = r.w;
                float ax = 1.f - wx, ay = 1.f - wy, az = 1.f - wz;
                int x1 = x0 + 1, y1 = y0 + 1, z1 = z0 + 1;
                float wtot = 0.f;
                if (pi == 0) {
                    if (x0 == a && y0 == c) wtot += ax * ay * az;
                    if (x0 == a && y1 == c) wtot += ax * wy * az;
                    if (x1 == a && y0 == c) wtot += wx * ay * az;
                    if (x1 == a && y1 == c) wtot += wx * wy * az;
                } else if (pi == 1) {
                    if (x0 == a && z0 == c) wtot += ax * ay * az;
                    if (x0 == a && z1 == c) wtot += ax * ay * wz;
                    if (x1 == a && z0 == c) wtot += wx * ay * az;
                    if (x1 == a && z1 == c) wtot += wx * wy * wz;
                } else {
                    if (y0 == a && z0 == c) wtot += ax * ay * az;
                    if (y0 == a && z1 == c) wtot += ax * ay * wz;
                    if (y1 == a && z0 == c) wtot += ax * wy * az;
                    if (y1 == a && z1 == c) wtot += wx * wy * wz;
                }
                facc += wtot * fbase[(size_t)n * C_ + lane];
                wsum += wtot;
            }
        }
        total += facc / fmaxf(wsum, 1e-8f);
    }
    f0[(((size_t)(pi * B_ + b)) * N_ + cell) * C_ + lane] += 0.25f * total;
}

// ---------- fused per-plane transformer layer (MFMA, barrier-free) ----------
__global__ __launch_bounds__(256, 3) void plane_mfma(
    const float* __restrict__ fin, float* __restrict__ fout,
    const unsigned short* __restrict__ pk,
    const float* __restrict__ ln1g, const float* __restrict__ ln1b,
    const float* __restrict__ ln2g, const float* __restrict__ ln2b,
    const float* __restrict__ inb, const float* __restrict__ outb,
    const float* __restrict__ fb1, const float* __restrict__ fb2) {
    __shared__ unsigned short Ahi[64 * 64];      // 8 KB
    __shared__ unsigned short Hhi[64 * 128];     // 16 KB

    const int tid = threadIdx.x;
    const int wid = tid >> 6, lane = tid & 63;
    const int cg = lane >> 4, cb = lane & 15;
    const int pi = blockIdx.y;
    const int R0 = wid * 16;                  // wave's first local row
    const int rowbase = blockIdx.x * 64;      // block's first global row
    const int b = rowbase >> 14;
    const int nn0 = rowbase & (N_ - 1);
    const int i0 = nn0 >> 7, j0 = nn0 & 127;
    const float lin_i = -1.0f + (2.0f * (float)i0) / 127.0f;

    float g1[4], b1v[4];
#pragma unroll
    for (int nt = 0; nt < 4; ++nt) { g1[nt] = ln1g[nt * 16 + cb]; b1v[nt] = ln1b[nt * 16 + cb]; }

    // ---- Phase A: load x, LN1 -> A-frags (wave-private LDS rows)
    const float* finp = fin + ((size_t)(pi * B_ + b) * N_ + nn0) * 64;
#pragma unroll
    for (int reg = 0; reg < 4; ++reg) {
        int rloc = R0 + cg * 4 + reg;
        float x0v = finp[(size_t)rloc * 64 + cb];
        float x1v = finp[(size_t)rloc * 64 + 16 + cb];
        float x2v = finp[(size_t)rloc * 64 + 32 + cb];
        float x3v = finp[(size_t)rloc * 64 + 48 + cb];
        float s = x0v + x1v + x2v + x3v;
#pragma unroll
        for (int m = 1; m < 16; m <<= 1) s += __shfl_xor(s, m, 64);
        float mean = s * (1.0f / 64.0f);
        float d0 = x0v - mean, d1 = x1v - mean, d2 = x2v - mean, d3 = x3v - mean;
        float sq = d0 * d0 + d1 * d1 + d2 * d2 + d3 * d3;
#pragma unroll
        for (int m = 1; m < 16; m <<= 1) sq += __shfl_xor(sq, m, 64);
        float rr = rsqrtf(sq * (1.0f / 64.0f) + 1e-5f);
        storeA4(Ahi, rloc, cb,
                d0 * rr * g1[0] + b1v[0], d1 * rr * g1[1] + b1v[1],
                d2 * rr * g1[2] + b1v[2], d3 * rr * g1[3] + b1v[3]);
    }

    // ---- Phase B: q = xn @ Wq^T + bq
    f32x4 qa[4];
#pragma unroll
    for (int nt = 0; nt < 4; ++nt) { float bq = inb[nt * 16 + cb]; qa[nt] = {bq, bq, bq, bq}; }
    {
        const unsigned short* pQ = pk;
#pragma unroll
        for (int ks = 0; ks < 2; ++ks) {
            bf16x8 ah = readFrag(Ahi, R0, lane, ks, 128, 7);
#pragma unroll
            for (int nt = 0; nt < 4; ++nt) {
                bf16x8 bh, bl;
                readB(pQ, 4096, 4, ks, nt, lane, bh, bl);
                qa[nt] = MFMA_B16(ah, bh, qa[nt]);
                qa[nt] = MFMA_B16(ah, bl, qa[nt]);
            }
        }
    }

    // ---- Phase C: t-loop — gather ctx, LN, k/v MFMA, online softmax (no max, no barriers)
    float kbias[4], vbias[4];
#pragma unroll
    for (int nt = 0; nt < 4; ++nt) { kbias[nt] = inb[64 + nt * 16 + cb]; vbias[nt] = inb[128 + nt * 16 + cb]; }
    float den_[4][4];
    f32x4 oa[4];
#pragma unroll
    for (int nt = 0; nt < 4; ++nt) {
        oa[nt] = {0.f, 0.f, 0.f, 0.f};
#pragma unroll
        for (int reg = 0; reg < 4; ++reg) den_[nt][reg] = 0.f;
    }
    const unsigned short* pK = pk + 2 * 4096;
    const unsigned short* pV = pk + 2 * 8192;

    for (int t = 0; t < T_; ++t) {
        int khalf = (t < 3) ? t : t - 3;
        float sk = (float)(khalf - 1);
        bool tl = (t < 3);
        int io;
        if (pi == 0) io = tl ? 1 : 2;
        else if (pi == 1) io = tl ? 0 : 2;
        else io = tl ? 0 : 1;
        const float* Fio = fin + (size_t)(io * B_ + b) * N_ * 64;

#pragma unroll
        for (int reg = 0; reg < 4; ++reg) {
            int rloc = R0 + cg * 4 + reg;
            float lin_j = -1.0f + (2.0f * (float)(j0 + rloc)) / 127.0f;
            float caf, cbf;
            if (pi == 0) { caf = tl ? lin_j : lin_i; cbf = sk; }
            else if (pi == 1) { if (tl) { caf = lin_j; cbf = sk; } else { caf = sk; cbf = lin_i; } }
            else { caf = sk; cbf = tl ? lin_j : lin_i; }
            float ua = fminf(fmaxf((caf * 0.5f + 0.5f) * 127.0f, 0.0f), 127.0f);
            float ub = fminf(fmaxf((cbf * 0.5f + 0.5f) * 127.0f, 0.0f), 127.0f);
            float gxp = fminf(fmaxf(((ua + 1.0f) * 0.5f) * 127.0f, 0.0f), 127.0f);
            float gyp = fminf(fmaxf(((ub + 1.0f) * 0.5f) * 127.0f, 0.0f), 127.0f);
            int xx0 = (int)gxp, yy0 = (int)gyp;
            int xx1 = xx0 + 1 < 128 ? xx0 + 1 : 127;
            int yy1 = yy0 + 1 < 128 ? yy0 + 1 : 127;
            float wx = gxp - (float)xx0, wyv = gyp - (float)yy0;
            size_t c00 = (size_t)(yy0 * R_ + xx0) * 64, c01 = (size_t)(yy0 * R_ + xx1) * 64;
            size_t c10 = (size_t)(yy1 * R_ + xx0) * 64, c11 = (size_t)(yy1 * R_ + xx1) * 64;
            float cv[4];
#pragma unroll
            for (int nt = 0; nt < 4; ++nt) {
                int ch = nt * 16 + cb;
                float v00 = Fio[c00 + ch], v01 = Fio[c01 + ch];
                float v10 = Fio[c10 + ch], v11 = Fio[c11 + ch];
                cv[nt] = (1.0f - wyv) * ((1.0f - wx) * v00 + wx * v01) +
                         wyv * ((1.0f - wx) * v10 + wx * v11);
            }
            float s = cv[0] + cv[1] + cv[2] + cv[3];
#pragma unroll
            for (int m = 1; m < 16; m <<= 1) s += __shfl_xor(s, m, 64);
            float mean = s * (1.0f / 64.0f);
            float d0 = cv[0] - mean, d1 = cv[1] - mean, d2 = cv[2] - mean, d3 = cv[3] - mean;
            float sq = d0 * d0 + d1 * d1 + d2 * d2 + d3 * d3;
#pragma unroll
            for (int m = 1; m < 16; m <<= 1) sq += __shfl_xor(sq, m, 64);
            float rr = rsqrtf(sq * (1.0f / 64.0f) + 1e-5f);
            storeA4(Ahi, rloc, cb,
                    d0 * rr * g1[0] + b1v[0], d1 * rr * g1[1] + b1v[1],
                    d2 * rr * g1[2] + b1v[2], d3 * rr * g1[3] + b1v[3]);
        }

        // k,v projections via MFMA
        f32x4 ka[4], va[4];
#pragma unroll
        for (int nt = 0; nt < 4; ++nt) {
            ka[nt] = {kbias[nt], kbias[nt], kbias[nt], kbias[nt]};
            va[nt] = {vbias[nt], vbias[nt], vbias[nt], vbias[nt]};
        }
#pragma unroll
        for (int ks = 0; ks < 2; ++ks) {
            bf16x8 ah = readFrag(Ahi, R0, lane, ks, 128, 7);
#pragma unroll
            for (int nt = 0; nt < 4; ++nt) {
                bf16x8 bh, bl;
                readB(pK, 4096, 4, ks, nt, lane, bh, bl);
                ka[nt] = MFMA_B16(ah, bh, ka[nt]);
                ka[nt] = MFMA_B16(ah, bl, ka[nt]);
                readB(pV, 4096, 4, ks, nt, lane, bh, bl);
                va[nt] = MFMA_B16(ah, bh, va[nt]);
                va[nt] = MFMA_B16(ah, bl, va[nt]);
            }
        }

        // scores (head = nt) + online softmax accumulate (no max tracking)
#pragma unroll
        for (int nt = 0; nt < 4; ++nt) {
            float d0 = qa[nt][0] * ka[nt][0];
            float d1 = qa[nt][1] * ka[nt][1];
            float d2 = qa[nt][2] * ka[nt][2];
            float d3 = qa[nt][3] * ka[nt][3];
#pragma unroll
            for (int m = 1; m < 16; m <<= 1) {
                d0 += __shfl_xor(d0, m, 64);
                d1 += __shfl_xor(d1, m, 64);
                d2 += __shfl_xor(d2, m, 64);
                d3 += __shfl_xor(d3, m, 64);
            }
            float e0 = __expf(d0 * 0.25f), e1 = __expf(d1 * 0.25f);
            float e2 = __expf(d2 * 0.25f), e3 = __expf(d3 * 0.25f);
            den_[nt][0] += e0; den_[nt][1] += e1; den_[nt][2] += e2; den_[nt][3] += e3;
            oa[nt][0] += e0 * va[nt][0];
            oa[nt][1] += e1 * va[nt][1];
            oa[nt][2] += e2 * va[nt][2];
            oa[nt][3] += e3 * va[nt][3];
        }
    }

    // ---- Phase D: o/den -> A-frags; out-proj; residual (reload x); LN2
#pragma unroll
    for (int reg = 0; reg < 4; ++reg) {
        int rloc = R0 + cg * 4 + reg;
        storeA4(Ahi, rloc, cb,
                oa[0][reg] / den_[0][reg], oa[1][reg] / den_[1][reg],
                oa[2][reg] / den_[2][reg], oa[3][reg] / den_[3][reg]);
    }
    f32x4 ao[4];
#pragma unroll
    for (int nt = 0; nt < 4; ++nt) { float bo_ = outb[nt * 16 + cb]; ao[nt] = {bo_, bo_, bo_, bo_}; }
    {
        const unsigned short* pO = pk + 2 * OFF_O;
#pragma unroll
        for (int ks = 0; ks < 2; ++ks) {
            bf16x8 ah = readFrag(Ahi, R0, lane, ks, 128, 7);
#pragma unroll
            for (int nt = 0; nt < 4; ++nt) {
                bf16x8 bh, bl;
                readB(pO, 4096, 4, ks, nt, lane, bh, bl);
                ao[nt] = MFMA_B16(ah, bh, ao[nt]);
                ao[nt] = MFMA_B16(ah, bl, ao[nt]);
            }
        }
    }
    float g2[4], b2v[4];
#pragma unroll
    for (int nt = 0; nt < 4; ++nt) { g2[nt] = ln2g[nt * 16 + cb]; b2v[nt] = ln2b[nt * 16 + cb]; }
    float x2[4][4];
#pragma unroll
    for (int reg = 0; reg < 4; ++reg) {
        int rloc = R0 + cg * 4 + reg;
        x2[reg][0] = finp[(size_t)rloc * 64 + cb]       + ao[0][reg];
        x2[reg][1] = finp[(size_t)rloc * 64 + 16 + cb]  + ao[1][reg];
        x2[reg][2] = finp[(size_t)rloc * 64 + 32 + cb]  + ao[2][reg];
        x2[reg][3] = finp[(size_t)rloc * 64 + 48 + cb]  + ao[3][reg];
        float s = x2[reg][0] + x2[reg][1] + x2[reg][2] + x2[reg][3];
#pragma unroll
        for (int m = 1; m < 16; m <<= 1) s += __shfl_xor(s, m, 64);
        float mean = s * (1.0f / 64.0f);
        float d0 = x2[reg][0] - mean, d1 = x2[reg][1] - mean, d2 = x2[reg][2] - mean, d3 = x2[reg][3] - mean;
        float sq = d0 * d0 + d1 * d1 + d2 * d2 + d3 * d3;
#pragma unroll
        for (int m = 1; m < 16; m <<= 1) sq += __shfl_xor(sq, m, 64);
        float rr = rsqrtf(sq * (1.0f / 64.0f) + 1e-5f);
        storeA4(Ahi, rloc, cb,
                d0 * rr * g2[0] + b2v[0], d1 * rr * g2[1] + b2v[1],
                d2 * rr * g2[2] + b2v[2], d3 * rr * g2[3] + b2v[3]);
    }

    // ---- Phase E: FFN 64->256 (gelu) ->64, 2 chunks of 128 hidden
    const unsigned short* pW1 = pk + 2 * OFF_W1;   // E=16384, NTm=16
    const unsigned short* pW2 = pk + 2 * OFF_W2;   // E=16384, NTm=4
    f32x4 ya[4];
#pragma unroll
    for (int nt = 0; nt < 4; ++nt) { float by = fb2[nt * 16 + cb]; ya[nt] = {by, by, by, by}; }

#pragma unroll
    for (int cc = 0; cc < 2; ++cc) {
        f32x4 ha[8];
#pragma unroll
        for (int n8 = 0; n8 < 8; ++n8) {
            float hb = fb1[(cc * 8 + n8) * 16 + cb];
            ha[n8] = {hb, hb, hb, hb};
        }
#pragma unroll
        for (int ks = 0; ks < 2; ++ks) {
            bf16x8 ah = readFrag(Ahi, R0, lane, ks, 128, 7);
#pragma unroll
            for (int n8 = 0; n8 < 8; ++n8) {
                bf16x8 bh, bl;
                readB(pW1, 16384, 16, ks, cc * 8 + n8, lane, bh, bl);
                ha[n8] = MFMA_B16(ah, bh, ha[n8]);
                ha[n8] = MFMA_B16(ah, bl, ha[n8]);
            }
        }
        // gelu -> H frags (K-permuted: p = cb*8 + n8 => one b128 per reg)
#pragma unroll
        for (int reg = 0; reg < 4; ++reg) {
            int rloc = R0 + cg * 4 + reg;
            u16x8 u;
#pragma unroll
            for (int n8 = 0; n8 < 8; ++n8) {
                float h = ha[n8][reg];
                h = 0.5f * h * (1.0f + erff(h * 0.70710678118654752f));
                u[n8] = (unsigned short)rne16(h);
            }
            int bo = (rloc * 256 + cb * 16) ^ ((rloc & 15) << 4);
            *(u16x8*)((char*)Hhi + bo) = u;
        }
        // W2 partial: K-chunk of 128
#pragma unroll
        for (int ks2 = 0; ks2 < 4; ++ks2) {
            bf16x8 ah = readFrag(Hhi, R0, lane, ks2, 256, 15);
            int ksg = cc * 4 + ks2;
#pragma unroll
            for (int nt = 0; nt < 4; ++nt) {
                bf16x8 bh, bl;
                readB(pW2, 16384, 4, ksg, nt, lane, bh, bl);
                ya[nt] = MFMA_B16(ah, bh, ya[nt]);
                ya[nt] = MFMA_B16(ah, bl, ya[nt]);
            }
        }
    }

    // ---- final write: fout = x2 + ffn
    float* foutp = fout + ((size_t)(pi * B_ + b) * N_ + nn0) * 64;
#pragma unroll
    for (int reg = 0; reg < 4; ++reg) {
        int rloc = R0 + cg * 4 + reg;
#pragma unroll
        for (int nt = 0; nt < 4; ++nt)
            foutp[(size_t)rloc * 64 + nt * 16 + cb] = x2[reg][nt] + ya[nt][reg];
    }
}

// ---------- output transpose ----------
__global__ __launch_bounds__(256) void output_kernel(const float* __restrict__ f,
                                                     float* __restrict__ out) {
    __shared__ float tile[64][65];
    int blk = blockIdx.x;
    int ntile = blk & 255;
    int bp = blk >> 8;
    int b = bp / 3, p = bp - b * 3;
    int n0 = ntile * 64;
    int tr = threadIdx.x >> 6, tc = threadIdx.x & 63;

    const float* src = f + ((size_t)(p * B_ + b) * N_ + n0) * C_;
#pragma unroll
    for (int it = 0; it < 16; ++it) {
        int r = it * 4 + tr;
        tile[r][tc] = src[(size_t)r * C_ + tc];
    }
    __syncthreads();
    float* dst = out + (size_t)(b * 3 + p) * C_ * N_ + n0;
#pragma unroll
    for (int it = 0; it < 16; ++it) {
        int cidx = it * 4 + tr;
        dst[(size_t)cidx * N_ + tc] = tile[tc][cidx];
    }
}

extern "C" void kernel_launch(void* const* d_in, const int* in_sizes, int n_in,
                              void* d_out, int out_size, void* d_ws, size_t ws_size,
                              hipStream_t stream) {
    const float* img_feats = (const float*)d_in[0];
    const float* pts       = (const float*)d_in[1];
    const float* query     = (const float*)d_in[2];
    const float* ln1_g     = (const float*)d_in[3];
    const float* ln1_b     = (const float*)d_in[4];
    const float* ln2_g     = (const float*)d_in[5];
    const float* ln2_b     = (const float*)d_in[6];
    const float* in_w      = (const float*)d_in[7];
    const float* in_b      = (const float*)d_in[8];
    const float* out_w     = (const float*)d_in[9];
    const float* out_b     = (const float*)d_in[10];
    const float* ffn_w1    = (const float*)d_in[11];
    const float* ffn_b1    = (const float*)d_in[12];
    const float* ffn_w2    = (const float*)d_in[13];
    const float* ffn_b2    = (const float*)d_in[14];

    const size_t FEAT_SZ = (size_t)3 * B_ * N_ * C_;  // 6,291,456

    float* ws = (float*)d_ws;
    float* ftr      = ws;
    float4* recs    = (float4*)(ftr + FTR_SZ);
    int* counts     = (int*)(ftr + FTR_SZ + REC_F);
    int* offsets    = counts + SEG_SZ;
    int* cursors    = offsets + SEG_SZ;
    int* idxlist    = cursors + SEG_SZ;
    float* fA       = (float*)(idxlist + SEG_SZ);
    float* fB       = fA + FEAT_SZ;
    unsigned short* pk_base = (unsigned short*)(fB + FEAT_SZ);

    // init plane feats with query tensors
    init_feats<<<(3 * N_ * C_ + 255) / 256, 256, 0, stream>>>(query, fA);

    // ---- splat via binning + gather (no float atomics)
    zero_counts<<<(int)(SEG_SZ / 4 + 255) / 256, 256, 0, stream>>>((int4*)counts, (int)(SEG_SZ / 4));
    transpose_feats<<<NBV * 256, 256, 0, stream>>>(img_feats, ftr);
    bin_count<<<(NBV * N_) / 256, 256, 0, stream>>>(pts, recs, counts);
    scan_bins<<<NSEG, 256, 0, stream>>>(counts, offsets, cursors);
    scatter_idx<<<(NBV * N_) / 256, 256, 0, stream>>>(recs, cursors, idxlist);
    gather_splat<<<dim3(N_ / 4, 3, B_), 256, 0, stream>>>(ftr, recs, counts, offsets,
                                                          idxlist, fA);

    // pack weights
    for (int l = 0; l < NL_; ++l) {
        pack_layer<<<(PK_ELEMS + 255) / 256, 256, 0, stream>>>(
            in_w + (size_t)l * 3 * C_ * C_, out_w + (size_t)l * C_ * C_,
            ffn_w1 + (size_t)l * 4 * C_ * C_, ffn_w2 + (size_t)l * C_ * 4 * C_,
            pk_base + (size_t)l * LAYER_PK);
    }

    dim3 pgrid((B_ * N_) / 64, 3);
    for (int l = 0; l < NL_; ++l) {
        const float* fin = (l == 0) ? fA : fB;
        float* fout      = (l == 0) ? fB : fA;
        plane_mfma<<<pgrid, 256, 0, stream>>>(
            fin, fout, pk_base + (size_t)l * LAYER_PK,
            ln1_g + l * C_, ln1_b + l * C_,
            ln2_g + l * C_, ln2_b + l * C_,
            in_b + l * 3 * C_, out_b + l * C_,
            ffn_b1 + l * 4 * C_, ffn_b2 + l * C_);
    }

    output_kernel<<<B_ * 3 * (N_ / 64), 256, 0, stream>>>(fA, (float*)d_out);
}

// Round 7
// 795.185 us; speedup vs baseline: 6.2142x; 1.1543x over previous
//
#include <hip/hip_runtime.h>
#include <math.h>

constexpr int R_ = 128, C_ = 64, NL_ = 2, B_ = 2, V_ = 4;
constexpr int N_ = R_ * R_;          // 16384
constexpr int T_ = 6;

typedef __attribute__((ext_vector_type(8))) short bf16x8;
typedef __attribute__((ext_vector_type(4))) float f32x4;
typedef __attribute__((ext_vector_type(4))) unsigned short u16x4;
typedef __attribute__((ext_vector_type(8))) unsigned short u16x8;

#define MFMA_B16(a, b, c) __builtin_amdgcn_mfma_f32_16x16x32_bf16((a), (b), (c), 0, 0, 0)

// packed-weight element offsets (per layer, in elements)
constexpr int OFF_O = 12288, OFF_W1 = 16384, OFF_W2 = 32768;
constexpr int PK_ELEMS = 49152;
constexpr int LAYER_PK = 2 * PK_ELEMS;   // ushorts per layer (hi+lo)

// splat-path sizes
constexpr int NBV = B_ * V_;                       // 8
constexpr size_t FTR_SZ = (size_t)NBV * N_ * C_;   // 8,388,608 floats
constexpr size_t REC_F  = (size_t)NBV * N_ * 4;    // 524,288 floats (float4 recs)
constexpr int NSEG = 3 * NBV;                      // 24 segments
constexpr size_t SEG_SZ = (size_t)NSEG * N_;       // 393,216 ints

// ---------- helpers ----------
__device__ inline unsigned rne16(float x) {
    unsigned b = __float_as_uint(x);
    return (b + 0x7fffu + ((b >> 16) & 1u)) >> 16;
}

// read A-fragment (16x32 bf16) for wave's M-tile from swizzled LDS
__device__ inline bf16x8 readFrag(const unsigned short* base, int rowBase, int lane,
                                  int ks, int rowStrideB, int swzMask) {
    int rowloc = rowBase + (lane & 15);
    int off = rowloc * rowStrideB + ks * 64 + ((lane >> 4) & 3) * 16;
    off ^= ((rowloc & swzMask) << 4);
    return *(const bf16x8*)((const char*)base + off);
}

// store 4 bf16-hi values (K-permuted: p = cb*4+nt) as one 8B write
__device__ inline void storeA4(unsigned short* base, int rloc, int cb,
                               float v0, float v1, float v2, float v3) {
    u16x4 u;
    u[0] = (unsigned short)rne16(v0);
    u[1] = (unsigned short)rne16(v1);
    u[2] = (unsigned short)rne16(v2);
    u[3] = (unsigned short)rne16(v3);
    int bo = (rloc * 128 + cb * 8) ^ ((rloc & 7) << 4);
    *(u16x4*)((char*)base + bo) = u;
}

// load B-fragment pair (hi,lo) from a weight table (global or LDS)
__device__ inline void readB(const unsigned short* matHi, int E, int NTm, int ks, int nt,
                             int lane, bf16x8& bh, bf16x8& bl) {
    int off = (((ks * NTm + nt) << 6) + lane) << 3;
    bh = *(const bf16x8*)(matHi + off);
    bl = *(const bf16x8*)(matHi + E + off);
}

// ---------- pack all weights of one layer (K-permuted, split hi/lo) ----------
__global__ __launch_bounds__(256) void pack_layer(const float* __restrict__ iw,
                                                  const float* __restrict__ ow,
                                                  const float* __restrict__ w1,
                                                  const float* __restrict__ w2,
                                                  unsigned short* __restrict__ pk) {
    int idx = blockIdx.x * 256 + threadIdx.x;
    if (idx >= PK_ELEMS) return;
    const float* W;
    int O, K, base, mode, lidx;
    if (idx < 12288)      { int m = idx >> 12; lidx = idx & 4095; W = iw + m * 4096; O = 64;  K = 64;  base = m * 4096; mode = 0; }
    else if (idx < 16384) { lidx = idx - 12288; W = ow; O = 64;  K = 64;  base = OFF_O;  mode = 0; }
    else if (idx < 32768) { lidx = idx - 16384; W = w1; O = 256; K = 64;  base = OFF_W1; mode = 0; }
    else                  { lidx = idx - 32768; W = w2; O = 64;  K = 256; base = OFF_W2; mode = 1; }
    int j = lidx & 7, l = (lidx >> 3) & 63, rem = lidx >> 9;
    int NTm = O >> 4;
    int nt = rem & (NTm - 1), ks = rem / NTm;
    int kfrag = ks * 32 + ((l >> 4) & 3) * 8 + j;
    int k;
    if (mode == 0) { int p = kfrag & 63; k = (p & 3) * 16 + (p >> 2); }
    else { int cc = kfrag >> 7; int pl = kfrag & 127; k = (cc * 8 + (pl & 7)) * 16 + (pl >> 3); }
    int o = nt * 16 + (l & 15);
    float w = W[(size_t)o * K + k];
    unsigned hb = rne16(w);
    float hf = __uint_as_float(hb << 16);
    unsigned lb = rne16(w - hf);
    int E = O * K;
    pk[2 * base + lidx] = (unsigned short)hb;
    pk[2 * base + E + lidx] = (unsigned short)lb;
}

// ---------- init plane feats with query tensors ----------
__global__ __launch_bounds__(256) void init_feats(const float* __restrict__ q,
                                                  float* __restrict__ f0) {
    int idx = blockIdx.x * 256 + threadIdx.x;
    if (idx >= 3 * N_ * C_) return;
    int p = idx / (N_ * C_);
    int rem = idx - p * (N_ * C_);
    float val = q[idx];
    f0[(size_t)(p * B_ + 0) * N_ * C_ + rem] = val;
    f0[(size_t)(p * B_ + 1) * N_ * C_ + rem] = val;
}

// ---------- zero bin counts ----------
__global__ __launch_bounds__(256) void zero_counts(int4* __restrict__ p, int n4) {
    int i = blockIdx.x * 256 + threadIdx.x;
    if (i < n4) p[i] = make_int4(0, 0, 0, 0);
}

// ---------- transpose features: [bv][c][n] -> [bv][n][c] ----------
__global__ __launch_bounds__(256) void transpose_feats(const float* __restrict__ src,
                                                       float* __restrict__ dst) {
    __shared__ float tile[64][65];
    int blk = blockIdx.x;             // NBV * 256
    int ntile = blk & 255;
    int bv = blk >> 8;
    int n0 = ntile * 64;
    int tr = threadIdx.x >> 6, tc = threadIdx.x & 63;
    const float* s = src + (size_t)bv * C_ * N_;
#pragma unroll
    for (int it = 0; it < 16; ++it) {
        int c = it * 4 + tr;
        tile[c][tc] = s[(size_t)c * N_ + n0 + tc];
    }
    __syncthreads();
    float* d = dst + ((size_t)bv * N_ + n0) * C_;
#pragma unroll
    for (int it = 0; it < 16; ++it) {
        int r = it * 4 + tr;
        d[(size_t)r * C_ + tc] = tile[tc][r];
    }
}

// ---------- bin count + per-point record ----------
__global__ __launch_bounds__(256) void bin_count(const float* __restrict__ pts,
                                                 float4* __restrict__ recs,
                                                 int* __restrict__ counts) {
    int idx = blockIdx.x * 256 + threadIdx.x;     // [0, NBV*N)
    if (idx >= NBV * N_) return;
    int bv = idx >> 14;
    const float* p = pts + (size_t)idx * 3;
    float px = p[0], py = p[1], pz = p[2];
    const float HI = (float)(127.0 - 1e-5);
    float gx = fminf(fmaxf((px + 1.0f) * 127.0f / 2.0f, 0.0f), HI);
    float gy = fminf(fmaxf((py + 1.0f) * 127.0f / 2.0f, 0.0f), HI);
    float gz = fminf(fmaxf((pz + 1.0f) * 127.0f / 2.0f, 0.0f), HI);
    int x0 = (int)gx, y0 = (int)gy, z0 = (int)gz;
    float wx = gx - (float)x0, wy = gy - (float)y0, wz = gz - (float)z0;
    float4 r;
    r.x = __uint_as_float((unsigned)(x0 | (y0 << 8) | (z0 << 16)));
    r.y = wx; r.z = wy; r.w = wz;
    recs[idx] = r;
    atomicAdd(&counts[(0 * NBV + bv) * N_ + x0 * R_ + y0], 1);
    atomicAdd(&counts[(1 * NBV + bv) * N_ + x0 * R_ + z0], 1);
    atomicAdd(&counts[(2 * NBV + bv) * N_ + y0 * R_ + z0], 1);
}

// ---------- per-segment exclusive scan (16384 bins each) ----------
__global__ __launch_bounds__(256) void scan_bins(const int* __restrict__ counts,
                                                 int* __restrict__ offsets,
                                                 int* __restrict__ cursors) {
    __shared__ int part[256];
    int seg = blockIdx.x;             // 24
    int t = threadIdx.x;
    const int* c = counts + (size_t)seg * N_;
    int sum = 0;
    for (int i = 0; i < 64; ++i) sum += c[t * 64 + i];
    part[t] = sum;
    __syncthreads();
    if (t == 0) {
        int run = 0;
        for (int i = 0; i < 256; ++i) { int v = part[i]; part[i] = run; run += v; }
    }
    __syncthreads();
    int run = part[t];
    int* o = offsets + (size_t)seg * N_;
    int* cu = cursors + (size_t)seg * N_;
    for (int i = 0; i < 64; ++i) {
        o[t * 64 + i] = run;
        cu[t * 64 + i] = run;
        run += c[t * 64 + i];
    }
}

// ---------- scatter point indices into bins ----------
__global__ __launch_bounds__(256) void scatter_idx(const float4* __restrict__ recs,
                                                   int* __restrict__ cursors,
                                                   int* __restrict__ idxlist) {
    int idx = blockIdx.x * 256 + threadIdx.x;
    if (idx >= NBV * N_) return;
    int bv = idx >> 14, n = idx & (N_ - 1);
    unsigned pc = __float_as_uint(recs[idx].x);
    int x0 = pc & 255, y0 = (pc >> 8) & 255, z0 = (pc >> 16) & 255;
    int s0 = (0 * NBV + bv) * N_;
    int s1 = (1 * NBV + bv) * N_;
    int s2 = (2 * NBV + bv) * N_;
    int p0 = atomicAdd(&cursors[s0 + x0 * R_ + y0], 1);
    idxlist[s0 + p0] = n;
    int p1 = atomicAdd(&cursors[s1 + x0 * R_ + z0], 1);
    idxlist[s1 + p1] = n;
    int p2 = atomicAdd(&cursors[s2 + y0 * R_ + z0], 1);
    idxlist[s2 + p2] = n;
}

// ---------- gather splat: one wave per (plane, b, cell), all 4 views ----------
__global__ __launch_bounds__(256) void gather_splat(
    const float* __restrict__ ftr, const float4* __restrict__ recs,
    const int* __restrict__ counts, const int* __restrict__ offsets,
    const int* __restrict__ idxlist, float* __restrict__ f0) {
    int wid = threadIdx.x >> 6, lane = threadIdx.x & 63;
    int cell = blockIdx.x * 4 + wid;          // [0, N)
    int pi = blockIdx.y, b = blockIdx.z;
    int a = cell >> 7, c = cell & 127;

    float total = 0.f;
#pragma unroll
    for (int v = 0; v < V_; ++v) {
        int bv = b * V_ + v;
        int seg = pi * NBV + bv;
        const int* segoff = offsets + (size_t)seg * N_;
        const int* segcnt = counts + (size_t)seg * N_;
        const int* seglst = idxlist + (size_t)seg * N_;
        const float* fbase = ftr + (size_t)bv * N_ * C_;
        float facc = 0.f, wsum = 0.f;
#pragma unroll
        for (int d = 0; d < 4; ++d) {
            int ba = a - (d >> 1), bc = c - (d & 1);
            if (ba < 0 || bc < 0) continue;
            int bin = ba * R_ + bc;
            int off = segoff[bin], cnt = segcnt[bin];
            for (int i = 0; i < cnt; ++i) {
                int n = seglst[off + i];
                float4 r = recs[(size_t)bv * N_ + n];
                unsigned pc = __float_as_uint(r.x);
                int x0 = pc & 255, y0 = (pc >> 8) & 255, z0 = (pc >> 16) & 255;
                float wx = r.y, wy = r.z, wz = r.w;
                float ax = 1.f - wx, ay = 1.f - wy, az = 1.f - wz;
                int x1 = x0 + 1, y1 = y0 + 1, z1 = z0 + 1;
                float wtot = 0.f;
                if (pi == 0) {
                    if (x0 == a && y0 == c) wtot += ax * ay * az;
                    if (x0 == a && y1 == c) wtot += ax * wy * az;
                    if (x1 == a && y0 == c) wtot += wx * ay * az;
                    if (x1 == a && y1 == c) wtot += wx * wy * az;
                } else if (pi == 1) {
                    if (x0 == a && z0 == c) wtot += ax * ay * az;
                    if (x0 == a && z1 == c) wtot += ax * ay * wz;
                    if (x1 == a && z0 == c) wtot += wx * ay * az;
                    if (x1 == a && z1 == c) wtot += wx * wy * wz;
                } else {
                    if (y0 == a && z0 == c) wtot += ax * ay * az;
                    if (y0 == a && z1 == c) wtot += ax * ay * wz;
                    if (y1 == a && z0 == c) wtot += ax * wy * az;
                    if (y1 == a && z1 == c) wtot += wx * wy * wz;
                }
                facc += wtot * fbase[(size_t)n * C_ + lane];
                wsum += wtot;
            }
        }
        total += facc / fmaxf(wsum, 1e-8f);
    }
    f0[(((size_t)(pi * B_ + b)) * N_ + cell) * C_ + lane] += 0.25f * total;
}

// ---------- fused per-plane transformer layer (MFMA, LDS-staged weights) ----------
__global__ __launch_bounds__(256, 2) void plane_mfma(
    const float* __restrict__ fin, float* __restrict__ fout,
    const unsigned short* __restrict__ pk,
    const float* __restrict__ ln1g, const float* __restrict__ ln1b,
    const float* __restrict__ ln2g, const float* __restrict__ ln2b,
    const float* __restrict__ inb, const float* __restrict__ outb,
    const float* __restrict__ fb1, const float* __restrict__ fb2) {
    __shared__ __attribute__((aligned(16))) unsigned short Wb[16384];  // 32 KB weight stage
    __shared__ __attribute__((aligned(16))) unsigned short Ahi[4096];  // 8 KB A-frags
    __shared__ __attribute__((aligned(16))) float Hf[4096];            // 16 KB H-frags / out stage
    unsigned short* Hhi = (unsigned short*)Hf;

    const int tid = threadIdx.x;
    const int wid = tid >> 6, lane = tid & 63;
    const int cg = lane >> 4, cb = lane & 15;
    const int pi = blockIdx.y;
    const int R0 = wid * 16;                  // wave's first local row
    const int rowbase = blockIdx.x * 64;      // block's first global row
    const int b = rowbase >> 14;
    const int nn0 = rowbase & (N_ - 1);
    const int i0 = nn0 >> 7, j0 = nn0 & 127;
    const float lin_i = -1.0f + (2.0f * (float)i0) / 127.0f;

    // ---- stage Q (hi+lo, 16 KB) into Wb[0:8192]
#pragma unroll
    for (int i = 0; i < 4; ++i)
        *(u16x8*)(Wb + (i * 256 + tid) * 8) = *(const u16x8*)(pk + (i * 256 + tid) * 8);

    float g1[4], b1v[4];
#pragma unroll
    for (int nt = 0; nt < 4; ++nt) { g1[nt] = ln1g[nt * 16 + cb]; b1v[nt] = ln1b[nt * 16 + cb]; }

    // ---- Phase A: load x (kept in regs), LN1 -> A-frags (wave-private LDS rows)
    float x[4][4];
    const float* finp = fin + ((size_t)(pi * B_ + b) * N_ + nn0) * 64;
#pragma unroll
    for (int reg = 0; reg < 4; ++reg) {
        int rloc = R0 + cg * 4 + reg;
#pragma unroll
        for (int nt = 0; nt < 4; ++nt) x[reg][nt] = finp[(size_t)rloc * 64 + nt * 16 + cb];
        float s = x[reg][0] + x[reg][1] + x[reg][2] + x[reg][3];
#pragma unroll
        for (int m = 1; m < 16; m <<= 1) s += __shfl_xor(s, m, 64);
        float mean = s * (1.0f / 64.0f);
        float d0 = x[reg][0] - mean, d1 = x[reg][1] - mean, d2 = x[reg][2] - mean, d3 = x[reg][3] - mean;
        float sq = d0 * d0 + d1 * d1 + d2 * d2 + d3 * d3;
#pragma unroll
        for (int m = 1; m < 16; m <<= 1) sq += __shfl_xor(sq, m, 64);
        float rr = rsqrtf(sq * (1.0f / 64.0f) + 1e-5f);
        storeA4(Ahi, rloc, cb,
                d0 * rr * g1[0] + b1v[0], d1 * rr * g1[1] + b1v[1],
                d2 * rr * g1[2] + b1v[2], d3 * rr * g1[3] + b1v[3]);
    }
    __syncthreads();

    // ---- Phase B: q = xn @ Wq^T + bq  (Wb = Q)
    f32x4 qa[4];
#pragma unroll
    for (int nt = 0; nt < 4; ++nt) { float bq = inb[nt * 16 + cb]; qa[nt] = {bq, bq, bq, bq}; }
#pragma unroll
    for (int ks = 0; ks < 2; ++ks) {
        bf16x8 ah = readFrag(Ahi, R0, lane, ks, 128, 7);
#pragma unroll
        for (int nt = 0; nt < 4; ++nt) {
            bf16x8 bh, bl;
            readB(Wb, 4096, 4, ks, nt, lane, bh, bl);
            qa[nt] = MFMA_B16(ah, bh, qa[nt]);
            qa[nt] = MFMA_B16(ah, bl, qa[nt]);
        }
    }
    __syncthreads();

    // ---- stage K+V (32 KB) into Wb
#pragma unroll
    for (int i = 0; i < 8; ++i)
        *(u16x8*)(Wb + (i * 256 + tid) * 8) = *(const u16x8*)(pk + 8192 + (i * 256 + tid) * 8);
    __syncthreads();

    // ---- Phase C: t-loop — gather ctx, LN, k/v MFMA, softmax accumulate (no barriers)
    float kbias[4], vbias[4];
#pragma unroll
    for (int nt = 0; nt < 4; ++nt) { kbias[nt] = inb[64 + nt * 16 + cb]; vbias[nt] = inb[128 + nt * 16 + cb]; }
    float den_[4][4];
    f32x4 oa[4];
#pragma unroll
    for (int nt = 0; nt < 4; ++nt) {
        oa[nt] = {0.f, 0.f, 0.f, 0.f};
#pragma unroll
        for (int reg = 0; reg < 4; ++reg) den_[nt][reg] = 0.f;
    }

    for (int t = 0; t < T_; ++t) {
        int khalf = (t < 3) ? t : t - 3;
        float sk = (float)(khalf - 1);
        bool tl = (t < 3);
        int io;
        if (pi == 0) io = tl ? 1 : 2;
        else if (pi == 1) io = tl ? 0 : 2;
        else io = tl ? 0 : 1;
        const float* Fio = fin + (size_t)(io * B_ + b) * N_ * 64;

#pragma unroll
        for (int reg = 0; reg < 4; ++reg) {
            int rloc = R0 + cg * 4 + reg;
            float lin_j = -1.0f + (2.0f * (float)(j0 + rloc)) / 127.0f;
            float caf, cbf;
            if (pi == 0) { caf = tl ? lin_j : lin_i; cbf = sk; }
            else if (pi == 1) { if (tl) { caf = lin_j; cbf = sk; } else { caf = sk; cbf = lin_i; } }
            else { caf = sk; cbf = tl ? lin_j : lin_i; }
            float ua = fminf(fmaxf((caf * 0.5f + 0.5f) * 127.0f, 0.0f), 127.0f);
            float ub = fminf(fmaxf((cbf * 0.5f + 0.5f) * 127.0f, 0.0f), 127.0f);
            float gxp = fminf(fmaxf(((ua + 1.0f) * 0.5f) * 127.0f, 0.0f), 127.0f);
            float gyp = fminf(fmaxf(((ub + 1.0f) * 0.5f) * 127.0f, 0.0f), 127.0f);
            int xx0 = (int)gxp, yy0 = (int)gyp;
            int xx1 = xx0 + 1 < 128 ? xx0 + 1 : 127;
            int yy1 = yy0 + 1 < 128 ? yy0 + 1 : 127;
            float wx = gxp - (float)xx0, wyv = gyp - (float)yy0;
            size_t c00 = (size_t)(yy0 * R_ + xx0) * 64, c01 = (size_t)(yy0 * R_ + xx1) * 64;
            size_t c10 = (size_t)(yy1 * R_ + xx0) * 64, c11 = (size_t)(yy1 * R_ + xx1) * 64;
            float cv[4];
#pragma unroll
            for (int nt = 0; nt < 4; ++nt) {
                int ch = nt * 16 + cb;
                float v00 = Fio[c00 + ch], v01 = Fio[c01 + ch];
                float v10 = Fio[c10 + ch], v11 = Fio[c11 + ch];
                cv[nt] = (1.0f - wyv) * ((1.0f - wx) * v00 + wx * v01) +
                         wyv * ((1.0f - wx) * v10 + wx * v11);
            }
            float s = cv[0] + cv[1] + cv[2] + cv[3];
#pragma unroll
            for (int m = 1; m < 16; m <<= 1) s += __shfl_xor(s, m, 64);
            float mean = s * (1.0f / 64.0f);
            float d0 = cv[0] - mean, d1 = cv[1] - mean, d2 = cv[2] - mean, d3 = cv[3] - mean;
            float sq = d0 * d0 + d1 * d1 + d2 * d2 + d3 * d3;
#pragma unroll
            for (int m = 1; m < 16; m <<= 1) sq += __shfl_xor(sq, m, 64);
            float rr = rsqrtf(sq * (1.0f / 64.0f) + 1e-5f);
            storeA4(Ahi, rloc, cb,
                    d0 * rr * g1[0] + b1v[0], d1 * rr * g1[1] + b1v[1],
                    d2 * rr * g1[2] + b1v[2], d3 * rr * g1[3] + b1v[3]);
        }

        // k,v projections via MFMA (K = Wb[0:8192], V = Wb[8192:16384])
        f32x4 ka[4], va[4];
#pragma unroll
        for (int nt = 0; nt < 4; ++nt) {
            ka[nt] = {kbias[nt], kbias[nt], kbias[nt], kbias[nt]};
            va[nt] = {vbias[nt], vbias[nt], vbias[nt], vbias[nt]};
        }
#pragma unroll
        for (int ks = 0; ks < 2; ++ks) {
            bf16x8 ah = readFrag(Ahi, R0, lane, ks, 128, 7);
#pragma unroll
            for (int nt = 0; nt < 4; ++nt) {
                bf16x8 bh, bl;
                readB(Wb, 4096, 4, ks, nt, lane, bh, bl);
                ka[nt] = MFMA_B16(ah, bh, ka[nt]);
                ka[nt] = MFMA_B16(ah, bl, ka[nt]);
                readB(Wb + 8192, 4096, 4, ks, nt, lane, bh, bl);
                va[nt] = MFMA_B16(ah, bh, va[nt]);
                va[nt] = MFMA_B16(ah, bl, va[nt]);
            }
        }

        // scores (head = nt) + online softmax accumulate (no max tracking)
#pragma unroll
        for (int nt = 0; nt < 4; ++nt) {
            float d0 = qa[nt][0] * ka[nt][0];
            float d1 = qa[nt][1] * ka[nt][1];
            float d2 = qa[nt][2] * ka[nt][2];
            float d3 = qa[nt][3] * ka[nt][3];
#pragma unroll
            for (int m = 1; m < 16; m <<= 1) {
                d0 += __shfl_xor(d0, m, 64);
                d1 += __shfl_xor(d1, m, 64);
                d2 += __shfl_xor(d2, m, 64);
                d3 += __shfl_xor(d3, m, 64);
            }
            float e0 = __expf(d0 * 0.25f), e1 = __expf(d1 * 0.25f);
            float e2 = __expf(d2 * 0.25f), e3 = __expf(d3 * 0.25f);
            den_[nt][0] += e0; den_[nt][1] += e1; den_[nt][2] += e2; den_[nt][3] += e3;
            oa[nt][0] += e0 * va[nt][0];
            oa[nt][1] += e1 * va[nt][1];
            oa[nt][2] += e2 * va[nt][2];
            oa[nt][3] += e3 * va[nt][3];
        }
    }
    __syncthreads();

    // ---- stage O (16 KB) into Wb[0:8192]; concurrently write o/den -> A-frags
#pragma unroll
    for (int i = 0; i < 4; ++i)
        *(u16x8*)(Wb + (i * 256 + tid) * 8) = *(const u16x8*)(pk + 24576 + (i * 256 + tid) * 8);
#pragma unroll
    for (int reg = 0; reg < 4; ++reg) {
        int rloc = R0 + cg * 4 + reg;
        storeA4(Ahi, rloc, cb,
                oa[0][reg] / den_[0][reg], oa[1][reg] / den_[1][reg],
                oa[2][reg] / den_[2][reg], oa[3][reg] / den_[3][reg]);
    }
    __syncthreads();

    // ---- Phase D: out-proj (Wb = O); residual (x in regs); LN2 -> A-frags
    f32x4 ao[4];
#pragma unroll
    for (int nt = 0; nt < 4; ++nt) { float bo_ = outb[nt * 16 + cb]; ao[nt] = {bo_, bo_, bo_, bo_}; }
#pragma unroll
    for (int ks = 0; ks < 2; ++ks) {
        bf16x8 ah = readFrag(Ahi, R0, lane, ks, 128, 7);
#pragma unroll
        for (int nt = 0; nt < 4; ++nt) {
            bf16x8 bh, bl;
            readB(Wb, 4096, 4, ks, nt, lane, bh, bl);
            ao[nt] = MFMA_B16(ah, bh, ao[nt]);
            ao[nt] = MFMA_B16(ah, bl, ao[nt]);
        }
    }
    float g2[4], b2v[4];
#pragma unroll
    for (int nt = 0; nt < 4; ++nt) { g2[nt] = ln2g[nt * 16 + cb]; b2v[nt] = ln2b[nt * 16 + cb]; }
    float x2[4][4];
#pragma unroll
    for (int reg = 0; reg < 4; ++reg) {
        int rloc = R0 + cg * 4 + reg;
#pragma unroll
        for (int nt = 0; nt < 4; ++nt) x2[reg][nt] = x[reg][nt] + ao[nt][reg];
        float s = x2[reg][0] + x2[reg][1] + x2[reg][2] + x2[reg][3];
#pragma unroll
        for (int m = 1; m < 16; m <<= 1) s += __shfl_xor(s, m, 64);
        float mean = s * (1.0f / 64.0f);
        float d0 = x2[reg][0] - mean, d1 = x2[reg][1] - mean, d2 = x2[reg][2] - mean, d3 = x2[reg][3] - mean;
        float sq = d0 * d0 + d1 * d1 + d2 * d2 + d3 * d3;
#pragma unroll
        for (int m = 1; m < 16; m <<= 1) sq += __shfl_xor(sq, m, 64);
        float rr = rsqrtf(sq * (1.0f / 64.0f) + 1e-5f);
        storeA4(Ahi, rloc, cb,
                d0 * rr * g2[0] + b2v[0], d1 * rr * g2[1] + b2v[1],
                d2 * rr * g2[2] + b2v[2], d3 * rr * g2[3] + b2v[3]);
    }
    __syncthreads();     // O reads done; Wb free for FFN staging

    // ---- Phase E: FFN 64->256 (gelu) ->64, 2 chunks of 128 hidden, staged weights
    const unsigned short* pW1 = pk + 2 * OFF_W1;
    const unsigned short* pW2 = pk + 2 * OFF_W2;
    f32x4 ya[4];
#pragma unroll
    for (int nt = 0; nt < 4; ++nt) { float by = fb2[nt * 16 + cb]; ya[nt] = {by, by, by, by}; }

#pragma unroll
    for (int cc = 0; cc < 2; ++cc) {
        // stage W1 chunk cc (32 KB): global tile gt=ks*16+cc*8+n8 -> lds tile lt=ks*8+n8
#pragma unroll
        for (int it = 0; it < 8; ++it) {
            int i = it * 256 + tid;
            int half = i >> 10, j = i & 1023;
            int lt = j >> 6, lr = j & 63;
            int ksl = lt >> 3, n8 = lt & 7;
            int gt = ksl * 16 + cc * 8 + n8;
            *(u16x8*)(Wb + half * 8192 + (lt * 64 + lr) * 8) =
                *(const u16x8*)(pW1 + half * 16384 + (gt * 64 + lr) * 8);
        }
        __syncthreads();

        f32x4 ha[8];
#pragma unroll
        for (int n8 = 0; n8 < 8; ++n8) {
            float hb = fb1[(cc * 8 + n8) * 16 + cb];
            ha[n8] = {hb, hb, hb, hb};
        }
#pragma unroll
        for (int ks = 0; ks < 2; ++ks) {
            bf16x8 ah = readFrag(Ahi, R0, lane, ks, 128, 7);
#pragma unroll
            for (int n8 = 0; n8 < 8; ++n8) {
                bf16x8 bh, bl;
                readB(Wb, 8192, 8, ks, n8, lane, bh, bl);
                ha[n8] = MFMA_B16(ah, bh, ha[n8]);
                ha[n8] = MFMA_B16(ah, bl, ha[n8]);
            }
        }
        // gelu -> H frags (wave-private rows)
#pragma unroll
        for (int reg = 0; reg < 4; ++reg) {
            int rloc = R0 + cg * 4 + reg;
            u16x8 u;
#pragma unroll
            for (int n8 = 0; n8 < 8; ++n8) {
                float h = ha[n8][reg];
                h = 0.5f * h * (1.0f + erff(h * 0.70710678118654752f));
                u[n8] = (unsigned short)rne16(h);
            }
            int bo = (rloc * 256 + cb * 16) ^ ((rloc & 15) << 4);
            *(u16x8*)((char*)Hhi + bo) = u;
        }
        __syncthreads();     // W1 reads done

        // stage W2 chunk cc (32 KB): contiguous tiles [cc*16, cc*16+16)
#pragma unroll
        for (int it = 0; it < 8; ++it) {
            int i = it * 256 + tid;
            int half = i >> 10, j = i & 1023;
            *(u16x8*)(Wb + half * 8192 + j * 8) =
                *(const u16x8*)(pW2 + half * 16384 + cc * 8192 + j * 8);
        }
        __syncthreads();

#pragma unroll
        for (int ks2 = 0; ks2 < 4; ++ks2) {
            bf16x8 ah = readFrag(Hhi, R0, lane, ks2, 256, 15);
#pragma unroll
            for (int nt = 0; nt < 4; ++nt) {
                bf16x8 bh, bl;
                readB(Wb, 8192, 4, ks2, nt, lane, bh, bl);
                ya[nt] = MFMA_B16(ah, bh, ya[nt]);
                ya[nt] = MFMA_B16(ah, bl, ya[nt]);
            }
        }
        __syncthreads();     // W2 reads done before next chunk restage
    }

    // ---- final: x2 + ffn -> Hf (wave-private rows), then coalesced float4 store
#pragma unroll
    for (int reg = 0; reg < 4; ++reg) {
        int rloc = R0 + cg * 4 + reg;
#pragma unroll
        for (int nt = 0; nt < 4; ++nt)
            Hf[rloc * 64 + nt * 16 + cb] = x2[reg][nt] + ya[nt][reg];
    }
    __syncthreads();
    {
        float4* dst4 = (float4*)(fout + ((size_t)(pi * B_ + b) * N_ + nn0) * 64);
        const float4* src4 = (const float4*)Hf;
#pragma unroll
        for (int it = 0; it < 4; ++it) {
            int i = it * 256 + tid;
            dst4[i] = src4[i];
        }
    }
}

// ---------- output transpose ----------
__global__ __launch_bounds__(256) void output_kernel(const float* __restrict__ f,
                                                     float* __restrict__ out) {
    __shared__ float tile[64][65];
    int blk = blockIdx.x;
    int ntile = blk & 255;
    int bp = blk >> 8;
    int b = bp / 3, p = bp - b * 3;
    int n0 = ntile * 64;
    int tr = threadIdx.x >> 6, tc = threadIdx.x & 63;

    const float* src = f + ((size_t)(p * B_ + b) * N_ + n0) * C_;
#pragma unroll
    for (int it = 0; it < 16; ++it) {
        int r = it * 4 + tr;
        tile[r][tc] = src[(size_t)r * C_ + tc];
    }
    __syncthreads();
    float* dst = out + (size_t)(b * 3 + p) * C_ * N_ + n0;
#pragma unroll
    for (int it = 0; it < 16; ++it) {
        int cidx = it * 4 + tr;
        dst[(size_t)cidx * N_ + tc] = tile[tc][cidx];
    }
}

extern "C" void kernel_launch(void* const* d_in, const int* in_sizes, int n_in,
                              void* d_out, int out_size, void* d_ws, size_t ws_size,
                              hipStream_t stream) {
    const float* img_feats = (const float*)d_in[0];
    const float* pts       = (const float*)d_in[1];
    const float* query     = (const float*)d_in[2];
    const float* ln1_g     = (const float*)d_in[3];
    const float* ln1_b     = (const float*)d_in[4];
    const float* ln2_g     = (const float*)d_in[5];
    const float* ln2_b     = (const float*)d_in[6];
    const float* in_w      = (const float*)d_in[7];
    const float* in_b      = (const float*)d_in[8];
    const float* out_w     = (const float*)d_in[9];
    const float* out_b     = (const float*)d_in[10];
    const float* ffn_w1    = (const float*)d_in[11];
    const float* ffn_b1    = (const float*)d_in[12];
    const float* ffn_w2    = (const float*)d_in[13];
    const float* ffn_b2    = (const float*)d_in[14];

    const size_t FEAT_SZ = (size_t)3 * B_ * N_ * C_;  // 6,291,456

    float* ws = (float*)d_ws;
    float* ftr      = ws;
    float4* recs    = (float4*)(ftr + FTR_SZ);
    int* counts     = (int*)(ftr + FTR_SZ + REC_F);
    int* offsets    = counts + SEG_SZ;
    int* cursors    = offsets + SEG_SZ;
    int* idxlist    = cursors + SEG_SZ;
    float* fA       = (float*)(idxlist + SEG_SZ);
    float* fB       = fA + FEAT_SZ;
    unsigned short* pk_base = (unsigned short*)(fB + FEAT_SZ);

    // init plane feats with query tensors
    init_feats<<<(3 * N_ * C_ + 255) / 256, 256, 0, stream>>>(query, fA);

    // ---- splat via binning + gather (no float atomics)
    zero_counts<<<(int)(SEG_SZ / 4 + 255) / 256, 256, 0, stream>>>((int4*)counts, (int)(SEG_SZ / 4));
    transpose_feats<<<NBV * 256, 256, 0, stream>>>(img_feats, ftr);
    bin_count<<<(NBV * N_) / 256, 256, 0, stream>>>(pts, recs, counts);
    scan_bins<<<NSEG, 256, 0, stream>>>(counts, offsets, cursors);
    scatter_idx<<<(NBV * N_) / 256, 256, 0, stream>>>(recs, cursors, idxlist);
    gather_splat<<<dim3(N_ / 4, 3, B_), 256, 0, stream>>>(ftr, recs, counts, offsets,
                                                          idxlist, fA);

    // pack weights
    for (int l = 0; l < NL_; ++l) {
        pack_layer<<<(PK_ELEMS + 255) / 256, 256, 0, stream>>>(
            in_w + (size_t)l * 3 * C_ * C_, out_w + (size_t)l * C_ * C_,
            ffn_w1 + (size_t)l * 4 * C_ * C_, ffn_w2 + (size_t)l * C_ * 4 * C_,
            pk_base + (size_t)l * LAYER_PK);
    }

    dim3 pgrid((B_ * N_) / 64, 3);
    for (int l = 0; l < NL_; ++l) {
        const float* fin = (l == 0) ? fA : fB;
        float* fout      = (l == 0) ? fB : fA;
        plane_mfma<<<pgrid, 256, 0, stream>>>(
            fin, fout, pk_base + (size_t)l * LAYER_PK,
            ln1_g + l * C_, ln1_b + l * C_,
            ln2_g + l * C_, ln2_b + l * C_,
            in_b + l * 3 * C_, out_b + l * C_,
            ffn_b1 + l * 4 * C_, ffn_b2 + l * C_);
    }

    output_kernel<<<B_ * 3 * (N_ / 64), 256, 0, stream>>>(fA, (float*)d_out);
}

// Round 8
// 700.533 us; speedup vs baseline: 7.0538x; 1.1351x over previous
//
#include <hip/hip_runtime.h>
#include <math.h>

constexpr int R_ = 128, C_ = 64, NL_ = 2, B_ = 2, V_ = 4;
constexpr int N_ = R_ * R_;          // 16384
constexpr int T_ = 6;

typedef __attribute__((ext_vector_type(8))) short bf16x8;
typedef __attribute__((ext_vector_type(4))) float f32x4;
typedef __attribute__((ext_vector_type(4))) unsigned short u16x4;
typedef __attribute__((ext_vector_type(8))) unsigned short u16x8;

#define MFMA_B16(a, b, c) __builtin_amdgcn_mfma_f32_16x16x32_bf16((a), (b), (c), 0, 0, 0)

// packed-weight element offsets (per layer, in elements)
constexpr int OFF_O = 12288, OFF_W1 = 16384, OFF_W2 = 32768;
constexpr int PK_ELEMS = 49152;
constexpr int LAYER_PK = 2 * PK_ELEMS;   // ushorts per layer (hi+lo)

// splat-path sizes
constexpr int NBV = B_ * V_;                       // 8
constexpr size_t FTR_SZ = (size_t)NBV * N_ * C_;   // 8,388,608 floats
constexpr int NSEG = 3 * NBV;                      // 24 segments
constexpr size_t SEG_SZ = (size_t)NSEG * N_;       // 393,216 ints
constexpr int OSTRIDE = N_ + 128;                  // offsets stride (sentinel pad)

// ---------- helpers ----------
__device__ inline unsigned rne16(float x) {
    unsigned b = __float_as_uint(x);
    return (b + 0x7fffu + ((b >> 16) & 1u)) >> 16;
}

// read A-fragment (16x32 bf16) for wave's M-tile from swizzled LDS
__device__ inline bf16x8 readFrag(const unsigned short* base, int rowBase, int lane,
                                  int ks, int rowStrideB, int swzMask) {
    int rowloc = rowBase + (lane & 15);
    int off = rowloc * rowStrideB + ks * 64 + ((lane >> 4) & 3) * 16;
    off ^= ((rowloc & swzMask) << 4);
    return *(const bf16x8*)((const char*)base + off);
}

// store 4 bf16-hi values (K-permuted: p = cb*4+nt) as one 8B write
__device__ inline void storeA4(unsigned short* base, int rloc, int cb,
                               float v0, float v1, float v2, float v3) {
    u16x4 u;
    u[0] = (unsigned short)rne16(v0);
    u[1] = (unsigned short)rne16(v1);
    u[2] = (unsigned short)rne16(v2);
    u[3] = (unsigned short)rne16(v3);
    int bo = (rloc * 128 + cb * 8) ^ ((rloc & 7) << 4);
    *(u16x4*)((char*)base + bo) = u;
}

// load B-fragment pair (hi,lo) from a weight table (global or LDS)
__device__ inline void readB(const unsigned short* matHi, int E, int NTm, int ks, int nt,
                             int lane, bf16x8& bh, bf16x8& bl) {
    int off = (((ks * NTm + nt) << 6) + lane) << 3;
    bh = *(const bf16x8*)(matHi + off);
    bl = *(const bf16x8*)(matHi + E + off);
}

// ---------- pack all weights of one layer (K-permuted, split hi/lo) ----------
__global__ __launch_bounds__(256) void pack_layer(const float* __restrict__ iw,
                                                  const float* __restrict__ ow,
                                                  const float* __restrict__ w1,
                                                  const float* __restrict__ w2,
                                                  unsigned short* __restrict__ pk) {
    int idx = blockIdx.x * 256 + threadIdx.x;
    if (idx >= PK_ELEMS) return;
    const float* W;
    int O, K, base, mode, lidx;
    if (idx < 12288)      { int m = idx >> 12; lidx = idx & 4095; W = iw + m * 4096; O = 64;  K = 64;  base = m * 4096; mode = 0; }
    else if (idx < 16384) { lidx = idx - 12288; W = ow; O = 64;  K = 64;  base = OFF_O;  mode = 0; }
    else if (idx < 32768) { lidx = idx - 16384; W = w1; O = 256; K = 64;  base = OFF_W1; mode = 0; }
    else                  { lidx = idx - 32768; W = w2; O = 64;  K = 256; base = OFF_W2; mode = 1; }
    int j = lidx & 7, l = (lidx >> 3) & 63, rem = lidx >> 9;
    int NTm = O >> 4;
    int nt = rem & (NTm - 1), ks = rem / NTm;
    int kfrag = ks * 32 + ((l >> 4) & 3) * 8 + j;
    int k;
    if (mode == 0) { int p = kfrag & 63; k = (p & 3) * 16 + (p >> 2); }
    else { int cc = kfrag >> 7; int pl = kfrag & 127; k = (cc * 8 + (pl & 7)) * 16 + (pl >> 3); }
    int o = nt * 16 + (l & 15);
    float w = W[(size_t)o * K + k];
    unsigned hb = rne16(w);
    float hf = __uint_as_float(hb << 16);
    unsigned lb = rne16(w - hf);
    int E = O * K;
    pk[2 * base + lidx] = (unsigned short)hb;
    pk[2 * base + E + lidx] = (unsigned short)lb;
}

// ---------- init plane feats with query tensors ----------
__global__ __launch_bounds__(256) void init_feats(const float* __restrict__ q,
                                                  float* __restrict__ f0) {
    int idx = blockIdx.x * 256 + threadIdx.x;
    if (idx >= 3 * N_ * C_) return;
    int p = idx / (N_ * C_);
    int rem = idx - p * (N_ * C_);
    float val = q[idx];
    f0[(size_t)(p * B_ + 0) * N_ * C_ + rem] = val;
    f0[(size_t)(p * B_ + 1) * N_ * C_ + rem] = val;
}

// ---------- zero bin counts ----------
__global__ __launch_bounds__(256) void zero_counts(int4* __restrict__ p, int n4) {
    int i = blockIdx.x * 256 + threadIdx.x;
    if (i < n4) p[i] = make_int4(0, 0, 0, 0);
}

// ---------- transpose features: [bv][c][n] -> [bv][n][c] ----------
__global__ __launch_bounds__(256) void transpose_feats(const float* __restrict__ src,
                                                       float* __restrict__ dst) {
    __shared__ float tile[64][65];
    int blk = blockIdx.x;             // NBV * 256
    int ntile = blk & 255;
    int bv = blk >> 8;
    int n0 = ntile * 64;
    int tr = threadIdx.x >> 6, tc = threadIdx.x & 63;
    const float* s = src + (size_t)bv * C_ * N_;
#pragma unroll
    for (int it = 0; it < 16; ++it) {
        int c = it * 4 + tr;
        tile[c][tc] = s[(size_t)c * N_ + n0 + tc];
    }
    __syncthreads();
    float* d = dst + ((size_t)bv * N_ + n0) * C_;
#pragma unroll
    for (int it = 0; it < 16; ++it) {
        int r = it * 4 + tr;
        d[(size_t)r * C_ + tc] = tile[tc][r];
    }
}

// ---------- bin count ----------
__global__ __launch_bounds__(256) void bin_count(const float* __restrict__ pts,
                                                 int* __restrict__ counts) {
    int idx = blockIdx.x * 256 + threadIdx.x;     // [0, NBV*N)
    if (idx >= NBV * N_) return;
    int bv = idx >> 14;
    const float* p = pts + (size_t)idx * 3;
    float px = p[0], py = p[1], pz = p[2];
    const float HI = (float)(127.0 - 1e-5);
    float gx = fminf(fmaxf((px + 1.0f) * 127.0f / 2.0f, 0.0f), HI);
    float gy = fminf(fmaxf((py + 1.0f) * 127.0f / 2.0f, 0.0f), HI);
    float gz = fminf(fmaxf((pz + 1.0f) * 127.0f / 2.0f, 0.0f), HI);
    int x0 = (int)gx, y0 = (int)gy, z0 = (int)gz;
    atomicAdd(&counts[(0 * NBV + bv) * N_ + x0 * R_ + y0], 1);
    atomicAdd(&counts[(1 * NBV + bv) * N_ + x0 * R_ + z0], 1);
    atomicAdd(&counts[(2 * NBV + bv) * N_ + y0 * R_ + z0], 1);
}

// ---------- per-segment exclusive scan (16384 bins each) + sentinel pad ----------
__global__ __launch_bounds__(256) void scan_bins(const int* __restrict__ counts,
                                                 int* __restrict__ offsets,
                                                 int* __restrict__ cursors) {
    __shared__ int part[256];
    int seg = blockIdx.x;             // 24
    int t = threadIdx.x;
    const int* c = counts + (size_t)seg * N_;
    int sum = 0;
    for (int i = 0; i < 64; ++i) sum += c[t * 64 + i];
    part[t] = sum;
    __syncthreads();
    if (t == 0) {
        int run = 0;
        for (int i = 0; i < 256; ++i) { int v = part[i]; part[i] = run; run += v; }
    }
    __syncthreads();
    int run = part[t];
    int* o = offsets + (size_t)seg * OSTRIDE;
    int* cu = cursors + (size_t)seg * N_;
    for (int i = 0; i < 64; ++i) {
        o[t * 64 + i] = run;
        cu[t * 64 + i] = run;
        run += c[t * 64 + i];
    }
    if (t < 128) o[N_ + t] = N_;      // sentinel: total per segment == N_
}

// ---------- scatter full point records into bin-sorted entry lists ----------
__global__ __launch_bounds__(256) void scatter_pts(const float* __restrict__ pts,
                                                   int* __restrict__ cursors,
                                                   float4* __restrict__ ent) {
    int idx = blockIdx.x * 256 + threadIdx.x;
    if (idx >= NBV * N_) return;
    int bv = idx >> 14, n = idx & (N_ - 1);
    const float* p = pts + (size_t)idx * 3;
    float px = p[0], py = p[1], pz = p[2];
    const float HI = (float)(127.0 - 1e-5);
    float gx = fminf(fmaxf((px + 1.0f) * 127.0f / 2.0f, 0.0f), HI);
    float gy = fminf(fmaxf((py + 1.0f) * 127.0f / 2.0f, 0.0f), HI);
    float gz = fminf(fmaxf((pz + 1.0f) * 127.0f / 2.0f, 0.0f), HI);
    int x0 = (int)gx, y0 = (int)gy, z0 = (int)gz;
    float4 e;
    e.x = __uint_as_float((unsigned)n);
    e.y = gx - (float)x0; e.z = gy - (float)y0; e.w = gz - (float)z0;
    int s0 = 0 * NBV + bv, s1 = 1 * NBV + bv, s2 = 2 * NBV + bv;
    int p0 = atomicAdd(&cursors[(size_t)s0 * N_ + x0 * R_ + y0], 1);
    ent[(size_t)s0 * N_ + p0] = e;
    int p1 = atomicAdd(&cursors[(size_t)s1 * N_ + x0 * R_ + z0], 1);
    ent[(size_t)s1 * N_ + p1] = e;
    int p2 = atomicAdd(&cursors[(size_t)s2 * N_ + y0 * R_ + z0], 1);
    ent[(size_t)s2 * N_ + p2] = e;
}

// ---------- gather splat: one wave per (plane, b, 8-cell row strip), all 4 views ----------
__global__ __launch_bounds__(256) void gather_splat(
    const float* __restrict__ ftr, const int* __restrict__ offsets,
    const float4* __restrict__ ent, float* __restrict__ f0) {
    int wid = threadIdx.x >> 6, lane = threadIdx.x & 63;
    int strip = blockIdx.x * 4 + wid;         // [0, 2048)
    int pi = blockIdx.y, b = blockIdx.z;
    int a = strip >> 4;                       // cell row
    int c0 = (strip & 15) << 3;               // first cell col of strip

    float total[8];
#pragma unroll
    for (int k = 0; k < 8; ++k) total[k] = 0.f;

    for (int v = 0; v < V_; ++v) {
        int bv = b * V_ + v;
        int seg = pi * NBV + bv;
        const int* ob = offsets + (size_t)seg * OSTRIDE;
        const float4* eb = ent + (size_t)seg * N_;
        const float* fbase = ftr + (size_t)bv * N_ * C_ + lane;
        float facc[8], wsum[8];
#pragma unroll
        for (int k = 0; k < 8; ++k) { facc[k] = 0.f; wsum[k] = 0.f; }

        for (int dr = 0; dr < 2; ++dr) {
            int ba = a - dr;
            if (ba < 0) continue;
            int rowbase = ba * R_ + c0 - 1;
            int o[10];
#pragma unroll
            for (int jj = 0; jj < 10; ++jj)
                o[jj] = ob[max(rowbase + jj, 0)];
#pragma unroll
            for (int j = 0; j < 9; ++j) {
                if (j == 0 && c0 == 0) continue;    // bin col -1 doesn't exist
                int e = o[j + 1];
                for (int i = o[j]; i < e; ++i) {
                    float4 r = eb[i];
                    int n = (int)__float_as_uint(r.x);
                    float wx = r.y, wy = r.z, wz = r.w;
                    float ax = 1.f - wx, ay = 1.f - wy, az = 1.f - wz;
                    float XA = dr ? wx : ax;
                    float YA = dr ? wy : ay;
                    // weight toward cell at dc=0 (local j-1) and dc=1 (local j)
                    float w0 = (pi == 2 ? ax * YA : XA * ay) * az;
                    float w1 = (pi == 0) ? XA * wy * az : XA * YA * wz;
                    float f = fbase[(size_t)n * C_];
                    if (j > 0) { facc[j - 1] += w0 * f; wsum[j - 1] += w0; }
                    if (j < 8) { facc[j] += w1 * f; wsum[j] += w1; }
                }
            }
        }
#pragma unroll
        for (int k = 0; k < 8; ++k)
            total[k] += facc[k] / fmaxf(wsum[k], 1e-8f);
    }
    float* dst = f0 + (((size_t)(pi * B_ + b)) * N_ + a * R_ + c0) * C_ + lane;
#pragma unroll
    for (int k = 0; k < 8; ++k)
        dst[(size_t)k * C_] += 0.25f * total[k];
}

// ---------- fused per-plane transformer layer (MFMA, LDS-staged weights) ----------
__global__ __launch_bounds__(256, 2) void plane_mfma(
    const float* __restrict__ fin, float* __restrict__ fout,
    const unsigned short* __restrict__ pk,
    const float* __restrict__ ln1g, const float* __restrict__ ln1b,
    const float* __restrict__ ln2g, const float* __restrict__ ln2b,
    const float* __restrict__ inb, const float* __restrict__ outb,
    const float* __restrict__ fb1, const float* __restrict__ fb2) {
    __shared__ __attribute__((aligned(16))) unsigned short Wb[16384];  // 32 KB weight stage
    __shared__ __attribute__((aligned(16))) unsigned short Ahi[4096];  // 8 KB A-frags
    __shared__ __attribute__((aligned(16))) float Hf[4096];            // 16 KB H-frags / out stage
    unsigned short* Hhi = (unsigned short*)Hf;

    const int tid = threadIdx.x;
    const int wid = tid >> 6, lane = tid & 63;
    const int cg = lane >> 4, cb = lane & 15;
    const int pi = blockIdx.y;
    const int R0 = wid * 16;                  // wave's first local row
    const int rowbase = blockIdx.x * 64;      // block's first global row
    const int b = rowbase >> 14;
    const int nn0 = rowbase & (N_ - 1);
    const int i0 = nn0 >> 7, j0 = nn0 & 127;
    const float lin_i = -1.0f + (2.0f * (float)i0) / 127.0f;

    // ---- stage Q (hi+lo, 16 KB) into Wb[0:8192]
#pragma unroll
    for (int i = 0; i < 4; ++i)
        *(u16x8*)(Wb + (i * 256 + tid) * 8) = *(const u16x8*)(pk + (i * 256 + tid) * 8);

    float g1[4], b1v[4];
#pragma unroll
    for (int nt = 0; nt < 4; ++nt) { g1[nt] = ln1g[nt * 16 + cb]; b1v[nt] = ln1b[nt * 16 + cb]; }

    // ---- Phase A: load x (kept in regs), LN1 -> A-frags (wave-private LDS rows)
    float x[4][4];
    const float* finp = fin + ((size_t)(pi * B_ + b) * N_ + nn0) * 64;
#pragma unroll
    for (int reg = 0; reg < 4; ++reg) {
        int rloc = R0 + cg * 4 + reg;
#pragma unroll
        for (int nt = 0; nt < 4; ++nt) x[reg][nt] = finp[(size_t)rloc * 64 + nt * 16 + cb];
        float s = x[reg][0] + x[reg][1] + x[reg][2] + x[reg][3];
#pragma unroll
        for (int m = 1; m < 16; m <<= 1) s += __shfl_xor(s, m, 64);
        float mean = s * (1.0f / 64.0f);
        float d0 = x[reg][0] - mean, d1 = x[reg][1] - mean, d2 = x[reg][2] - mean, d3 = x[reg][3] - mean;
        float sq = d0 * d0 + d1 * d1 + d2 * d2 + d3 * d3;
#pragma unroll
        for (int m = 1; m < 16; m <<= 1) sq += __shfl_xor(sq, m, 64);
        float rr = rsqrtf(sq * (1.0f / 64.0f) + 1e-5f);
        storeA4(Ahi, rloc, cb,
                d0 * rr * g1[0] + b1v[0], d1 * rr * g1[1] + b1v[1],
                d2 * rr * g1[2] + b1v[2], d3 * rr * g1[3] + b1v[3]);
    }
    __syncthreads();

    // ---- Phase B: q = xn @ Wq^T + bq  (Wb = Q)
    f32x4 qa[4];
#pragma unroll
    for (int nt = 0; nt < 4; ++nt) { float bq = inb[nt * 16 + cb]; qa[nt] = {bq, bq, bq, bq}; }
#pragma unroll
    for (int ks = 0; ks < 2; ++ks) {
        bf16x8 ah = readFrag(Ahi, R0, lane, ks, 128, 7);
#pragma unroll
        for (int nt = 0; nt < 4; ++nt) {
            bf16x8 bh, bl;
            readB(Wb, 4096, 4, ks, nt, lane, bh, bl);
            qa[nt] = MFMA_B16(ah, bh, qa[nt]);
            qa[nt] = MFMA_B16(ah, bl, qa[nt]);
        }
    }
    __syncthreads();

    // ---- stage K+V (32 KB) into Wb
#pragma unroll
    for (int i = 0; i < 8; ++i)
        *(u16x8*)(Wb + (i * 256 + tid) * 8) = *(const u16x8*)(pk + 8192 + (i * 256 + tid) * 8);
    __syncthreads();

    // ---- Phase C: t-loop — gather ctx, LN, k/v MFMA, softmax accumulate (no barriers)
    float kbias[4], vbias[4];
#pragma unroll
    for (int nt = 0; nt < 4; ++nt) { kbias[nt] = inb[64 + nt * 16 + cb]; vbias[nt] = inb[128 + nt * 16 + cb]; }
    float den_[4][4];
    f32x4 oa[4];
#pragma unroll
    for (int nt = 0; nt < 4; ++nt) {
        oa[nt] = {0.f, 0.f, 0.f, 0.f};
#pragma unroll
        for (int reg = 0; reg < 4; ++reg) den_[nt][reg] = 0.f;
    }

    for (int t = 0; t < T_; ++t) {
        int khalf = (t < 3) ? t : t - 3;
        float sk = (float)(khalf - 1);
        bool tl = (t < 3);
        int io;
        if (pi == 0) io = tl ? 1 : 2;
        else if (pi == 1) io = tl ? 0 : 2;
        else io = tl ? 0 : 1;
        const float* Fio = fin + (size_t)(io * B_ + b) * N_ * 64;

#pragma unroll
        for (int reg = 0; reg < 4; ++reg) {
            int rloc = R0 + cg * 4 + reg;
            float lin_j = -1.0f + (2.0f * (float)(j0 + rloc)) / 127.0f;
            float caf, cbf;
            if (pi == 0) { caf = tl ? lin_j : lin_i; cbf = sk; }
            else if (pi == 1) { if (tl) { caf = lin_j; cbf = sk; } else { caf = sk; cbf = lin_i; } }
            else { caf = sk; cbf = tl ? lin_j : lin_i; }
            float ua = fminf(fmaxf((caf * 0.5f + 0.5f) * 127.0f, 0.0f), 127.0f);
            float ub = fminf(fmaxf((cbf * 0.5f + 0.5f) * 127.0f, 0.0f), 127.0f);
            float gxp = fminf(fmaxf(((ua + 1.0f) * 0.5f) * 127.0f, 0.0f), 127.0f);
            float gyp = fminf(fmaxf(((ub + 1.0f) * 0.5f) * 127.0f, 0.0f), 127.0f);
            int xx0 = (int)gxp, yy0 = (int)gyp;
            int xx1 = xx0 + 1 < 128 ? xx0 + 1 : 127;
            int yy1 = yy0 + 1 < 128 ? yy0 + 1 : 127;
            float wx = gxp - (float)xx0, wyv = gyp - (float)yy0;
            size_t c00 = (size_t)(yy0 * R_ + xx0) * 64, c01 = (size_t)(yy0 * R_ + xx1) * 64;
            size_t c10 = (size_t)(yy1 * R_ + xx0) * 64, c11 = (size_t)(yy1 * R_ + xx1) * 64;
            float cv[4];
#pragma unroll
            for (int nt = 0; nt < 4; ++nt) {
                int ch = nt * 16 + cb;
                float v00 = Fio[c00 + ch], v01 = Fio[c01 + ch];
                float v10 = Fio[c10 + ch], v11 = Fio[c11 + ch];
                cv[nt] = (1.0f - wyv) * ((1.0f - wx) * v00 + wx * v01) +
                         wyv * ((1.0f - wx) * v10 + wx * v11);
            }
            float s = cv[0] + cv[1] + cv[2] + cv[3];
#pragma unroll
            for (int m = 1; m < 16; m <<= 1) s += __shfl_xor(s, m, 64);
            float mean = s * (1.0f / 64.0f);
            float d0 = cv[0] - mean, d1 = cv[1] - mean, d2 = cv[2] - mean, d3 = cv[3] - mean;
            float sq = d0 * d0 + d1 * d1 + d2 * d2 + d3 * d3;
#pragma unroll
            for (int m = 1; m < 16; m <<= 1) sq += __shfl_xor(sq, m, 64);
            float rr = rsqrtf(sq * (1.0f / 64.0f) + 1e-5f);
            storeA4(Ahi, rloc, cb,
                    d0 * rr * g1[0] + b1v[0], d1 * rr * g1[1] + b1v[1],
                    d2 * rr * g1[2] + b1v[2], d3 * rr * g1[3] + b1v[3]);
        }

        // k,v projections via MFMA (K = Wb[0:8192], V = Wb[8192:16384])
        f32x4 ka[4], va[4];
#pragma unroll
        for (int nt = 0; nt < 4; ++nt) {
            ka[nt] = {kbias[nt], kbias[nt], kbias[nt], kbias[nt]};
            va[nt] = {vbias[nt], vbias[nt], vbias[nt], vbias[nt]};
        }
#pragma unroll
        for (int ks = 0; ks < 2; ++ks) {
            bf16x8 ah = readFrag(Ahi, R0, lane, ks, 128, 7);
#pragma unroll
            for (int nt = 0; nt < 4; ++nt) {
                bf16x8 bh, bl;
                readB(Wb, 4096, 4, ks, nt, lane, bh, bl);
                ka[nt] = MFMA_B16(ah, bh, ka[nt]);
                ka[nt] = MFMA_B16(ah, bl, ka[nt]);
                readB(Wb + 8192, 4096, 4, ks, nt, lane, bh, bl);
                va[nt] = MFMA_B16(ah, bh, va[nt]);
                va[nt] = MFMA_B16(ah, bl, va[nt]);
            }
        }

        // scores (head = nt) + online softmax accumulate (no max tracking)
#pragma unroll
        for (int nt = 0; nt < 4; ++nt) {
            float d0 = qa[nt][0] * ka[nt][0];
            float d1 = qa[nt][1] * ka[nt][1];
            float d2 = qa[nt][2] * ka[nt][2];
            float d3 = qa[nt][3] * ka[nt][3];
#pragma unroll
            for (int m = 1; m < 16; m <<= 1) {
                d0 += __shfl_xor(d0, m, 64);
                d1 += __shfl_xor(d1, m, 64);
                d2 += __shfl_xor(d2, m, 64);
                d3 += __shfl_xor(d3, m, 64);
            }
            float e0 = __expf(d0 * 0.25f), e1 = __expf(d1 * 0.25f);
            float e2 = __expf(d2 * 0.25f), e3 = __expf(d3 * 0.25f);
            den_[nt][0] += e0; den_[nt][1] += e1; den_[nt][2] += e2; den_[nt][3] += e3;
            oa[nt][0] += e0 * va[nt][0];
            oa[nt][1] += e1 * va[nt][1];
            oa[nt][2] += e2 * va[nt][2];
            oa[nt][3] += e3 * va[nt][3];
        }
    }
    __syncthreads();

    // ---- stage O (16 KB) into Wb[0:8192]; concurrently write o/den -> A-frags
#pragma unroll
    for (int i = 0; i < 4; ++i)
        *(u16x8*)(Wb + (i * 256 + tid) * 8) = *(const u16x8*)(pk + 24576 + (i * 256 + tid) * 8);
#pragma unroll
    for (int reg = 0; reg < 4; ++reg) {
        int rloc = R0 + cg * 4 + reg;
        storeA4(Ahi, rloc, cb,
                oa[0][reg] / den_[0][reg], oa[1][reg] / den_[1][reg],
                oa[2][reg] / den_[2][reg], oa[3][reg] / den_[3][reg]);
    }
    __syncthreads();

    // ---- Phase D: out-proj (Wb = O); residual (x in regs); LN2 -> A-frags
    f32x4 ao[4];
#pragma unroll
    for (int nt = 0; nt < 4; ++nt) { float bo_ = outb[nt * 16 + cb]; ao[nt] = {bo_, bo_, bo_, bo_}; }
#pragma unroll
    for (int ks = 0; ks < 2; ++ks) {
        bf16x8 ah = readFrag(Ahi, R0, lane, ks, 128, 7);
#pragma unroll
        for (int nt = 0; nt < 4; ++nt) {
            bf16x8 bh, bl;
            readB(Wb, 4096, 4, ks, nt, lane, bh, bl);
            ao[nt] = MFMA_B16(ah, bh, ao[nt]);
            ao[nt] = MFMA_B16(ah, bl, ao[nt]);
        }
    }
    float g2[4], b2v[4];
#pragma unroll
    for (int nt = 0; nt < 4; ++nt) { g2[nt] = ln2g[nt * 16 + cb]; b2v[nt] = ln2b[nt * 16 + cb]; }
    float x2[4][4];
#pragma unroll
    for (int reg = 0; reg < 4; ++reg) {
        int rloc = R0 + cg * 4 + reg;
#pragma unroll
        for (int nt = 0; nt < 4; ++nt) x2[reg][nt] = x[reg][nt] + ao[nt][reg];
        float s = x2[reg][0] + x2[reg][1] + x2[reg][2] + x2[reg][3];
#pragma unroll
        for (int m = 1; m < 16; m <<= 1) s += __shfl_xor(s, m, 64);
        float mean = s * (1.0f / 64.0f);
        float d0 = x2[reg][0] - mean, d1 = x2[reg][1] - mean, d2 = x2[reg][2] - mean, d3 = x2[reg][3] - mean;
        float sq = d0 * d0 + d1 * d1 + d2 * d2 + d3 * d3;
#pragma unroll
        for (int m = 1; m < 16; m <<= 1) sq += __shfl_xor(sq, m, 64);
        float rr = rsqrtf(sq * (1.0f / 64.0f) + 1e-5f);
        storeA4(Ahi, rloc, cb,
                d0 * rr * g2[0] + b2v[0], d1 * rr * g2[1] + b2v[1],
                d2 * rr * g2[2] + b2v[2], d3 * rr * g2[3] + b2v[3]);
    }
    __syncthreads();     // O reads done; Wb free for FFN staging

    // ---- Phase E: FFN 64->256 (gelu) ->64, 2 chunks of 128 hidden, staged weights
    const unsigned short* pW1 = pk + 2 * OFF_W1;
    const unsigned short* pW2 = pk + 2 * OFF_W2;
    f32x4 ya[4];
#pragma unroll
    for (int nt = 0; nt < 4; ++nt) { float by = fb2[nt * 16 + cb]; ya[nt] = {by, by, by, by}; }

#pragma unroll
    for (int cc = 0; cc < 2; ++cc) {
        // stage W1 chunk cc (32 KB): global tile gt=ks*16+cc*8+n8 -> lds tile lt=ks*8+n8
#pragma unroll
        for (int it = 0; it < 8; ++it) {
            int i = it * 256 + tid;
            int half = i >> 10, j = i & 1023;
            int lt = j >> 6, lr = j & 63;
            int ksl = lt >> 3, n8 = lt & 7;
            int gt = ksl * 16 + cc * 8 + n8;
            *(u16x8*)(Wb + half * 8192 + (lt * 64 + lr) * 8) =
                *(const u16x8*)(pW1 + half * 16384 + (gt * 64 + lr) * 8);
        }
        __syncthreads();

        f32x4 ha[8];
#pragma unroll
        for (int n8 = 0; n8 < 8; ++n8) {
            float hb = fb1[(cc * 8 + n8) * 16 + cb];
            ha[n8] = {hb, hb, hb, hb};
        }
#pragma unroll
        for (int ks = 0; ks < 2; ++ks) {
            bf16x8 ah = readFrag(Ahi, R0, lane, ks, 128, 7);
#pragma unroll
            for (int n8 = 0; n8 < 8; ++n8) {
                bf16x8 bh, bl;
                readB(Wb, 8192, 8, ks, n8, lane, bh, bl);
                ha[n8] = MFMA_B16(ah, bh, ha[n8]);
                ha[n8] = MFMA_B16(ah, bl, ha[n8]);
            }
        }
        // gelu -> H frags (wave-private rows)
#pragma unroll
        for (int reg = 0; reg < 4; ++reg) {
            int rloc = R0 + cg * 4 + reg;
            u16x8 u;
#pragma unroll
            for (int n8 = 0; n8 < 8; ++n8) {
                float h = ha[n8][reg];
                h = 0.5f * h * (1.0f + erff(h * 0.70710678118654752f));
                u[n8] = (unsigned short)rne16(h);
            }
            int bo = (rloc * 256 + cb * 16) ^ ((rloc & 15) << 4);
            *(u16x8*)((char*)Hhi + bo) = u;
        }
        __syncthreads();     // W1 reads done

        // stage W2 chunk cc (32 KB): contiguous tiles [cc*16, cc*16+16)
#pragma unroll
        for (int it = 0; it < 8; ++it) {
            int i = it * 256 + tid;
            int half = i >> 10, j = i & 1023;
            *(u16x8*)(Wb + half * 8192 + j * 8) =
                *(const u16x8*)(pW2 + half * 16384 + cc * 8192 + j * 8);
        }
        __syncthreads();

#pragma unroll
        for (int ks2 = 0; ks2 < 4; ++ks2) {
            bf16x8 ah = readFrag(Hhi, R0, lane, ks2, 256, 15);
#pragma unroll
            for (int nt = 0; nt < 4; ++nt) {
                bf16x8 bh, bl;
                readB(Wb, 8192, 4, ks2, nt, lane, bh, bl);
                ya[nt] = MFMA_B16(ah, bh, ya[nt]);
                ya[nt] = MFMA_B16(ah, bl, ya[nt]);
            }
        }
        __syncthreads();     // W2 reads done before next chunk restage
    }

    // ---- final: x2 + ffn -> Hf (wave-private rows), then coalesced float4 store
#pragma unroll
    for (int reg = 0; reg < 4; ++reg) {
        int rloc = R0 + cg * 4 + reg;
#pragma unroll
        for (int nt = 0; nt < 4; ++nt)
            Hf[rloc * 64 + nt * 16 + cb] = x2[reg][nt] + ya[nt][reg];
    }
    __syncthreads();
    {
        float4* dst4 = (float4*)(fout + ((size_t)(pi * B_ + b) * N_ + nn0) * 64);
        const float4* src4 = (const float4*)Hf;
#pragma unroll
        for (int it = 0; it < 4; ++it) {
            int i = it * 256 + tid;
            dst4[i] = src4[i];
        }
    }
}

// ---------- output transpose ----------
__global__ __launch_bounds__(256) void output_kernel(const float* __restrict__ f,
                                                     float* __restrict__ out) {
    __shared__ float tile[64][65];
    int blk = blockIdx.x;
    int ntile = blk & 255;
    int bp = blk >> 8;
    int b = bp / 3, p = bp - b * 3;
    int n0 = ntile * 64;
    int tr = threadIdx.x >> 6, tc = threadIdx.x & 63;

    const float* src = f + ((size_t)(p * B_ + b) * N_ + n0) * C_;
#pragma unroll
    for (int it = 0; it < 16; ++it) {
        int r = it * 4 + tr;
        tile[r][tc] = src[(size_t)r * C_ + tc];
    }
    __syncthreads();
    float* dst = out + (size_t)(b * 3 + p) * C_ * N_ + n0;
#pragma unroll
    for (int it = 0; it < 16; ++it) {
        int cidx = it * 4 + tr;
        dst[(size_t)cidx * N_ + tc] = tile[tc][cidx];
    }
}

extern "C" void kernel_launch(void* const* d_in, const int* in_sizes, int n_in,
                              void* d_out, int out_size, void* d_ws, size_t ws_size,
                              hipStream_t stream) {
    const float* img_feats = (const float*)d_in[0];
    const float* pts       = (const float*)d_in[1];
    const float* query     = (const float*)d_in[2];
    const float* ln1_g     = (const float*)d_in[3];
    const float* ln1_b     = (const float*)d_in[4];
    const float* ln2_g     = (const float*)d_in[5];
    const float* ln2_b     = (const float*)d_in[6];
    const float* in_w      = (const float*)d_in[7];
    const float* in_b      = (const float*)d_in[8];
    const float* out_w     = (const float*)d_in[9];
    const float* out_b     = (const float*)d_in[10];
    const float* ffn_w1    = (const float*)d_in[11];
    const float* ffn_b1    = (const float*)d_in[12];
    const float* ffn_w2    = (const float*)d_in[13];
    const float* ffn_b2    = (const float*)d_in[14];

    const size_t FEAT_SZ = (size_t)3 * B_ * N_ * C_;  // 6,291,456

    float* ws = (float*)d_ws;
    float* ftr      = ws;                                  // FTR_SZ floats
    int* counts     = (int*)(ftr + FTR_SZ);                // SEG_SZ
    int* offsets    = counts + SEG_SZ;                     // NSEG*OSTRIDE
    int* cursors    = offsets + (size_t)NSEG * OSTRIDE;    // SEG_SZ
    float4* ent     = (float4*)(cursors + SEG_SZ);         // SEG_SZ float4
    float* fA       = (float*)(ent + SEG_SZ);
    float* fB       = fA + FEAT_SZ;
    unsigned short* pk_base = (unsigned short*)(fB + FEAT_SZ);

    // init plane feats with query tensors
    init_feats<<<(3 * N_ * C_ + 255) / 256, 256, 0, stream>>>(query, fA);

    // ---- splat via binning + strip gather (no float atomics)
    zero_counts<<<(int)(SEG_SZ / 4 + 255) / 256, 256, 0, stream>>>((int4*)counts, (int)(SEG_SZ / 4));
    transpose_feats<<<NBV * 256, 256, 0, stream>>>(img_feats, ftr);
    bin_count<<<(NBV * N_) / 256, 256, 0, stream>>>(pts, counts);
    scan_bins<<<NSEG, 256, 0, stream>>>(counts, offsets, cursors);
    scatter_pts<<<(NBV * N_) / 256, 256, 0, stream>>>(pts, cursors, ent);
    gather_splat<<<dim3(512, 3, B_), 256, 0, stream>>>(ftr, offsets, ent, fA);

    // pack weights
    for (int l = 0; l < NL_; ++l) {
        pack_layer<<<(PK_ELEMS + 255) / 256, 256, 0, stream>>>(
            in_w + (size_t)l * 3 * C_ * C_, out_w + (size_t)l * C_ * C_,
            ffn_w1 + (size_t)l * 4 * C_ * C_, ffn_w2 + (size_t)l * C_ * 4 * C_,
            pk_base + (size_t)l * LAYER_PK);
    }

    dim3 pgrid((B_ * N_) / 64, 3);
    for (int l = 0; l < NL_; ++l) {
        const float* fin = (l == 0) ? fA : fB;
        float* fout      = (l == 0) ? fB : fA;
        plane_mfma<<<pgrid, 256, 0, stream>>>(
            fin, fout, pk_base + (size_t)l * LAYER_PK,
            ln1_g + l * C_, ln1_b + l * C_,
            ln2_g + l * C_, ln2_b + l * C_,
            in_b + l * 3 * C_, out_b + l * C_,
            ffn_b1 + l * 4 * C_, ffn_b2 + l * C_);
    }

    output_kernel<<<B_ * 3 * (N_ / 64), 256, 0, stream>>>(fA, (float*)d_out);
}

// Round 9
// 456.832 us; speedup vs baseline: 10.8167x; 1.5335x over previous
//
#include <hip/hip_runtime.h>
#include <math.h>

constexpr int R_ = 128, C_ = 64, NL_ = 2, B_ = 2, V_ = 4;
constexpr int N_ = R_ * R_;          // 16384
constexpr int T_ = 6;

typedef __attribute__((ext_vector_type(8))) short bf16x8;
typedef __attribute__((ext_vector_type(4))) float f32x4;
typedef __attribute__((ext_vector_type(4))) unsigned short u16x4;
typedef __attribute__((ext_vector_type(8))) unsigned short u16x8;

#define MFMA_B16(a, b, c) __builtin_amdgcn_mfma_f32_16x16x32_bf16((a), (b), (c), 0, 0, 0)

// packed-weight element offsets (per layer, in elements)
constexpr int OFF_O = 12288, OFF_W1 = 16384, OFF_W2 = 32768;
constexpr int PK_ELEMS = 49152;
constexpr int LAYER_PK = 2 * PK_ELEMS;   // ushorts per layer (hi+lo)

// splat-path sizes
constexpr int NBV = B_ * V_;                       // 8
constexpr size_t FTR_SZ = (size_t)NBV * N_ * C_;   // 8,388,608 floats
constexpr int NSEG = 3 * NBV;                      // 24 segments
constexpr size_t SEG_SZ = (size_t)NSEG * N_;       // 393,216 ints
constexpr int OSTRIDE = N_ + 128;                  // offsets stride (sentinel pad)
constexpr size_t KV_SZ = (size_t)3 * B_ * T_ * 128 * 64;   // 294,912 floats

// ---------- helpers ----------
__device__ inline unsigned rne16(float x) {
    unsigned b = __float_as_uint(x);
    return (b + 0x7fffu + ((b >> 16) & 1u)) >> 16;
}

__device__ inline float wsum(float v) {
#pragma unroll
    for (int m = 1; m < 64; m <<= 1) v += __shfl_xor(v, m, 64);
    return v;
}

__device__ inline float lnorm(float v, float g, float b) {
    float m = wsum(v) * (1.f / 64.f);
    float d = v - m;
    float var = wsum(d * d) * (1.f / 64.f);
    return d * rsqrtf(var + 1e-5f) * g + b;
}

// stage a 64x64 row-major fp32 matrix into LDS buf[c*68 + u]
__device__ inline void stageW(const float* __restrict__ W, float* buf, int tid) {
#pragma unroll
    for (int it = 0; it < 4; ++it) {
        int idx4 = it * 256 + tid;
        int r = idx4 >> 4, u4 = idx4 & 15;
        float4 v = ((const float4*)W)[idx4];
        *(float4*)&buf[r * 68 + u4 * 4] = v;
    }
}

// read A-fragment (16x32 bf16) for wave's M-tile from swizzled LDS
__device__ inline bf16x8 readFrag(const unsigned short* base, int rowBase, int lane,
                                  int ks, int rowStrideB, int swzMask) {
    int rowloc = rowBase + (lane & 15);
    int off = rowloc * rowStrideB + ks * 64 + ((lane >> 4) & 3) * 16;
    off ^= ((rowloc & swzMask) << 4);
    return *(const bf16x8*)((const char*)base + off);
}

// store 4 bf16-hi values (K-permuted: p = cb*4+nt) as one 8B write
__device__ inline void storeA4(unsigned short* base, int rloc, int cb,
                               float v0, float v1, float v2, float v3) {
    u16x4 u;
    u[0] = (unsigned short)rne16(v0);
    u[1] = (unsigned short)rne16(v1);
    u[2] = (unsigned short)rne16(v2);
    u[3] = (unsigned short)rne16(v3);
    int bo = (rloc * 128 + cb * 8) ^ ((rloc & 7) << 4);
    *(u16x4*)((char*)base + bo) = u;
}

// load B-fragment pair (hi,lo) from a weight table (global or LDS)
__device__ inline void readB(const unsigned short* matHi, int E, int NTm, int ks, int nt,
                             int lane, bf16x8& bh, bf16x8& bl) {
    int off = (((ks * NTm + nt) << 6) + lane) << 3;
    bh = *(const bf16x8*)(matHi + off);
    bl = *(const bf16x8*)(matHi + E + off);
}

// ---------- pack all weights of one layer (K-permuted, split hi/lo) ----------
__global__ __launch_bounds__(256) void pack_layer(const float* __restrict__ iw,
                                                  const float* __restrict__ ow,
                                                  const float* __restrict__ w1,
                                                  const float* __restrict__ w2,
                                                  unsigned short* __restrict__ pk) {
    int idx = blockIdx.x * 256 + threadIdx.x;
    if (idx >= PK_ELEMS) return;
    const float* W;
    int O, K, base, mode, lidx;
    if (idx < 12288)      { int m = idx >> 12; lidx = idx & 4095; W = iw + m * 4096; O = 64;  K = 64;  base = m * 4096; mode = 0; }
    else if (idx < 16384) { lidx = idx - 12288; W = ow; O = 64;  K = 64;  base = OFF_O;  mode = 0; }
    else if (idx < 32768) { lidx = idx - 16384; W = w1; O = 256; K = 64;  base = OFF_W1; mode = 0; }
    else                  { lidx = idx - 32768; W = w2; O = 64;  K = 256; base = OFF_W2; mode = 1; }
    int j = lidx & 7, l = (lidx >> 3) & 63, rem = lidx >> 9;
    int NTm = O >> 4;
    int nt = rem & (NTm - 1), ks = rem / NTm;
    int kfrag = ks * 32 + ((l >> 4) & 3) * 8 + j;
    int k;
    if (mode == 0) { int p = kfrag & 63; k = (p & 3) * 16 + (p >> 2); }
    else { int cc = kfrag >> 7; int pl = kfrag & 127; k = (cc * 8 + (pl & 7)) * 16 + (pl >> 3); }
    int o = nt * 16 + (l & 15);
    float w = W[(size_t)o * K + k];
    unsigned hb = rne16(w);
    float hf = __uint_as_float(hb << 16);
    unsigned lb = rne16(w - hf);
    int E = O * K;
    pk[2 * base + lidx] = (unsigned short)hb;
    pk[2 * base + E + lidx] = (unsigned short)lb;
}

// ---------- init plane feats with query tensors ----------
__global__ __launch_bounds__(256) void init_feats(const float* __restrict__ q,
                                                  float* __restrict__ f0) {
    int idx = blockIdx.x * 256 + threadIdx.x;
    if (idx >= 3 * N_ * C_) return;
    int p = idx / (N_ * C_);
    int rem = idx - p * (N_ * C_);
    float val = q[idx];
    f0[(size_t)(p * B_ + 0) * N_ * C_ + rem] = val;
    f0[(size_t)(p * B_ + 1) * N_ * C_ + rem] = val;
}

// ---------- zero bin counts ----------
__global__ __launch_bounds__(256) void zero_counts(int4* __restrict__ p, int n4) {
    int i = blockIdx.x * 256 + threadIdx.x;
    if (i < n4) p[i] = make_int4(0, 0, 0, 0);
}

// ---------- transpose features: [bv][c][n] -> [bv][n][c] ----------
__global__ __launch_bounds__(256) void transpose_feats(const float* __restrict__ src,
                                                       float* __restrict__ dst) {
    __shared__ float tile[64][65];
    int blk = blockIdx.x;             // NBV * 256
    int ntile = blk & 255;
    int bv = blk >> 8;
    int n0 = ntile * 64;
    int tr = threadIdx.x >> 6, tc = threadIdx.x & 63;
    const float* s = src + (size_t)bv * C_ * N_;
#pragma unroll
    for (int it = 0; it < 16; ++it) {
        int c = it * 4 + tr;
        tile[c][tc] = s[(size_t)c * N_ + n0 + tc];
    }
    __syncthreads();
    float* d = dst + ((size_t)bv * N_ + n0) * C_;
#pragma unroll
    for (int it = 0; it < 16; ++it) {
        int r = it * 4 + tr;
        d[(size_t)r * C_ + tc] = tile[tc][r];
    }
}

// ---------- bin count ----------
__global__ __launch_bounds__(256) void bin_count(const float* __restrict__ pts,
                                                 int* __restrict__ counts) {
    int idx = blockIdx.x * 256 + threadIdx.x;     // [0, NBV*N)
    if (idx >= NBV * N_) return;
    int bv = idx >> 14;
    const float* p = pts + (size_t)idx * 3;
    float px = p[0], py = p[1], pz = p[2];
    const float HI = (float)(127.0 - 1e-5);
    float gx = fminf(fmaxf((px + 1.0f) * 127.0f / 2.0f, 0.0f), HI);
    float gy = fminf(fmaxf((py + 1.0f) * 127.0f / 2.0f, 0.0f), HI);
    float gz = fminf(fmaxf((pz + 1.0f) * 127.0f / 2.0f, 0.0f), HI);
    int x0 = (int)gx, y0 = (int)gy, z0 = (int)gz;
    atomicAdd(&counts[(0 * NBV + bv) * N_ + x0 * R_ + y0], 1);
    atomicAdd(&counts[(1 * NBV + bv) * N_ + x0 * R_ + z0], 1);
    atomicAdd(&counts[(2 * NBV + bv) * N_ + y0 * R_ + z0], 1);
}

// ---------- per-segment exclusive scan (16384 bins each) + sentinel pad ----------
__global__ __launch_bounds__(256) void scan_bins(const int* __restrict__ counts,
                                                 int* __restrict__ offsets,
                                                 int* __restrict__ cursors) {
    __shared__ int part[256];
    int seg = blockIdx.x;             // 24
    int t = threadIdx.x;
    const int* c = counts + (size_t)seg * N_;
    int sum = 0;
    for (int i = 0; i < 64; ++i) sum += c[t * 64 + i];
    part[t] = sum;
    __syncthreads();
    if (t == 0) {
        int run = 0;
        for (int i = 0; i < 256; ++i) { int v = part[i]; part[i] = run; run += v; }
    }
    __syncthreads();
    int run = part[t];
    int* o = offsets + (size_t)seg * OSTRIDE;
    int* cu = cursors + (size_t)seg * N_;
    for (int i = 0; i < 64; ++i) {
        o[t * 64 + i] = run;
        cu[t * 64 + i] = run;
        run += c[t * 64 + i];
    }
    if (t < 128) o[N_ + t] = N_;      // sentinel: total per segment == N_
}

// ---------- scatter full point records into bin-sorted entry lists ----------
__global__ __launch_bounds__(256) void scatter_pts(const float* __restrict__ pts,
                                                   int* __restrict__ cursors,
                                                   float4* __restrict__ ent) {
    int idx = blockIdx.x * 256 + threadIdx.x;
    if (idx >= NBV * N_) return;
    int bv = idx >> 14, n = idx & (N_ - 1);
    const float* p = pts + (size_t)idx * 3;
    float px = p[0], py = p[1], pz = p[2];
    const float HI = (float)(127.0 - 1e-5);
    float gx = fminf(fmaxf((px + 1.0f) * 127.0f / 2.0f, 0.0f), HI);
    float gy = fminf(fmaxf((py + 1.0f) * 127.0f / 2.0f, 0.0f), HI);
    float gz = fminf(fmaxf((pz + 1.0f) * 127.0f / 2.0f, 0.0f), HI);
    int x0 = (int)gx, y0 = (int)gy, z0 = (int)gz;
    float4 e;
    e.x = __uint_as_float((unsigned)n);
    e.y = gx - (float)x0; e.z = gy - (float)y0; e.w = gz - (float)z0;
    int s0 = 0 * NBV + bv, s1 = 1 * NBV + bv, s2 = 2 * NBV + bv;
    int p0 = atomicAdd(&cursors[(size_t)s0 * N_ + x0 * R_ + y0], 1);
    ent[(size_t)s0 * N_ + p0] = e;
    int p1 = atomicAdd(&cursors[(size_t)s1 * N_ + x0 * R_ + z0], 1);
    ent[(size_t)s1 * N_ + p1] = e;
    int p2 = atomicAdd(&cursors[(size_t)s2 * N_ + y0 * R_ + z0], 1);
    ent[(size_t)s2 * N_ + p2] = e;
}

// ---------- gather splat: one wave per (plane, b, 8-cell row strip), all 4 views ----------
__global__ __launch_bounds__(256) void gather_splat(
    const float* __restrict__ ftr, const int* __restrict__ offsets,
    const float4* __restrict__ ent, float* __restrict__ f0) {
    int wid = threadIdx.x >> 6, lane = threadIdx.x & 63;
    int strip = blockIdx.x * 4 + wid;         // [0, 2048)
    int pi = blockIdx.y, b = blockIdx.z;
    int a = strip >> 4;                       // cell row
    int c0 = (strip & 15) << 3;               // first cell col of strip

    float total[8];
#pragma unroll
    for (int k = 0; k < 8; ++k) total[k] = 0.f;

    for (int v = 0; v < V_; ++v) {
        int bv = b * V_ + v;
        int seg = pi * NBV + bv;
        const int* ob = offsets + (size_t)seg * OSTRIDE;
        const float4* eb = ent + (size_t)seg * N_;
        const float* fbase = ftr + (size_t)bv * N_ * C_ + lane;
        float facc[8], wsum_[8];
#pragma unroll
        for (int k = 0; k < 8; ++k) { facc[k] = 0.f; wsum_[k] = 0.f; }

        for (int dr = 0; dr < 2; ++dr) {
            int ba = a - dr;
            if (ba < 0) continue;
            int rowbase = ba * R_ + c0 - 1;
            int o[10];
#pragma unroll
            for (int jj = 0; jj < 10; ++jj)
                o[jj] = ob[max(rowbase + jj, 0)];
#pragma unroll
            for (int j = 0; j < 9; ++j) {
                if (j == 0 && c0 == 0) continue;    // bin col -1 doesn't exist
                int e = o[j + 1];
                for (int i = o[j]; i < e; ++i) {
                    float4 r = eb[i];
                    int n = (int)__float_as_uint(r.x);
                    float wx = r.y, wy = r.z, wz = r.w;
                    float ax = 1.f - wx, ay = 1.f - wy, az = 1.f - wz;
                    float XA = dr ? wx : ax;
                    float YA = dr ? wy : ay;
                    float w0 = (pi == 2 ? ax * YA : XA * ay) * az;
                    float w1 = (pi == 0) ? XA * wy * az : XA * YA * wz;
                    float f = fbase[(size_t)n * C_];
                    if (j > 0) { facc[j - 1] += w0 * f; wsum_[j - 1] += w0; }
                    if (j < 8) { facc[j] += w1 * f; wsum_[j] += w1; }
                }
            }
        }
#pragma unroll
        for (int k = 0; k < 8; ++k)
            total[k] += facc[k] / fmaxf(wsum_[k], 1e-8f);
    }
    float* dst = f0 + (((size_t)(pi * B_ + b)) * N_ + a * R_ + c0) * C_ + lane;
#pragma unroll
    for (int k = 0; k < 8; ++k)
        dst[(size_t)k * C_] += 0.25f * total[k];
}

// ---------- ctx k/v table: 4608 rows = (pi, b, t, pos) ----------
__global__ __launch_bounds__(256) void ctx_kv(
    const float* __restrict__ fin,
    const float* __restrict__ ln1g, const float* __restrict__ ln1b,
    const float* __restrict__ inw, const float* __restrict__ inb,
    float* __restrict__ kvk, float* __restrict__ kvv) {
    __shared__ float s_wk[64 * 68];
    __shared__ float s_wv[64 * 68];
    __shared__ float s_act[32 * 68];
    int tid = threadIdx.x, wid = tid >> 6, lane = tid & 63;
    stageW(inw + 4096, s_wk, tid);     // Wk
    stageW(inw + 8192, s_wv, tid);     // Wv

    int rid0 = blockIdx.x * 32 + wid * 8;
    int seg = rid0 >> 7;               // (pi*2+b)*6 + t
    int pos0 = rid0 & 127;
    int t = seg % 6;
    int pib = seg / 6;
    int pi = pib >> 1, b = pib & 1;
    int khalf = (t < 3) ? t : t - 3;
    float sk = (float)(khalf - 1);
    bool tl = t < 3;
    int io;
    if (pi == 0) io = tl ? 1 : 2;
    else if (pi == 1) io = tl ? 0 : 2;
    else io = tl ? 0 : 1;
    const float* Fio = fin + (size_t)(io * B_ + b) * N_ * 64;
    float g1 = ln1g[lane], b1 = ln1b[lane];

#pragma unroll
    for (int rr = 0; rr < 8; ++rr) {
        int pos = pos0 + rr;
        float lp = -1.0f + (2.0f * (float)pos) / 127.0f;
        float caf, cbf;
        if (pi == 0) { caf = lp; cbf = sk; }
        else if (pi == 1) { if (tl) { caf = lp; cbf = sk; } else { caf = sk; cbf = lp; } }
        else { caf = sk; cbf = lp; }
        float ua = fminf(fmaxf((caf * 0.5f + 0.5f) * 127.0f, 0.0f), 127.0f);
        float ub = fminf(fmaxf((cbf * 0.5f + 0.5f) * 127.0f, 0.0f), 127.0f);
        float gxp = fminf(fmaxf(((ua + 1.0f) * 0.5f) * 127.0f, 0.0f), 127.0f);
        float gyp = fminf(fmaxf(((ub + 1.0f) * 0.5f) * 127.0f, 0.0f), 127.0f);
        int xx0 = (int)gxp, yy0 = (int)gyp;
        int xx1 = xx0 + 1 < 128 ? xx0 + 1 : 127;
        int yy1 = yy0 + 1 < 128 ? yy0 + 1 : 127;
        float wx = gxp - (float)xx0, wy = gyp - (float)yy0;
        float v00 = Fio[(size_t)(yy0 * R_ + xx0) * 64 + lane];
        float v01 = Fio[(size_t)(yy0 * R_ + xx1) * 64 + lane];
        float v10 = Fio[(size_t)(yy1 * R_ + xx0) * 64 + lane];
        float v11 = Fio[(size_t)(yy1 * R_ + xx1) * 64 + lane];
        float cv = (1.0f - wy) * ((1.0f - wx) * v00 + wx * v01) +
                   wy * ((1.0f - wx) * v10 + wx * v11);
        s_act[(wid * 8 + rr) * 68 + lane] = lnorm(cv, g1, b1);
    }
    __syncthreads();

    float kk[8], vv[8];
    float bk = inb[64 + lane], bv = inb[128 + lane];
#pragma unroll
    for (int rr = 0; rr < 8; ++rr) { kk[rr] = bk; vv[rr] = bv; }
    const float* wrk = s_wk + lane * 68;
    const float* wrv = s_wv + lane * 68;
#pragma unroll 4
    for (int g = 0; g < 16; ++g) {
        float4 wk4 = *(const float4*)(wrk + g * 4);
        float4 wv4 = *(const float4*)(wrv + g * 4);
#pragma unroll
        for (int rr = 0; rr < 8; ++rr) {
            float4 xv = *(const float4*)(s_act + (wid * 8 + rr) * 68 + g * 4);
            kk[rr] = fmaf(xv.x, wk4.x, fmaf(xv.y, wk4.y, fmaf(xv.z, wk4.z, fmaf(xv.w, wk4.w, kk[rr]))));
            vv[rr] = fmaf(xv.x, wv4.x, fmaf(xv.y, wv4.y, fmaf(xv.z, wv4.z, fmaf(xv.w, wv4.w, vv[rr]))));
        }
    }
#pragma unroll
    for (int rr = 0; rr < 8; ++rr) {
        size_t o = ((size_t)seg * 128 + pos0 + rr) * 64 + lane;
        kvk[o] = kk[rr];
        kvv[o] = vv[rr];
    }
}

// ---------- fused per-plane transformer layer (MFMA, precomputed k/v) ----------
__global__ __launch_bounds__(256, 2) void plane_mfma(
    const float* __restrict__ fin, float* __restrict__ fout,
    const unsigned short* __restrict__ pk,
    const float* __restrict__ kvk, const float* __restrict__ kvv,
    const float* __restrict__ ln1g, const float* __restrict__ ln1b,
    const float* __restrict__ ln2g, const float* __restrict__ ln2b,
    const float* __restrict__ inb, const float* __restrict__ outb,
    const float* __restrict__ fb1, const float* __restrict__ fb2) {
    __shared__ __attribute__((aligned(16))) unsigned short Wb[16384];  // 32 KB weight stage
    __shared__ __attribute__((aligned(16))) unsigned short Ahi[4096];  // 8 KB A-frags
    __shared__ __attribute__((aligned(16))) float Hf[4096];            // 16 KB H-frags / out stage
    unsigned short* Hhi = (unsigned short*)Hf;

    const int tid = threadIdx.x;
    const int wid = tid >> 6, lane = tid & 63;
    const int cg = lane >> 4, cb = lane & 15;
    const int pi = blockIdx.y;
    const int R0 = wid * 16;
    const int rowbase = blockIdx.x * 64;
    const int b = rowbase >> 14;
    const int nn0 = rowbase & (N_ - 1);
    const int i0 = nn0 >> 7, j0 = nn0 & 127;

    // ---- stage Q (hi+lo, 16 KB) into Wb[0:8192]
#pragma unroll
    for (int i = 0; i < 4; ++i)
        *(u16x8*)(Wb + (i * 256 + tid) * 8) = *(const u16x8*)(pk + (i * 256 + tid) * 8);

    float g1[4], b1v[4];
#pragma unroll
    for (int nt = 0; nt < 4; ++nt) { g1[nt] = ln1g[nt * 16 + cb]; b1v[nt] = ln1b[nt * 16 + cb]; }

    // ---- Phase A: load x (kept in regs), LN1 -> A-frags (wave-private LDS rows)
    float x[4][4];
    const float* finp = fin + ((size_t)(pi * B_ + b) * N_ + nn0) * 64;
#pragma unroll
    for (int reg = 0; reg < 4; ++reg) {
        int rloc = R0 + cg * 4 + reg;
#pragma unroll
        for (int nt = 0; nt < 4; ++nt) x[reg][nt] = finp[(size_t)rloc * 64 + nt * 16 + cb];
        float s = x[reg][0] + x[reg][1] + x[reg][2] + x[reg][3];
#pragma unroll
        for (int m = 1; m < 16; m <<= 1) s += __shfl_xor(s, m, 64);
        float mean = s * (1.0f / 64.0f);
        float d0 = x[reg][0] - mean, d1 = x[reg][1] - mean, d2 = x[reg][2] - mean, d3 = x[reg][3] - mean;
        float sq = d0 * d0 + d1 * d1 + d2 * d2 + d3 * d3;
#pragma unroll
        for (int m = 1; m < 16; m <<= 1) sq += __shfl_xor(sq, m, 64);
        float rr = rsqrtf(sq * (1.0f / 64.0f) + 1e-5f);
        storeA4(Ahi, rloc, cb,
                d0 * rr * g1[0] + b1v[0], d1 * rr * g1[1] + b1v[1],
                d2 * rr * g1[2] + b1v[2], d3 * rr * g1[3] + b1v[3]);
    }
    __syncthreads();

    // ---- Phase B: q = xn @ Wq^T + bq  (Wb = Q)
    f32x4 qa[4];
#pragma unroll
    for (int nt = 0; nt < 4; ++nt) { float bq = inb[nt * 16 + cb]; qa[nt] = {bq, bq, bq, bq}; }
#pragma unroll
    for (int ks = 0; ks < 2; ++ks) {
        bf16x8 ah = readFrag(Ahi, R0, lane, ks, 128, 7);
#pragma unroll
        for (int nt = 0; nt < 4; ++nt) {
            bf16x8 bh, bl;
            readB(Wb, 4096, 4, ks, nt, lane, bh, bl);
            qa[nt] = MFMA_B16(ah, bh, qa[nt]);
            qa[nt] = MFMA_B16(ah, bl, qa[nt]);
        }
    }

    // ---- Phase C: attention with precomputed k/v (no barriers, no LDS)
    const float* kvkb = kvk + (size_t)((pi * 2 + b) * 6) * 128 * 64;
    const float* kvvb = kvv + (size_t)((pi * 2 + b) * 6) * 128 * 64;
    float den_[4][4];
    f32x4 oa[4];
#pragma unroll
    for (int nt = 0; nt < 4; ++nt) {
        oa[nt] = {0.f, 0.f, 0.f, 0.f};
#pragma unroll
        for (int reg = 0; reg < 4; ++reg) den_[nt][reg] = 0.f;
    }

    // t = 0..2: k/v depend on j (per-row)
#pragma unroll
    for (int t = 0; t < 3; ++t) {
        float kvr[4][4], vvr[4][4];
#pragma unroll
        for (int reg = 0; reg < 4; ++reg) {
            int pos = j0 + R0 + cg * 4 + reg;
            const float* kr = kvkb + ((size_t)t * 128 + pos) * 64 + cb;
            const float* vr = kvvb + ((size_t)t * 128 + pos) * 64 + cb;
#pragma unroll
            for (int nt = 0; nt < 4; ++nt) {
                kvr[reg][nt] = kr[nt * 16];
                vvr[reg][nt] = vr[nt * 16];
            }
        }
#pragma unroll
        for (int nt = 0; nt < 4; ++nt) {
            float d0 = qa[nt][0] * kvr[0][nt];
            float d1 = qa[nt][1] * kvr[1][nt];
            float d2 = qa[nt][2] * kvr[2][nt];
            float d3 = qa[nt][3] * kvr[3][nt];
#pragma unroll
            for (int m = 1; m < 16; m <<= 1) {
                d0 += __shfl_xor(d0, m, 64);
                d1 += __shfl_xor(d1, m, 64);
                d2 += __shfl_xor(d2, m, 64);
                d3 += __shfl_xor(d3, m, 64);
            }
            float e0 = __expf(d0 * 0.25f), e1 = __expf(d1 * 0.25f);
            float e2 = __expf(d2 * 0.25f), e3 = __expf(d3 * 0.25f);
            den_[nt][0] += e0; den_[nt][1] += e1; den_[nt][2] += e2; den_[nt][3] += e3;
            oa[nt][0] += e0 * vvr[0][nt];
            oa[nt][1] += e1 * vvr[1][nt];
            oa[nt][2] += e2 * vvr[2][nt];
            oa[nt][3] += e3 * vvr[3][nt];
        }
    }
    // t = 3..5: k/v depend on i (block-uniform row i0)
#pragma unroll
    for (int t = 3; t < 6; ++t) {
        float ku[4], vu[4];
        const float* kr = kvkb + ((size_t)t * 128 + i0) * 64 + cb;
        const float* vr = kvvb + ((size_t)t * 128 + i0) * 64 + cb;
#pragma unroll
        for (int nt = 0; nt < 4; ++nt) { ku[nt] = kr[nt * 16]; vu[nt] = vr[nt * 16]; }
#pragma unroll
        for (int nt = 0; nt < 4; ++nt) {
            float d0 = qa[nt][0] * ku[nt];
            float d1 = qa[nt][1] * ku[nt];
            float d2 = qa[nt][2] * ku[nt];
            float d3 = qa[nt][3] * ku[nt];
#pragma unroll
            for (int m = 1; m < 16; m <<= 1) {
                d0 += __shfl_xor(d0, m, 64);
                d1 += __shfl_xor(d1, m, 64);
                d2 += __shfl_xor(d2, m, 64);
                d3 += __shfl_xor(d3, m, 64);
            }
            float e0 = __expf(d0 * 0.25f), e1 = __expf(d1 * 0.25f);
            float e2 = __expf(d2 * 0.25f), e3 = __expf(d3 * 0.25f);
            den_[nt][0] += e0; den_[nt][1] += e1; den_[nt][2] += e2; den_[nt][3] += e3;
            oa[nt][0] += e0 * vu[nt];
            oa[nt][1] += e1 * vu[nt];
            oa[nt][2] += e2 * vu[nt];
            oa[nt][3] += e3 * vu[nt];
        }
    }
    __syncthreads();     // all waves past q-proj; Wb free

    // ---- stage O (16 KB) into Wb[0:8192]; write o/den -> A-frags
#pragma unroll
    for (int i = 0; i < 4; ++i)
        *(u16x8*)(Wb + (i * 256 + tid) * 8) = *(const u16x8*)(pk + 24576 + (i * 256 + tid) * 8);
#pragma unroll
    for (int reg = 0; reg < 4; ++reg) {
        int rloc = R0 + cg * 4 + reg;
        storeA4(Ahi, rloc, cb,
                oa[0][reg] / den_[0][reg], oa[1][reg] / den_[1][reg],
                oa[2][reg] / den_[2][reg], oa[3][reg] / den_[3][reg]);
    }
    __syncthreads();

    // ---- Phase D: out-proj (Wb = O); residual (x in regs); LN2 -> A-frags
    f32x4 ao[4];
#pragma unroll
    for (int nt = 0; nt < 4; ++nt) { float bo_ = outb[nt * 16 + cb]; ao[nt] = {bo_, bo_, bo_, bo_}; }
#pragma unroll
    for (int ks = 0; ks < 2; ++ks) {
        bf16x8 ah = readFrag(Ahi, R0, lane, ks, 128, 7);
#pragma unroll
        for (int nt = 0; nt < 4; ++nt) {
            bf16x8 bh, bl;
            readB(Wb, 4096, 4, ks, nt, lane, bh, bl);
            ao[nt] = MFMA_B16(ah, bh, ao[nt]);
            ao[nt] = MFMA_B16(ah, bl, ao[nt]);
        }
    }
    float g2[4], b2v[4];
#pragma unroll
    for (int nt = 0; nt < 4; ++nt) { g2[nt] = ln2g[nt * 16 + cb]; b2v[nt] = ln2b[nt * 16 + cb]; }
    float x2[4][4];
#pragma unroll
    for (int reg = 0; reg < 4; ++reg) {
        int rloc = R0 + cg * 4 + reg;
#pragma unroll
        for (int nt = 0; nt < 4; ++nt) x2[reg][nt] = x[reg][nt] + ao[nt][reg];
        float s = x2[reg][0] + x2[reg][1] + x2[reg][2] + x2[reg][3];
#pragma unroll
        for (int m = 1; m < 16; m <<= 1) s += __shfl_xor(s, m, 64);
        float mean = s * (1.0f / 64.0f);
        float d0 = x2[reg][0] - mean, d1 = x2[reg][1] - mean, d2 = x2[reg][2] - mean, d3 = x2[reg][3] - mean;
        float sq = d0 * d0 + d1 * d1 + d2 * d2 + d3 * d3;
#pragma unroll
        for (int m = 1; m < 16; m <<= 1) sq += __shfl_xor(sq, m, 64);
        float rr = rsqrtf(sq * (1.0f / 64.0f) + 1e-5f);
        storeA4(Ahi, rloc, cb,
                d0 * rr * g2[0] + b2v[0], d1 * rr * g2[1] + b2v[1],
                d2 * rr * g2[2] + b2v[2], d3 * rr * g2[3] + b2v[3]);
    }
    __syncthreads();     // O reads done; Wb free for FFN staging

    // ---- Phase E: FFN 64->256 (gelu) ->64, 2 chunks of 128 hidden, staged weights
    const unsigned short* pW1 = pk + 2 * OFF_W1;
    const unsigned short* pW2 = pk + 2 * OFF_W2;
    f32x4 ya[4];
#pragma unroll
    for (int nt = 0; nt < 4; ++nt) { float by = fb2[nt * 16 + cb]; ya[nt] = {by, by, by, by}; }

#pragma unroll
    for (int cc = 0; cc < 2; ++cc) {
        // stage W1 chunk cc (32 KB): global tile gt=ks*16+cc*8+n8 -> lds tile lt=ks*8+n8
#pragma unroll
        for (int it = 0; it < 8; ++it) {
            int i = it * 256 + tid;
            int half = i >> 10, j = i & 1023;
            int lt = j >> 6, lr = j & 63;
            int ksl = lt >> 3, n8 = lt & 7;
            int gt = ksl * 16 + cc * 8 + n8;
            *(u16x8*)(Wb + half * 8192 + (lt * 64 + lr) * 8) =
                *(const u16x8*)(pW1 + half * 16384 + (gt * 64 + lr) * 8);
        }
        __syncthreads();

        f32x4 ha[8];
#pragma unroll
        for (int n8 = 0; n8 < 8; ++n8) {
            float hb = fb1[(cc * 8 + n8) * 16 + cb];
            ha[n8] = {hb, hb, hb, hb};
        }
#pragma unroll
        for (int ks = 0; ks < 2; ++ks) {
            bf16x8 ah = readFrag(Ahi, R0, lane, ks, 128, 7);
#pragma unroll
            for (int n8 = 0; n8 < 8; ++n8) {
                bf16x8 bh, bl;
                readB(Wb, 8192, 8, ks, n8, lane, bh, bl);
                ha[n8] = MFMA_B16(ah, bh, ha[n8]);
                ha[n8] = MFMA_B16(ah, bl, ha[n8]);
            }
        }
        // gelu -> H frags (wave-private rows)
#pragma unroll
        for (int reg = 0; reg < 4; ++reg) {
            int rloc = R0 + cg * 4 + reg;
            u16x8 u;
#pragma unroll
            for (int n8 = 0; n8 < 8; ++n8) {
                float h = ha[n8][reg];
                h = 0.5f * h * (1.0f + erff(h * 0.70710678118654752f));
                u[n8] = (unsigned short)rne16(h);
            }
            int bo = (rloc * 256 + cb * 16) ^ ((rloc & 15) << 4);
            *(u16x8*)((char*)Hhi + bo) = u;
        }
        __syncthreads();     // W1 reads done

        // stage W2 chunk cc (32 KB): contiguous tiles [cc*16, cc*16+16)
#pragma unroll
        for (int it = 0; it < 8; ++it) {
            int i = it * 256 + tid;
            int half = i >> 10, j = i & 1023;
            *(u16x8*)(Wb + half * 8192 + j * 8) =
                *(const u16x8*)(pW2 + half * 16384 + cc * 8192 + j * 8);
        }
        __syncthreads();

#pragma unroll
        for (int ks2 = 0; ks2 < 4; ++ks2) {
            bf16x8 ah = readFrag(Hhi, R0, lane, ks2, 256, 15);
#pragma unroll
            for (int nt = 0; nt < 4; ++nt) {
                bf16x8 bh, bl;
                readB(Wb, 8192, 4, ks2, nt, lane, bh, bl);
                ya[nt] = MFMA_B16(ah, bh, ya[nt]);
                ya[nt] = MFMA_B16(ah, bl, ya[nt]);
            }
        }
        __syncthreads();     // W2 reads done before next chunk restage
    }

    // ---- final: x2 + ffn -> Hf (wave-private rows), then coalesced float4 store
#pragma unroll
    for (int reg = 0; reg < 4; ++reg) {
        int rloc = R0 + cg * 4 + reg;
#pragma unroll
        for (int nt = 0; nt < 4; ++nt)
            Hf[rloc * 64 + nt * 16 + cb] = x2[reg][nt] + ya[nt][reg];
    }
    __syncthreads();
    {
        float4* dst4 = (float4*)(fout + ((size_t)(pi * B_ + b) * N_ + nn0) * 64);
        const float4* src4 = (const float4*)Hf;
#pragma unroll
        for (int it = 0; it < 4; ++it) {
            int i = it * 256 + tid;
            dst4[i] = src4[i];
        }
    }
}

// ---------- output transpose ----------
__global__ __launch_bounds__(256) void output_kernel(const float* __restrict__ f,
                                                     float* __restrict__ out) {
    __shared__ float tile[64][65];
    int blk = blockIdx.x;
    int ntile = blk & 255;
    int bp = blk >> 8;
    int b = bp / 3, p = bp - b * 3;
    int n0 = ntile * 64;
    int tr = threadIdx.x >> 6, tc = threadIdx.x & 63;

    const float* src = f + ((size_t)(p * B_ + b) * N_ + n0) * C_;
#pragma unroll
    for (int it = 0; it < 16; ++it) {
        int r = it * 4 + tr;
        tile[r][tc] = src[(size_t)r * C_ + tc];
    }
    __syncthreads();
    float* dst = out + (size_t)(b * 3 + p) * C_ * N_ + n0;
#pragma unroll
    for (int it = 0; it < 16; ++it) {
        int cidx = it * 4 + tr;
        dst[(size_t)cidx * N_ + tc] = tile[tc][cidx];
    }
}

extern "C" void kernel_launch(void* const* d_in, const int* in_sizes, int n_in,
                              void* d_out, int out_size, void* d_ws, size_t ws_size,
                              hipStream_t stream) {
    const float* img_feats = (const float*)d_in[0];
    const float* pts       = (const float*)d_in[1];
    const float* query     = (const float*)d_in[2];
    const float* ln1_g     = (const float*)d_in[3];
    const float* ln1_b     = (const float*)d_in[4];
    const float* ln2_g     = (const float*)d_in[5];
    const float* ln2_b     = (const float*)d_in[6];
    const float* in_w      = (const float*)d_in[7];
    const float* in_b      = (const float*)d_in[8];
    const float* out_w     = (const float*)d_in[9];
    const float* out_b     = (const float*)d_in[10];
    const float* ffn_w1    = (const float*)d_in[11];
    const float* ffn_b1    = (const float*)d_in[12];
    const float* ffn_w2    = (const float*)d_in[13];
    const float* ffn_b2    = (const float*)d_in[14];

    const size_t FEAT_SZ = (size_t)3 * B_ * N_ * C_;  // 6,291,456

    float* ws = (float*)d_ws;
    float* ftr      = ws;                                  // FTR_SZ floats
    int* counts     = (int*)(ftr + FTR_SZ);                // SEG_SZ
    int* offsets    = counts + SEG_SZ;                     // NSEG*OSTRIDE
    int* cursors    = offsets + (size_t)NSEG * OSTRIDE;    // SEG_SZ
    float4* ent     = (float4*)(cursors + SEG_SZ);         // SEG_SZ float4
    float* fA       = (float*)(ent + SEG_SZ);
    float* fB       = fA + FEAT_SZ;
    unsigned short* pk_base = (unsigned short*)(fB + FEAT_SZ);
    // kv tables alias the (dead after gather_splat) counts/offsets region
    float* kvk = (float*)counts;
    float* kvv = kvk + KV_SZ;

    // init plane feats with query tensors
    init_feats<<<(3 * N_ * C_ + 255) / 256, 256, 0, stream>>>(query, fA);

    // ---- splat via binning + strip gather (no float atomics)
    zero_counts<<<(int)(SEG_SZ / 4 + 255) / 256, 256, 0, stream>>>((int4*)counts, (int)(SEG_SZ / 4));
    transpose_feats<<<NBV * 256, 256, 0, stream>>>(img_feats, ftr);
    bin_count<<<(NBV * N_) / 256, 256, 0, stream>>>(pts, counts);
    scan_bins<<<NSEG, 256, 0, stream>>>(counts, offsets, cursors);
    scatter_pts<<<(NBV * N_) / 256, 256, 0, stream>>>(pts, cursors, ent);
    gather_splat<<<dim3(512, 3, B_), 256, 0, stream>>>(ftr, offsets, ent, fA);

    // pack weights
    for (int l = 0; l < NL_; ++l) {
        pack_layer<<<(PK_ELEMS + 255) / 256, 256, 0, stream>>>(
            in_w + (size_t)l * 3 * C_ * C_, out_w + (size_t)l * C_ * C_,
            ffn_w1 + (size_t)l * 4 * C_ * C_, ffn_w2 + (size_t)l * C_ * 4 * C_,
            pk_base + (size_t)l * LAYER_PK);
    }

    dim3 pgrid((B_ * N_) / 64, 3);
    for (int l = 0; l < NL_; ++l) {
        const float* fin = (l == 0) ? fA : fB;
        float* fout      = (l == 0) ? fB : fA;
        ctx_kv<<<144, 256, 0, stream>>>(fin, ln1_g + l * C_, ln1_b + l * C_,
                                        in_w + (size_t)l * 3 * C_ * C_, in_b + l * 3 * C_,
                                        kvk, kvv);
        plane_mfma<<<pgrid, 256, 0, stream>>>(
            fin, fout, pk_base + (size_t)l * LAYER_PK, kvk, kvv,
            ln1_g + l * C_, ln1_b + l * C_,
            ln2_g + l * C_, ln2_b + l * C_,
            in_b + l * 3 * C_, out_b + l * C_,
            ffn_b1 + l * 4 * C_, ffn_b2 + l * C_);
    }

    output_kernel<<<B_ * 3 * (N_ / 64), 256, 0, stream>>>(fA, (float*)d_out);
}

// Round 10
// 397.939 us; speedup vs baseline: 12.4176x; 1.1480x over previous
//
#include <hip/hip_runtime.h>
#include <math.h>

constexpr int R_ = 128, C_ = 64, NL_ = 2, B_ = 2, V_ = 4;
constexpr int N_ = R_ * R_;          // 16384
constexpr int T_ = 6;

typedef __attribute__((ext_vector_type(8))) short bf16x8;
typedef __attribute__((ext_vector_type(4))) float f32x4;
typedef __attribute__((ext_vector_type(4))) unsigned short u16x4;
typedef __attribute__((ext_vector_type(8))) unsigned short u16x8;

#define MFMA_B16(a, b, c) __builtin_amdgcn_mfma_f32_16x16x32_bf16((a), (b), (c), 0, 0, 0)

// packed-weight element offsets (per layer, in elements)
constexpr int OFF_O = 12288, OFF_W1 = 16384, OFF_W2 = 32768;
constexpr int PK_ELEMS = 49152;
constexpr int LAYER_PK = 2 * PK_ELEMS;   // ushorts per layer (hi+lo)

// splat-path sizes
constexpr int NBV = B_ * V_;                       // 8
constexpr size_t FTR_SZ = (size_t)NBV * N_ * C_;   // 8,388,608 floats
constexpr int NSEG = 3 * NBV;                      // 24 segments
constexpr size_t SEG_SZ = (size_t)NSEG * N_;       // 393,216 ints
constexpr int OSTRIDE = N_ + 128;                  // offsets stride (sentinel pad)
constexpr size_t KV_SZ = (size_t)3 * B_ * T_ * 128 * 64;   // 294,912 floats

// ---------- helpers ----------
__device__ inline unsigned rne16(float x) {
    unsigned b = __float_as_uint(x);
    return (b + 0x7fffu + ((b >> 16) & 1u)) >> 16;
}

__device__ inline float wsum(float v) {
#pragma unroll
    for (int m = 1; m < 64; m <<= 1) v += __shfl_xor(v, m, 64);
    return v;
}

__device__ inline float lnorm(float v, float g, float b) {
    float m = wsum(v) * (1.f / 64.f);
    float d = v - m;
    float var = wsum(d * d) * (1.f / 64.f);
    return d * rsqrtf(var + 1e-5f) * g + b;
}

// stage a 64x64 row-major fp32 matrix into LDS buf[c*68 + u]
__device__ inline void stageW(const float* __restrict__ W, float* buf, int tid) {
#pragma unroll
    for (int it = 0; it < 4; ++it) {
        int idx4 = it * 256 + tid;
        int r = idx4 >> 4, u4 = idx4 & 15;
        float4 v = ((const float4*)W)[idx4];
        *(float4*)&buf[r * 68 + u4 * 4] = v;
    }
}

// read A-fragment (16x32 bf16) for wave's M-tile from swizzled LDS
__device__ inline bf16x8 readFrag(const unsigned short* base, int rowBase, int lane,
                                  int ks, int rowStrideB, int swzMask) {
    int rowloc = rowBase + (lane & 15);
    int off = rowloc * rowStrideB + ks * 64 + ((lane >> 4) & 3) * 16;
    off ^= ((rowloc & swzMask) << 4);
    return *(const bf16x8*)((const char*)base + off);
}

// store 4 bf16-hi values (K-permuted: p = cb*4+nt) as one 8B write
__device__ inline void storeA4(unsigned short* base, int rloc, int cb,
                               float v0, float v1, float v2, float v3) {
    u16x4 u;
    u[0] = (unsigned short)rne16(v0);
    u[1] = (unsigned short)rne16(v1);
    u[2] = (unsigned short)rne16(v2);
    u[3] = (unsigned short)rne16(v3);
    int bo = (rloc * 128 + cb * 8) ^ ((rloc & 7) << 4);
    *(u16x4*)((char*)base + bo) = u;
}

// load B-fragment pair (hi,lo) from a weight table (global or LDS)
__device__ inline void readB(const unsigned short* matHi, int E, int NTm, int ks, int nt,
                             int lane, bf16x8& bh, bf16x8& bl) {
    int off = (((ks * NTm + nt) << 6) + lane) << 3;
    bh = *(const bf16x8*)(matHi + off);
    bl = *(const bf16x8*)(matHi + E + off);
}

// ---------- pack all weights of one layer (K-permuted, split hi/lo) ----------
__global__ __launch_bounds__(256) void pack_layer(const float* __restrict__ iw,
                                                  const float* __restrict__ ow,
                                                  const float* __restrict__ w1,
                                                  const float* __restrict__ w2,
                                                  unsigned short* __restrict__ pk) {
    int idx = blockIdx.x * 256 + threadIdx.x;
    if (idx >= PK_ELEMS) return;
    const float* W;
    int O, K, base, mode, lidx;
    if (idx < 12288)      { int m = idx >> 12; lidx = idx & 4095; W = iw + m * 4096; O = 64;  K = 64;  base = m * 4096; mode = 0; }
    else if (idx < 16384) { lidx = idx - 12288; W = ow; O = 64;  K = 64;  base = OFF_O;  mode = 0; }
    else if (idx < 32768) { lidx = idx - 16384; W = w1; O = 256; K = 64;  base = OFF_W1; mode = 0; }
    else                  { lidx = idx - 32768; W = w2; O = 64;  K = 256; base = OFF_W2; mode = 1; }
    int j = lidx & 7, l = (lidx >> 3) & 63, rem = lidx >> 9;
    int NTm = O >> 4;
    int nt = rem & (NTm - 1), ks = rem / NTm;
    int kfrag = ks * 32 + ((l >> 4) & 3) * 8 + j;
    int k;
    if (mode == 0) { int p = kfrag & 63; k = (p & 3) * 16 + (p >> 2); }
    else { int cc = kfrag >> 7; int pl = kfrag & 127; k = (cc * 8 + (pl & 7)) * 16 + (pl >> 3); }
    int o = nt * 16 + (l & 15);
    float w = W[(size_t)o * K + k];
    unsigned hb = rne16(w);
    float hf = __uint_as_float(hb << 16);
    unsigned lb = rne16(w - hf);
    int E = O * K;
    pk[2 * base + lidx] = (unsigned short)hb;
    pk[2 * base + E + lidx] = (unsigned short)lb;
}

// ---------- init plane feats with query tensors ----------
__global__ __launch_bounds__(256) void init_feats(const float* __restrict__ q,
                                                  float* __restrict__ f0) {
    int idx = blockIdx.x * 256 + threadIdx.x;
    if (idx >= 3 * N_ * C_) return;
    int p = idx / (N_ * C_);
    int rem = idx - p * (N_ * C_);
    float val = q[idx];
    f0[(size_t)(p * B_ + 0) * N_ * C_ + rem] = val;
    f0[(size_t)(p * B_ + 1) * N_ * C_ + rem] = val;
}

// ---------- zero bin counts ----------
__global__ __launch_bounds__(256) void zero_counts(int4* __restrict__ p, int n4) {
    int i = blockIdx.x * 256 + threadIdx.x;
    if (i < n4) p[i] = make_int4(0, 0, 0, 0);
}

// ---------- transpose features: [bv][c][n] -> [bv][n][c] ----------
__global__ __launch_bounds__(256) void transpose_feats(const float* __restrict__ src,
                                                       float* __restrict__ dst) {
    __shared__ float tile[64][65];
    int blk = blockIdx.x;             // NBV * 256
    int ntile = blk & 255;
    int bv = blk >> 8;
    int n0 = ntile * 64;
    int tr = threadIdx.x >> 6, tc = threadIdx.x & 63;
    const float* s = src + (size_t)bv * C_ * N_;
#pragma unroll
    for (int it = 0; it < 16; ++it) {
        int c = it * 4 + tr;
        tile[c][tc] = s[(size_t)c * N_ + n0 + tc];
    }
    __syncthreads();
    float* d = dst + ((size_t)bv * N_ + n0) * C_;
#pragma unroll
    for (int it = 0; it < 16; ++it) {
        int r = it * 4 + tr;
        d[(size_t)r * C_ + tc] = tile[tc][r];
    }
}

// ---------- bin count ----------
__global__ __launch_bounds__(256) void bin_count(const float* __restrict__ pts,
                                                 int* __restrict__ counts) {
    int idx = blockIdx.x * 256 + threadIdx.x;     // [0, NBV*N)
    if (idx >= NBV * N_) return;
    int bv = idx >> 14;
    const float* p = pts + (size_t)idx * 3;
    float px = p[0], py = p[1], pz = p[2];
    const float HI = (float)(127.0 - 1e-5);
    float gx = fminf(fmaxf((px + 1.0f) * 127.0f / 2.0f, 0.0f), HI);
    float gy = fminf(fmaxf((py + 1.0f) * 127.0f / 2.0f, 0.0f), HI);
    float gz = fminf(fmaxf((pz + 1.0f) * 127.0f / 2.0f, 0.0f), HI);
    int x0 = (int)gx, y0 = (int)gy, z0 = (int)gz;
    atomicAdd(&counts[(0 * NBV + bv) * N_ + x0 * R_ + y0], 1);
    atomicAdd(&counts[(1 * NBV + bv) * N_ + x0 * R_ + z0], 1);
    atomicAdd(&counts[(2 * NBV + bv) * N_ + y0 * R_ + z0], 1);
}

// ---------- per-segment exclusive scan (16384 bins each) + sentinel pad ----------
__global__ __launch_bounds__(256) void scan_bins(const int* __restrict__ counts,
                                                 int* __restrict__ offsets,
                                                 int* __restrict__ cursors) {
    __shared__ int part[256];
    int seg = blockIdx.x;             // 24
    int t = threadIdx.x;
    const int* c = counts + (size_t)seg * N_;
    int sum = 0;
    for (int i = 0; i < 64; ++i) sum += c[t * 64 + i];
    part[t] = sum;
    __syncthreads();
    if (t == 0) {
        int run = 0;
        for (int i = 0; i < 256; ++i) { int v = part[i]; part[i] = run; run += v; }
    }
    __syncthreads();
    int run = part[t];
    int* o = offsets + (size_t)seg * OSTRIDE;
    int* cu = cursors + (size_t)seg * N_;
    for (int i = 0; i < 64; ++i) {
        o[t * 64 + i] = run;
        cu[t * 64 + i] = run;
        run += c[t * 64 + i];
    }
    if (t < 128) o[N_ + t] = N_;      // sentinel: total per segment == N_
}

// ---------- scatter full point records into bin-sorted entry lists ----------
__global__ __launch_bounds__(256) void scatter_pts(const float* __restrict__ pts,
                                                   int* __restrict__ cursors,
                                                   float4* __restrict__ ent) {
    int idx = blockIdx.x * 256 + threadIdx.x;
    if (idx >= NBV * N_) return;
    int bv = idx >> 14, n = idx & (N_ - 1);
    const float* p = pts + (size_t)idx * 3;
    float px = p[0], py = p[1], pz = p[2];
    const float HI = (float)(127.0 - 1e-5);
    float gx = fminf(fmaxf((px + 1.0f) * 127.0f / 2.0f, 0.0f), HI);
    float gy = fminf(fmaxf((py + 1.0f) * 127.0f / 2.0f, 0.0f), HI);
    float gz = fminf(fmaxf((pz + 1.0f) * 127.0f / 2.0f, 0.0f), HI);
    int x0 = (int)gx, y0 = (int)gy, z0 = (int)gz;
    float4 e;
    e.x = __uint_as_float((unsigned)n);
    e.y = gx - (float)x0; e.z = gy - (float)y0; e.w = gz - (float)z0;
    int s0 = 0 * NBV + bv, s1 = 1 * NBV + bv, s2 = 2 * NBV + bv;
    int p0 = atomicAdd(&cursors[(size_t)s0 * N_ + x0 * R_ + y0], 1);
    ent[(size_t)s0 * N_ + p0] = e;
    int p1 = atomicAdd(&cursors[(size_t)s1 * N_ + x0 * R_ + z0], 1);
    ent[(size_t)s1 * N_ + p1] = e;
    int p2 = atomicAdd(&cursors[(size_t)s2 * N_ + y0 * R_ + z0], 1);
    ent[(size_t)s2 * N_ + p2] = e;
}

// ---------- gather splat: block = one 8-cell strip; wave = one view ----------
__global__ __launch_bounds__(256) void gather_splat(
    const float* __restrict__ ftr, const int* __restrict__ offsets,
    const float4* __restrict__ ent, float* __restrict__ f0) {
    __shared__ float sfacc[4][8][64];
    __shared__ float swsum[4][8];
    int wid = threadIdx.x >> 6, lane = threadIdx.x & 63;
    int strip = blockIdx.x;                   // [0, 2048)
    int pi = blockIdx.y, b = blockIdx.z;
    int a = strip >> 4;                       // cell row
    int c0 = (strip & 15) << 3;               // first cell col of strip

    // wave handles view v = wid
    int bv = b * V_ + wid;
    int seg = pi * NBV + bv;
    const int* ob = offsets + (size_t)seg * OSTRIDE;
    const float4* eb = ent + (size_t)seg * N_;
    const float* fbase = ftr + (size_t)bv * N_ * C_ + lane;
    float facc[8], wsum_[8];
#pragma unroll
    for (int k = 0; k < 8; ++k) { facc[k] = 0.f; wsum_[k] = 0.f; }

    for (int dr = 0; dr < 2; ++dr) {
        int ba = a - dr;
        if (ba < 0) continue;
        int rowbase = ba * R_ + c0 - 1;
        int o[10];
#pragma unroll
        for (int jj = 0; jj < 10; ++jj)
            o[jj] = ob[max(rowbase + jj, 0)];
#pragma unroll
        for (int j = 0; j < 9; ++j) {
            if (j == 0 && c0 == 0) continue;    // bin col -1 doesn't exist
            int e = o[j + 1];
            for (int i = o[j]; i < e; ++i) {
                float4 r = eb[i];
                int n = (int)__float_as_uint(r.x);
                float wx = r.y, wy = r.z, wz = r.w;
                float ax = 1.f - wx, ay = 1.f - wy, az = 1.f - wz;
                float XA = dr ? wx : ax;
                float YA = dr ? wy : ay;
                float w0 = (pi == 2 ? ax * YA : XA * ay) * az;
                float w1 = (pi == 0) ? XA * wy * az : XA * YA * wz;
                float f = fbase[(size_t)n * C_];
                if (j > 0) { facc[j - 1] += w0 * f; wsum_[j - 1] += w0; }
                if (j < 8) { facc[j] += w1 * f; wsum_[j] += w1; }
            }
        }
    }
#pragma unroll
    for (int k = 0; k < 8; ++k) sfacc[wid][k][lane] = facc[k];
    if (lane == 0) {
#pragma unroll
        for (int k = 0; k < 8; ++k) swsum[wid][k] = wsum_[k];
    }
    __syncthreads();

    // combine: wave wid handles cells 2*wid, 2*wid+1
    float* dst = f0 + (((size_t)(pi * B_ + b)) * N_ + a * R_ + c0) * C_ + lane;
#pragma unroll
    for (int k2 = 0; k2 < 2; ++k2) {
        int k = wid * 2 + k2;
        float tot = 0.f;
#pragma unroll
        for (int vv = 0; vv < 4; ++vv)
            tot += sfacc[vv][k][lane] / fmaxf(swsum[vv][k], 1e-8f);
        dst[(size_t)k * C_] += 0.25f * tot;
    }
}

// ---------- ctx k/v table: 4608 rows = (pi, b, t, pos) ----------
__global__ __launch_bounds__(256) void ctx_kv(
    const float* __restrict__ fin,
    const float* __restrict__ ln1g, const float* __restrict__ ln1b,
    const float* __restrict__ inw, const float* __restrict__ inb,
    float* __restrict__ kvk, float* __restrict__ kvv) {
    __shared__ float s_wk[64 * 68];
    __shared__ float s_wv[64 * 68];
    __shared__ float s_act[32 * 68];
    int tid = threadIdx.x, wid = tid >> 6, lane = tid & 63;
    stageW(inw + 4096, s_wk, tid);     // Wk
    stageW(inw + 8192, s_wv, tid);     // Wv

    int rid0 = blockIdx.x * 32 + wid * 8;
    int seg = rid0 >> 7;               // (pi*2+b)*6 + t
    int pos0 = rid0 & 127;
    int t = seg % 6;
    int pib = seg / 6;
    int pi = pib >> 1, b = pib & 1;
    int khalf = (t < 3) ? t : t - 3;
    float sk = (float)(khalf - 1);
    bool tl = t < 3;
    int io;
    if (pi == 0) io = tl ? 1 : 2;
    else if (pi == 1) io = tl ? 0 : 2;
    else io = tl ? 0 : 1;
    const float* Fio = fin + (size_t)(io * B_ + b) * N_ * 64;
    float g1 = ln1g[lane], b1 = ln1b[lane];

#pragma unroll
    for (int rr = 0; rr < 8; ++rr) {
        int pos = pos0 + rr;
        float lp = -1.0f + (2.0f * (float)pos) / 127.0f;
        float caf, cbf;
        if (pi == 0) { caf = lp; cbf = sk; }
        else if (pi == 1) { if (tl) { caf = lp; cbf = sk; } else { caf = sk; cbf = lp; } }
        else { caf = sk; cbf = lp; }
        float ua = fminf(fmaxf((caf * 0.5f + 0.5f) * 127.0f, 0.0f), 127.0f);
        float ub = fminf(fmaxf((cbf * 0.5f + 0.5f) * 127.0f, 0.0f), 127.0f);
        float gxp = fminf(fmaxf(((ua + 1.0f) * 0.5f) * 127.0f, 0.0f), 127.0f);
        float gyp = fminf(fmaxf(((ub + 1.0f) * 0.5f) * 127.0f, 0.0f), 127.0f);
        int xx0 = (int)gxp, yy0 = (int)gyp;
        int xx1 = xx0 + 1 < 128 ? xx0 + 1 : 127;
        int yy1 = yy0 + 1 < 128 ? yy0 + 1 : 127;
        float wx = gxp - (float)xx0, wy = gyp - (float)yy0;
        float v00 = Fio[(size_t)(yy0 * R_ + xx0) * 64 + lane];
        float v01 = Fio[(size_t)(yy0 * R_ + xx1) * 64 + lane];
        float v10 = Fio[(size_t)(yy1 * R_ + xx0) * 64 + lane];
        float v11 = Fio[(size_t)(yy1 * R_ + xx1) * 64 + lane];
        float cv = (1.0f - wy) * ((1.0f - wx) * v00 + wx * v01) +
                   wy * ((1.0f - wx) * v10 + wx * v11);
        s_act[(wid * 8 + rr) * 68 + lane] = lnorm(cv, g1, b1);
    }
    __syncthreads();

    float kk[8], vv[8];
    float bk = inb[64 + lane], bv = inb[128 + lane];
#pragma unroll
    for (int rr = 0; rr < 8; ++rr) { kk[rr] = bk; vv[rr] = bv; }
    const float* wrk = s_wk + lane * 68;
    const float* wrv = s_wv + lane * 68;
#pragma unroll 4
    for (int g = 0; g < 16; ++g) {
        float4 wk4 = *(const float4*)(wrk + g * 4);
        float4 wv4 = *(const float4*)(wrv + g * 4);
#pragma unroll
        for (int rr = 0; rr < 8; ++rr) {
            float4 xv = *(const float4*)(s_act + (wid * 8 + rr) * 68 + g * 4);
            kk[rr] = fmaf(xv.x, wk4.x, fmaf(xv.y, wk4.y, fmaf(xv.z, wk4.z, fmaf(xv.w, wk4.w, kk[rr]))));
            vv[rr] = fmaf(xv.x, wv4.x, fmaf(xv.y, wv4.y, fmaf(xv.z, wv4.z, fmaf(xv.w, wv4.w, vv[rr]))));
        }
    }
#pragma unroll
    for (int rr = 0; rr < 8; ++rr) {
        size_t o = ((size_t)seg * 128 + pos0 + rr) * 64 + lane;
        kvk[o] = kk[rr];
        kvv[o] = vv[rr];
    }
}

// ---------- fused per-plane transformer layer (MFMA, precomputed k/v) ----------
__global__ __launch_bounds__(256, 2) void plane_mfma(
    const float* __restrict__ fin, float* __restrict__ fout,
    const unsigned short* __restrict__ pk,
    const float* __restrict__ kvk, const float* __restrict__ kvv,
    const float* __restrict__ ln1g, const float* __restrict__ ln1b,
    const float* __restrict__ ln2g, const float* __restrict__ ln2b,
    const float* __restrict__ inb, const float* __restrict__ outb,
    const float* __restrict__ fb1, const float* __restrict__ fb2) {
    __shared__ __attribute__((aligned(16))) unsigned short Wb[16384];  // 32 KB weight stage
    __shared__ __attribute__((aligned(16))) unsigned short Ahi[4096];  // 8 KB A-frags
    __shared__ __attribute__((aligned(16))) float Hf[4096];            // 16 KB H-frags / out stage
    unsigned short* Hhi = (unsigned short*)Hf;

    const int tid = threadIdx.x;
    const int wid = tid >> 6, lane = tid & 63;
    const int cg = lane >> 4, cb = lane & 15;
    const int pi = blockIdx.y;
    const int R0 = wid * 16;
    const int rowbase = blockIdx.x * 64;
    const int b = rowbase >> 14;
    const int nn0 = rowbase & (N_ - 1);
    const int i0 = nn0 >> 7, j0 = nn0 & 127;

    // ---- stage Q (hi+lo, 16 KB) into Wb[0:8192]
#pragma unroll
    for (int i = 0; i < 4; ++i)
        *(u16x8*)(Wb + (i * 256 + tid) * 8) = *(const u16x8*)(pk + (i * 256 + tid) * 8);

    float g1[4], b1v[4];
#pragma unroll
    for (int nt = 0; nt < 4; ++nt) { g1[nt] = ln1g[nt * 16 + cb]; b1v[nt] = ln1b[nt * 16 + cb]; }

    // ---- Phase A: load x (kept in regs), LN1 -> A-frags (wave-private LDS rows)
    float x[4][4];
    const float* finp = fin + ((size_t)(pi * B_ + b) * N_ + nn0) * 64;
#pragma unroll
    for (int reg = 0; reg < 4; ++reg) {
        int rloc = R0 + cg * 4 + reg;
#pragma unroll
        for (int nt = 0; nt < 4; ++nt) x[reg][nt] = finp[(size_t)rloc * 64 + nt * 16 + cb];
        float s = x[reg][0] + x[reg][1] + x[reg][2] + x[reg][3];
#pragma unroll
        for (int m = 1; m < 16; m <<= 1) s += __shfl_xor(s, m, 64);
        float mean = s * (1.0f / 64.0f);
        float d0 = x[reg][0] - mean, d1 = x[reg][1] - mean, d2 = x[reg][2] - mean, d3 = x[reg][3] - mean;
        float sq = d0 * d0 + d1 * d1 + d2 * d2 + d3 * d3;
#pragma unroll
        for (int m = 1; m < 16; m <<= 1) sq += __shfl_xor(sq, m, 64);
        float rr = rsqrtf(sq * (1.0f / 64.0f) + 1e-5f);
        storeA4(Ahi, rloc, cb,
                d0 * rr * g1[0] + b1v[0], d1 * rr * g1[1] + b1v[1],
                d2 * rr * g1[2] + b1v[2], d3 * rr * g1[3] + b1v[3]);
    }
    __syncthreads();

    // ---- Phase B: q = xn @ Wq^T + bq  (Wb = Q)
    f32x4 qa[4];
#pragma unroll
    for (int nt = 0; nt < 4; ++nt) { float bq = inb[nt * 16 + cb]; qa[nt] = {bq, bq, bq, bq}; }
#pragma unroll
    for (int ks = 0; ks < 2; ++ks) {
        bf16x8 ah = readFrag(Ahi, R0, lane, ks, 128, 7);
#pragma unroll
        for (int nt = 0; nt < 4; ++nt) {
            bf16x8 bh, bl;
            readB(Wb, 4096, 4, ks, nt, lane, bh, bl);
            qa[nt] = MFMA_B16(ah, bh, qa[nt]);
            qa[nt] = MFMA_B16(ah, bl, qa[nt]);
        }
    }

    // ---- Phase C: attention with precomputed k/v (no barriers, no LDS)
    const float* kvkb = kvk + (size_t)((pi * 2 + b) * 6) * 128 * 64;
    const float* kvvb = kvv + (size_t)((pi * 2 + b) * 6) * 128 * 64;
    float den_[4][4];
    f32x4 oa[4];
#pragma unroll
    for (int nt = 0; nt < 4; ++nt) {
        oa[nt] = {0.f, 0.f, 0.f, 0.f};
#pragma unroll
        for (int reg = 0; reg < 4; ++reg) den_[nt][reg] = 0.f;
    }

    // t = 0..2: k/v depend on j (per-row)
#pragma unroll
    for (int t = 0; t < 3; ++t) {
        float kvr[4][4], vvr[4][4];
#pragma unroll
        for (int reg = 0; reg < 4; ++reg) {
            int pos = j0 + R0 + cg * 4 + reg;
            const float* kr = kvkb + ((size_t)t * 128 + pos) * 64 + cb;
            const float* vr = kvvb + ((size_t)t * 128 + pos) * 64 + cb;
#pragma unroll
            for (int nt = 0; nt < 4; ++nt) {
                kvr[reg][nt] = kr[nt * 16];
                vvr[reg][nt] = vr[nt * 16];
            }
        }
#pragma unroll
        for (int nt = 0; nt < 4; ++nt) {
            float d0 = qa[nt][0] * kvr[0][nt];
            float d1 = qa[nt][1] * kvr[1][nt];
            float d2 = qa[nt][2] * kvr[2][nt];
            float d3 = qa[nt][3] * kvr[3][nt];
#pragma unroll
            for (int m = 1; m < 16; m <<= 1) {
                d0 += __shfl_xor(d0, m, 64);
                d1 += __shfl_xor(d1, m, 64);
                d2 += __shfl_xor(d2, m, 64);
                d3 += __shfl_xor(d3, m, 64);
            }
            float e0 = __expf(d0 * 0.25f), e1 = __expf(d1 * 0.25f);
            float e2 = __expf(d2 * 0.25f), e3 = __expf(d3 * 0.25f);
            den_[nt][0] += e0; den_[nt][1] += e1; den_[nt][2] += e2; den_[nt][3] += e3;
            oa[nt][0] += e0 * vvr[0][nt];
            oa[nt][1] += e1 * vvr[1][nt];
            oa[nt][2] += e2 * vvr[2][nt];
            oa[nt][3] += e3 * vvr[3][nt];
        }
    }
    // t = 3..5: k/v depend on i (block-uniform row i0)
#pragma unroll
    for (int t = 3; t < 6; ++t) {
        float ku[4], vu[4];
        const float* kr = kvkb + ((size_t)t * 128 + i0) * 64 + cb;
        const float* vr = kvvb + ((size_t)t * 128 + i0) * 64 + cb;
#pragma unroll
        for (int nt = 0; nt < 4; ++nt) { ku[nt] = kr[nt * 16]; vu[nt] = vr[nt * 16]; }
#pragma unroll
        for (int nt = 0; nt < 4; ++nt) {
            float d0 = qa[nt][0] * ku[nt];
            float d1 = qa[nt][1] * ku[nt];
            float d2 = qa[nt][2] * ku[nt];
            float d3 = qa[nt][3] * ku[nt];
#pragma unroll
            for (int m = 1; m < 16; m <<= 1) {
                d0 += __shfl_xor(d0, m, 64);
                d1 += __shfl_xor(d1, m, 64);
                d2 += __shfl_xor(d2, m, 64);
                d3 += __shfl_xor(d3, m, 64);
            }
            float e0 = __expf(d0 * 0.25f), e1 = __expf(d1 * 0.25f);
            float e2 = __expf(d2 * 0.25f), e3 = __expf(d3 * 0.25f);
            den_[nt][0] += e0; den_[nt][1] += e1; den_[nt][2] += e2; den_[nt][3] += e3;
            oa[nt][0] += e0 * vu[nt];
            oa[nt][1] += e1 * vu[nt];
            oa[nt][2] += e2 * vu[nt];
            oa[nt][3] += e3 * vu[nt];
        }
    }
    __syncthreads();     // all waves past q-proj; Wb free

    // ---- stage O (16 KB) into Wb[0:8192]; write o/den -> A-frags
#pragma unroll
    for (int i = 0; i < 4; ++i)
        *(u16x8*)(Wb + (i * 256 + tid) * 8) = *(const u16x8*)(pk + 24576 + (i * 256 + tid) * 8);
#pragma unroll
    for (int reg = 0; reg < 4; ++reg) {
        int rloc = R0 + cg * 4 + reg;
        storeA4(Ahi, rloc, cb,
                oa[0][reg] / den_[0][reg], oa[1][reg] / den_[1][reg],
                oa[2][reg] / den_[2][reg], oa[3][reg] / den_[3][reg]);
    }
    __syncthreads();

    // ---- Phase D: out-proj (Wb = O); residual (x in regs); LN2 -> A-frags
    f32x4 ao[4];
#pragma unroll
    for (int nt = 0; nt < 4; ++nt) { float bo_ = outb[nt * 16 + cb]; ao[nt] = {bo_, bo_, bo_, bo_}; }
#pragma unroll
    for (int ks = 0; ks < 2; ++ks) {
        bf16x8 ah = readFrag(Ahi, R0, lane, ks, 128, 7);
#pragma unroll
        for (int nt = 0; nt < 4; ++nt) {
            bf16x8 bh, bl;
            readB(Wb, 4096, 4, ks, nt, lane, bh, bl);
            ao[nt] = MFMA_B16(ah, bh, ao[nt]);
            ao[nt] = MFMA_B16(ah, bl, ao[nt]);
        }
    }
    float g2[4], b2v[4];
#pragma unroll
    for (int nt = 0; nt < 4; ++nt) { g2[nt] = ln2g[nt * 16 + cb]; b2v[nt] = ln2b[nt * 16 + cb]; }
    float x2[4][4];
#pragma unroll
    for (int reg = 0; reg < 4; ++reg) {
        int rloc = R0 + cg * 4 + reg;
#pragma unroll
        for (int nt = 0; nt < 4; ++nt) x2[reg][nt] = x[reg][nt] + ao[nt][reg];
        float s = x2[reg][0] + x2[reg][1] + x2[reg][2] + x2[reg][3];
#pragma unroll
        for (int m = 1; m < 16; m <<= 1) s += __shfl_xor(s, m, 64);
        float mean = s * (1.0f / 64.0f);
        float d0 = x2[reg][0] - mean, d1 = x2[reg][1] - mean, d2 = x2[reg][2] - mean, d3 = x2[reg][3] - mean;
        float sq = d0 * d0 + d1 * d1 + d2 * d2 + d3 * d3;
#pragma unroll
        for (int m = 1; m < 16; m <<= 1) sq += __shfl_xor(sq, m, 64);
        float rr = rsqrtf(sq * (1.0f / 64.0f) + 1e-5f);
        storeA4(Ahi, rloc, cb,
                d0 * rr * g2[0] + b2v[0], d1 * rr * g2[1] + b2v[1],
                d2 * rr * g2[2] + b2v[2], d3 * rr * g2[3] + b2v[3]);
    }
    __syncthreads();     // O reads done; Wb free for FFN staging

    // ---- Phase E: FFN 64->256 (gelu) ->64, 2 chunks of 128 hidden, staged weights
    const unsigned short* pW1 = pk + 2 * OFF_W1;
    const unsigned short* pW2 = pk + 2 * OFF_W2;
    f32x4 ya[4];
#pragma unroll
    for (int nt = 0; nt < 4; ++nt) { float by = fb2[nt * 16 + cb]; ya[nt] = {by, by, by, by}; }

#pragma unroll
    for (int cc = 0; cc < 2; ++cc) {
        // stage W1 chunk cc (32 KB): global tile gt=ks*16+cc*8+n8 -> lds tile lt=ks*8+n8
#pragma unroll
        for (int it = 0; it < 8; ++it) {
            int i = it * 256 + tid;
            int half = i >> 10, j = i & 1023;
            int lt = j >> 6, lr = j & 63;
            int ksl = lt >> 3, n8 = lt & 7;
            int gt = ksl * 16 + cc * 8 + n8;
            *(u16x8*)(Wb + half * 8192 + (lt * 64 + lr) * 8) =
                *(const u16x8*)(pW1 + half * 16384 + (gt * 64 + lr) * 8);
        }
        __syncthreads();

        f32x4 ha[8];
#pragma unroll
        for (int n8 = 0; n8 < 8; ++n8) {
            float hb = fb1[(cc * 8 + n8) * 16 + cb];
            ha[n8] = {hb, hb, hb, hb};
        }
#pragma unroll
        for (int ks = 0; ks < 2; ++ks) {
            bf16x8 ah = readFrag(Ahi, R0, lane, ks, 128, 7);
#pragma unroll
            for (int n8 = 0; n8 < 8; ++n8) {
                bf16x8 bh, bl;
                readB(Wb, 8192, 8, ks, n8, lane, bh, bl);
                ha[n8] = MFMA_B16(ah, bh, ha[n8]);
                ha[n8] = MFMA_B16(ah, bl, ha[n8]);
            }
        }
        // gelu -> H frags (wave-private rows)
#pragma unroll
        for (int reg = 0; reg < 4; ++reg) {
            int rloc = R0 + cg * 4 + reg;
            u16x8 u;
#pragma unroll
            for (int n8 = 0; n8 < 8; ++n8) {
                float h = ha[n8][reg];
                h = 0.5f * h * (1.0f + erff(h * 0.70710678118654752f));
                u[n8] = (unsigned short)rne16(h);
            }
            int bo = (rloc * 256 + cb * 16) ^ ((rloc & 15) << 4);
            *(u16x8*)((char*)Hhi + bo) = u;
        }
        __syncthreads();     // W1 reads done

        // stage W2 chunk cc (32 KB): contiguous tiles [cc*16, cc*16+16)
#pragma unroll
        for (int it = 0; it < 8; ++it) {
            int i = it * 256 + tid;
            int half = i >> 10, j = i & 1023;
            *(u16x8*)(Wb + half * 8192 + j * 8) =
                *(const u16x8*)(pW2 + half * 16384 + cc * 8192 + j * 8);
        }
        __syncthreads();

#pragma unroll
        for (int ks2 = 0; ks2 < 4; ++ks2) {
            bf16x8 ah = readFrag(Hhi, R0, lane, ks2, 256, 15);
#pragma unroll
            for (int nt = 0; nt < 4; ++nt) {
                bf16x8 bh, bl;
                readB(Wb, 8192, 4, ks2, nt, lane, bh, bl);
                ya[nt] = MFMA_B16(ah, bh, ya[nt]);
                ya[nt] = MFMA_B16(ah, bl, ya[nt]);
            }
        }
        __syncthreads();     // W2 reads done before next chunk restage
    }

    // ---- final: x2 + ffn -> Hf (wave-private rows), then coalesced float4 store
#pragma unroll
    for (int reg = 0; reg < 4; ++reg) {
        int rloc = R0 + cg * 4 + reg;
#pragma unroll
        for (int nt = 0; nt < 4; ++nt)
            Hf[rloc * 64 + nt * 16 + cb] = x2[reg][nt] + ya[nt][reg];
    }
    __syncthreads();
    {
        float4* dst4 = (float4*)(fout + ((size_t)(pi * B_ + b) * N_ + nn0) * 64);
        const float4* src4 = (const float4*)Hf;
#pragma unroll
        for (int it = 0; it < 4; ++it) {
            int i = it * 256 + tid;
            dst4[i] = src4[i];
        }
    }
}

// ---------- output transpose ----------
__global__ __launch_bounds__(256) void output_kernel(const float* __restrict__ f,
                                                     float* __restrict__ out) {
    __shared__ float tile[64][65];
    int blk = blockIdx.x;
    int ntile = blk & 255;
    int bp = blk >> 8;
    int b = bp / 3, p = bp - b * 3;
    int n0 = ntile * 64;
    int tr = threadIdx.x >> 6, tc = threadIdx.x & 63;

    const float* src = f + ((size_t)(p * B_ + b) * N_ + n0) * C_;
#pragma unroll
    for (int it = 0; it < 16; ++it) {
        int r = it * 4 + tr;
        tile[r][tc] = src[(size_t)r * C_ + tc];
    }
    __syncthreads();
    float* dst = out + (size_t)(b * 3 + p) * C_ * N_ + n0;
#pragma unroll
    for (int it = 0; it < 16; ++it) {
        int cidx = it * 4 + tr;
        dst[(size_t)cidx * N_ + tc] = tile[tc][cidx];
    }
}

extern "C" void kernel_launch(void* const* d_in, const int* in_sizes, int n_in,
                              void* d_out, int out_size, void* d_ws, size_t ws_size,
                              hipStream_t stream) {
    const float* img_feats = (const float*)d_in[0];
    const float* pts       = (const float*)d_in[1];
    const float* query     = (const float*)d_in[2];
    const float* ln1_g     = (const float*)d_in[3];
    const float* ln1_b     = (const float*)d_in[4];
    const float* ln2_g     = (const float*)d_in[5];
    const float* ln2_b     = (const float*)d_in[6];
    const float* in_w      = (const float*)d_in[7];
    const float* in_b      = (const float*)d_in[8];
    const float* out_w     = (const float*)d_in[9];
    const float* out_b     = (const float*)d_in[10];
    const float* ffn_w1    = (const float*)d_in[11];
    const float* ffn_b1    = (const float*)d_in[12];
    const float* ffn_w2    = (const float*)d_in[13];
    const float* ffn_b2    = (const float*)d_in[14];

    const size_t FEAT_SZ = (size_t)3 * B_ * N_ * C_;  // 6,291,456

    float* ws = (float*)d_ws;
    float* ftr      = ws;                                  // FTR_SZ floats
    int* counts     = (int*)(ftr + FTR_SZ);                // SEG_SZ
    int* offsets    = counts + SEG_SZ;                     // NSEG*OSTRIDE
    int* cursors    = offsets + (size_t)NSEG * OSTRIDE;    // SEG_SZ
    float4* ent     = (float4*)(cursors + SEG_SZ);         // SEG_SZ float4
    float* fA       = (float*)(ent + SEG_SZ);
    float* fB       = fA + FEAT_SZ;
    unsigned short* pk_base = (unsigned short*)(fB + FEAT_SZ);
    // kv tables alias the (dead after gather_splat) counts/offsets region
    float* kvk = (float*)counts;
    float* kvv = kvk + KV_SZ;

    // init plane feats with query tensors
    init_feats<<<(3 * N_ * C_ + 255) / 256, 256, 0, stream>>>(query, fA);

    // ---- splat via binning + strip gather (no float atomics)
    zero_counts<<<(int)(SEG_SZ / 4 + 255) / 256, 256, 0, stream>>>((int4*)counts, (int)(SEG_SZ / 4));
    transpose_feats<<<NBV * 256, 256, 0, stream>>>(img_feats, ftr);
    bin_count<<<(NBV * N_) / 256, 256, 0, stream>>>(pts, counts);
    scan_bins<<<NSEG, 256, 0, stream>>>(counts, offsets, cursors);
    scatter_pts<<<(NBV * N_) / 256, 256, 0, stream>>>(pts, cursors, ent);
    gather_splat<<<dim3(2048, 3, B_), 256, 0, stream>>>(ftr, offsets, ent, fA);

    // pack weights
    for (int l = 0; l < NL_; ++l) {
        pack_layer<<<(PK_ELEMS + 255) / 256, 256, 0, stream>>>(
            in_w + (size_t)l * 3 * C_ * C_, out_w + (size_t)l * C_ * C_,
            ffn_w1 + (size_t)l * 4 * C_ * C_, ffn_w2 + (size_t)l * C_ * 4 * C_,
            pk_base + (size_t)l * LAYER_PK);
    }

    dim3 pgrid((B_ * N_) / 64, 3);
    for (int l = 0; l < NL_; ++l) {
        const float* fin = (l == 0) ? fA : fB;
        float* fout      = (l == 0) ? fB : fA;
        ctx_kv<<<144, 256, 0, stream>>>(fin, ln1_g + l * C_, ln1_b + l * C_,
                                        in_w + (size_t)l * 3 * C_ * C_, in_b + l * 3 * C_,
                                        kvk, kvv);
        plane_mfma<<<pgrid, 256, 0, stream>>>(
            fin, fout, pk_base + (size_t)l * LAYER_PK, kvk, kvv,
            ln1_g + l * C_, ln1_b + l * C_,
            ln2_g + l * C_, ln2_b + l * C_,
            in_b + l * 3 * C_, out_b + l * C_,
            ffn_b1 + l * 4 * C_, ffn_b2 + l * C_);
    }

    output_kernel<<<B_ * 3 * (N_ / 64), 256, 0, stream>>>(fA, (float*)d_out);
}

// Round 11
// 357.016 us; speedup vs baseline: 13.8409x; 1.1146x over previous
//
#include <hip/hip_runtime.h>
#include <math.h>

constexpr int R_ = 128, C_ = 64, NL_ = 2, B_ = 2, V_ = 4;
constexpr int N_ = R_ * R_;          // 16384
constexpr int T_ = 6;

typedef __attribute__((ext_vector_type(8))) short bf16x8;
typedef __attribute__((ext_vector_type(4))) float f32x4;
typedef __attribute__((ext_vector_type(4))) unsigned short u16x4;
typedef __attribute__((ext_vector_type(8))) unsigned short u16x8;

#define MFMA_B16(a, b, c) __builtin_amdgcn_mfma_f32_16x16x32_bf16((a), (b), (c), 0, 0, 0)

// packed-weight element offsets (per layer, in elements)
constexpr int OFF_O = 12288, OFF_W1 = 16384, OFF_W2 = 32768;
constexpr int PK_ELEMS = 49152;
constexpr int LAYER_PK = 2 * PK_ELEMS;   // ushorts per layer (hi+lo)

// splat-path sizes
constexpr int NBV = B_ * V_;                       // 8
constexpr size_t FTR_SZ = (size_t)NBV * N_ * C_;   // 8,388,608 floats
constexpr int NSEG = 3 * NBV;                      // 24 segments
constexpr size_t SEG_SZ = (size_t)NSEG * N_;       // 393,216 ints
constexpr int OSTRIDE = N_ + 128;                  // offsets stride (sentinel pad)
constexpr size_t KV_SZ = (size_t)3 * B_ * T_ * 128 * 64;   // 294,912 floats

// ---------- helpers ----------
__device__ inline unsigned rne16(float x) {
    unsigned b = __float_as_uint(x);
    return (b + 0x7fffu + ((b >> 16) & 1u)) >> 16;
}

__device__ inline float wsum(float v) {
#pragma unroll
    for (int m = 1; m < 64; m <<= 1) v += __shfl_xor(v, m, 64);
    return v;
}

__device__ inline float lnorm(float v, float g, float b) {
    float m = wsum(v) * (1.f / 64.f);
    float d = v - m;
    float var = wsum(d * d) * (1.f / 64.f);
    return d * rsqrtf(var + 1e-5f) * g + b;
}

// stage a 64x64 row-major fp32 matrix into LDS buf[c*68 + u]
__device__ inline void stageW(const float* __restrict__ W, float* buf, int tid) {
#pragma unroll
    for (int it = 0; it < 4; ++it) {
        int idx4 = it * 256 + tid;
        int r = idx4 >> 4, u4 = idx4 & 15;
        float4 v = ((const float4*)W)[idx4];
        *(float4*)&buf[r * 68 + u4 * 4] = v;
    }
}

// read A-fragment (16x32 bf16) for wave's M-tile from swizzled LDS
__device__ inline bf16x8 readFrag(const unsigned short* base, int rowBase, int lane,
                                  int ks, int rowStrideB, int swzMask) {
    int rowloc = rowBase + (lane & 15);
    int off = rowloc * rowStrideB + ks * 64 + ((lane >> 4) & 3) * 16;
    off ^= ((rowloc & swzMask) << 4);
    return *(const bf16x8*)((const char*)base + off);
}

// store 4 bf16-hi values (K-permuted: p = cb*4+nt) as one 8B write
__device__ inline void storeA4(unsigned short* base, int rloc, int cb,
                               float v0, float v1, float v2, float v3) {
    u16x4 u;
    u[0] = (unsigned short)rne16(v0);
    u[1] = (unsigned short)rne16(v1);
    u[2] = (unsigned short)rne16(v2);
    u[3] = (unsigned short)rne16(v3);
    int bo = (rloc * 128 + cb * 8) ^ ((rloc & 7) << 4);
    *(u16x4*)((char*)base + bo) = u;
}

// load B-fragment pair (hi,lo) from a weight table (global or LDS)
__device__ inline void readB(const unsigned short* matHi, int E, int NTm, int ks, int nt,
                             int lane, bf16x8& bh, bf16x8& bl) {
    int off = (((ks * NTm + nt) << 6) + lane) << 3;
    bh = *(const bf16x8*)(matHi + off);
    bl = *(const bf16x8*)(matHi + E + off);
}

// ---------- pack all weights of one layer (K-permuted, split hi/lo) ----------
__global__ __launch_bounds__(256) void pack_layer(const float* __restrict__ iw,
                                                  const float* __restrict__ ow,
                                                  const float* __restrict__ w1,
                                                  const float* __restrict__ w2,
                                                  unsigned short* __restrict__ pk) {
    int idx = blockIdx.x * 256 + threadIdx.x;
    if (idx >= PK_ELEMS) return;
    const float* W;
    int O, K, base, mode, lidx;
    if (idx < 12288)      { int m = idx >> 12; lidx = idx & 4095; W = iw + m * 4096; O = 64;  K = 64;  base = m * 4096; mode = 0; }
    else if (idx < 16384) { lidx = idx - 12288; W = ow; O = 64;  K = 64;  base = OFF_O;  mode = 0; }
    else if (idx < 32768) { lidx = idx - 16384; W = w1; O = 256; K = 64;  base = OFF_W1; mode = 0; }
    else                  { lidx = idx - 32768; W = w2; O = 64;  K = 256; base = OFF_W2; mode = 1; }
    int j = lidx & 7, l = (lidx >> 3) & 63, rem = lidx >> 9;
    int NTm = O >> 4;
    int nt = rem & (NTm - 1), ks = rem / NTm;
    int kfrag = ks * 32 + ((l >> 4) & 3) * 8 + j;
    int k;
    if (mode == 0) { int p = kfrag & 63; k = (p & 3) * 16 + (p >> 2); }
    else { int cc = kfrag >> 7; int pl = kfrag & 127; k = (cc * 8 + (pl & 7)) * 16 + (pl >> 3); }
    int o = nt * 16 + (l & 15);
    float w = W[(size_t)o * K + k];
    unsigned hb = rne16(w);
    float hf = __uint_as_float(hb << 16);
    unsigned lb = rne16(w - hf);
    int E = O * K;
    pk[2 * base + lidx] = (unsigned short)hb;
    pk[2 * base + E + lidx] = (unsigned short)lb;
}

// ---------- init plane feats with query tensors ----------
__global__ __launch_bounds__(256) void init_feats(const float* __restrict__ q,
                                                  float* __restrict__ f0) {
    int idx = blockIdx.x * 256 + threadIdx.x;
    if (idx >= 3 * N_ * C_) return;
    int p = idx / (N_ * C_);
    int rem = idx - p * (N_ * C_);
    float val = q[idx];
    f0[(size_t)(p * B_ + 0) * N_ * C_ + rem] = val;
    f0[(size_t)(p * B_ + 1) * N_ * C_ + rem] = val;
}

// ---------- zero bin counts ----------
__global__ __launch_bounds__(256) void zero_counts(int4* __restrict__ p, int n4) {
    int i = blockIdx.x * 256 + threadIdx.x;
    if (i < n4) p[i] = make_int4(0, 0, 0, 0);
}

// ---------- transpose features: [bv][c][n] -> [bv][n][c] ----------
__global__ __launch_bounds__(256) void transpose_feats(const float* __restrict__ src,
                                                       float* __restrict__ dst) {
    __shared__ float tile[64][65];
    int blk = blockIdx.x;             // NBV * 256
    int ntile = blk & 255;
    int bv = blk >> 8;
    int n0 = ntile * 64;
    int tr = threadIdx.x >> 6, tc = threadIdx.x & 63;
    const float* s = src + (size_t)bv * C_ * N_;
#pragma unroll
    for (int it = 0; it < 16; ++it) {
        int c = it * 4 + tr;
        tile[c][tc] = s[(size_t)c * N_ + n0 + tc];
    }
    __syncthreads();
    float* d = dst + ((size_t)bv * N_ + n0) * C_;
#pragma unroll
    for (int it = 0; it < 16; ++it) {
        int r = it * 4 + tr;
        d[(size_t)r * C_ + tc] = tile[tc][r];
    }
}

// ---------- bin count ----------
__global__ __launch_bounds__(256) void bin_count(const float* __restrict__ pts,
                                                 int* __restrict__ counts) {
    int idx = blockIdx.x * 256 + threadIdx.x;     // [0, NBV*N)
    if (idx >= NBV * N_) return;
    int bv = idx >> 14;
    const float* p = pts + (size_t)idx * 3;
    float px = p[0], py = p[1], pz = p[2];
    const float HI = (float)(127.0 - 1e-5);
    float gx = fminf(fmaxf((px + 1.0f) * 127.0f / 2.0f, 0.0f), HI);
    float gy = fminf(fmaxf((py + 1.0f) * 127.0f / 2.0f, 0.0f), HI);
    float gz = fminf(fmaxf((pz + 1.0f) * 127.0f / 2.0f, 0.0f), HI);
    int x0 = (int)gx, y0 = (int)gy, z0 = (int)gz;
    atomicAdd(&counts[(0 * NBV + bv) * N_ + x0 * R_ + y0], 1);
    atomicAdd(&counts[(1 * NBV + bv) * N_ + x0 * R_ + z0], 1);
    atomicAdd(&counts[(2 * NBV + bv) * N_ + y0 * R_ + z0], 1);
}

// ---------- per-segment exclusive scan (16384 bins each) + sentinel pad ----------
__global__ __launch_bounds__(256) void scan_bins(const int* __restrict__ counts,
                                                 int* __restrict__ offsets,
                                                 int* __restrict__ cursors) {
    __shared__ int part[256];
    int seg = blockIdx.x;             // 24
    int t = threadIdx.x;
    const int* c = counts + (size_t)seg * N_;
    int sum = 0;
    for (int i = 0; i < 64; ++i) sum += c[t * 64 + i];
    part[t] = sum;
    __syncthreads();
    if (t == 0) {
        int run = 0;
        for (int i = 0; i < 256; ++i) { int v = part[i]; part[i] = run; run += v; }
    }
    __syncthreads();
    int run = part[t];
    int* o = offsets + (size_t)seg * OSTRIDE;
    int* cu = cursors + (size_t)seg * N_;
    for (int i = 0; i < 64; ++i) {
        o[t * 64 + i] = run;
        cu[t * 64 + i] = run;
        run += c[t * 64 + i];
    }
    if (t < 128) o[N_ + t] = N_;      // sentinel: total per segment == N_
}

// ---------- scatter full point records into bin-sorted entry lists ----------
__global__ __launch_bounds__(256) void scatter_pts(const float* __restrict__ pts,
                                                   int* __restrict__ cursors,
                                                   float4* __restrict__ ent) {
    int idx = blockIdx.x * 256 + threadIdx.x;
    if (idx >= NBV * N_) return;
    int bv = idx >> 14, n = idx & (N_ - 1);
    const float* p = pts + (size_t)idx * 3;
    float px = p[0], py = p[1], pz = p[2];
    const float HI = (float)(127.0 - 1e-5);
    float gx = fminf(fmaxf((px + 1.0f) * 127.0f / 2.0f, 0.0f), HI);
    float gy = fminf(fmaxf((py + 1.0f) * 127.0f / 2.0f, 0.0f), HI);
    float gz = fminf(fmaxf((pz + 1.0f) * 127.0f / 2.0f, 0.0f), HI);
    int x0 = (int)gx, y0 = (int)gy, z0 = (int)gz;
    float4 e;
    e.x = __uint_as_float((unsigned)n);
    e.y = gx - (float)x0; e.z = gy - (float)y0; e.w = gz - (float)z0;
    int s0 = 0 * NBV + bv, s1 = 1 * NBV + bv, s2 = 2 * NBV + bv;
    int p0 = atomicAdd(&cursors[(size_t)s0 * N_ + x0 * R_ + y0], 1);
    ent[(size_t)s0 * N_ + p0] = e;
    int p1 = atomicAdd(&cursors[(size_t)s1 * N_ + x0 * R_ + z0], 1);
    ent[(size_t)s1 * N_ + p1] = e;
    int p2 = atomicAdd(&cursors[(size_t)s2 * N_ + y0 * R_ + z0], 1);
    ent[(size_t)s2 * N_ + p2] = e;
}

// ---------- gather splat: block = one 8-cell strip; wave = (view, bin-row) ----------
__global__ __launch_bounds__(512) void gather_splat(
    const float* __restrict__ ftr, const int* __restrict__ offsets,
    const float4* __restrict__ ent, float* __restrict__ f0) {
    __shared__ float sfacc[8][8][64];
    __shared__ float swsum[8][8];
    int wid = threadIdx.x >> 6, lane = threadIdx.x & 63;
    int v = wid >> 1, dr = wid & 1;
    int strip = blockIdx.x;                   // [0, 2048)
    int pi = blockIdx.y, b = blockIdx.z;
    int a = strip >> 4;                       // cell row
    int c0 = (strip & 15) << 3;               // first cell col of strip

    int bv = b * V_ + v;
    int seg = pi * NBV + bv;
    const int* ob = offsets + (size_t)seg * OSTRIDE;
    const float4* eb = ent + (size_t)seg * N_;
    const float* fbase = ftr + (size_t)bv * N_ * C_ + lane;
    float facc[8], wsum_[8];
#pragma unroll
    for (int k = 0; k < 8; ++k) { facc[k] = 0.f; wsum_[k] = 0.f; }

    int ba = a - dr;
    if (ba >= 0) {
        int rowbase = ba * R_ + c0 - 1;
        int o[10];
#pragma unroll
        for (int jj = 0; jj < 10; ++jj)
            o[jj] = ob[max(rowbase + jj, 0)];
#pragma unroll
        for (int j = 0; j < 9; ++j) {
            if (j == 0 && c0 == 0) continue;    // bin col -1 doesn't exist
            int e = o[j + 1];
            for (int i = o[j]; i < e; ++i) {
                float4 r = eb[i];
                int n = (int)__float_as_uint(r.x);
                float wx = r.y, wy = r.z, wz = r.w;
                float ax = 1.f - wx, ay = 1.f - wy, az = 1.f - wz;
                float XA = dr ? wx : ax;
                float YA = dr ? wy : ay;
                float w0 = (pi == 2 ? ax * YA : XA * ay) * az;
                float w1 = (pi == 0) ? XA * wy * az : XA * YA * wz;
                float f = fbase[(size_t)n * C_];
                if (j > 0) { facc[j - 1] += w0 * f; wsum_[j - 1] += w0; }
                if (j < 8) { facc[j] += w1 * f; wsum_[j] += w1; }
            }
        }
    }
#pragma unroll
    for (int k = 0; k < 8; ++k) sfacc[wid][k][lane] = facc[k];
    if (lane == 0) {
#pragma unroll
        for (int k = 0; k < 8; ++k) swsum[wid][k] = wsum_[k];
    }
    __syncthreads();

    // combine: wave wid handles cell k = wid (sum dr pair per view, then normalize)
    int k = wid;
    float tot = 0.f;
#pragma unroll
    for (int v2 = 0; v2 < 4; ++v2) {
        float fa = sfacc[v2 * 2][k][lane] + sfacc[v2 * 2 + 1][k][lane];
        float wsv = swsum[v2 * 2][k] + swsum[v2 * 2 + 1][k];
        tot += fa / fmaxf(wsv, 1e-8f);
    }
    float* dst = f0 + (((size_t)(pi * B_ + b)) * N_ + a * R_ + c0 + k) * C_ + lane;
    *dst += 0.25f * tot;
}

// ---------- ctx k/v table: 4608 rows = (pi, b, t, pos) ----------
__global__ __launch_bounds__(256) void ctx_kv(
    const float* __restrict__ fin,
    const float* __restrict__ ln1g, const float* __restrict__ ln1b,
    const float* __restrict__ inw, const float* __restrict__ inb,
    float* __restrict__ kvk, float* __restrict__ kvv) {
    __shared__ float s_wk[64 * 68];
    __shared__ float s_wv[64 * 68];
    __shared__ float s_act[32 * 68];
    int tid = threadIdx.x, wid = tid >> 6, lane = tid & 63;
    stageW(inw + 4096, s_wk, tid);     // Wk
    stageW(inw + 8192, s_wv, tid);     // Wv

    int rid0 = blockIdx.x * 32 + wid * 8;
    int seg = rid0 >> 7;               // (pi*2+b)*6 + t
    int pos0 = rid0 & 127;
    int t = seg % 6;
    int pib = seg / 6;
    int pi = pib >> 1, b = pib & 1;
    int khalf = (t < 3) ? t : t - 3;
    float sk = (float)(khalf - 1);
    bool tl = t < 3;
    int io;
    if (pi == 0) io = tl ? 1 : 2;
    else if (pi == 1) io = tl ? 0 : 2;
    else io = tl ? 0 : 1;
    const float* Fio = fin + (size_t)(io * B_ + b) * N_ * 64;
    float g1 = ln1g[lane], b1 = ln1b[lane];

#pragma unroll
    for (int rr = 0; rr < 8; ++rr) {
        int pos = pos0 + rr;
        float lp = -1.0f + (2.0f * (float)pos) / 127.0f;
        float caf, cbf;
        if (pi == 0) { caf = lp; cbf = sk; }
        else if (pi == 1) { if (tl) { caf = lp; cbf = sk; } else { caf = sk; cbf = lp; } }
        else { caf = sk; cbf = lp; }
        float ua = fminf(fmaxf((caf * 0.5f + 0.5f) * 127.0f, 0.0f), 127.0f);
        float ub = fminf(fmaxf((cbf * 0.5f + 0.5f) * 127.0f, 0.0f), 127.0f);
        float gxp = fminf(fmaxf(((ua + 1.0f) * 0.5f) * 127.0f, 0.0f), 127.0f);
        float gyp = fminf(fmaxf(((ub + 1.0f) * 0.5f) * 127.0f, 0.0f), 127.0f);
        int xx0 = (int)gxp, yy0 = (int)gyp;
        int xx1 = xx0 + 1 < 128 ? xx0 + 1 : 127;
        int yy1 = yy0 + 1 < 128 ? yy0 + 1 : 127;
        float wx = gxp - (float)xx0, wy = gyp - (float)yy0;
        float v00 = Fio[(size_t)(yy0 * R_ + xx0) * 64 + lane];
        float v01 = Fio[(size_t)(yy0 * R_ + xx1) * 64 + lane];
        float v10 = Fio[(size_t)(yy1 * R_ + xx0) * 64 + lane];
        float v11 = Fio[(size_t)(yy1 * R_ + xx1) * 64 + lane];
        float cv = (1.0f - wy) * ((1.0f - wx) * v00 + wx * v01) +
                   wy * ((1.0f - wx) * v10 + wx * v11);
        s_act[(wid * 8 + rr) * 68 + lane] = lnorm(cv, g1, b1);
    }
    __syncthreads();

    float kk[8], vv[8];
    float bk = inb[64 + lane], bv = inb[128 + lane];
#pragma unroll
    for (int rr = 0; rr < 8; ++rr) { kk[rr] = bk; vv[rr] = bv; }
    const float* wrk = s_wk + lane * 68;
    const float* wrv = s_wv + lane * 68;
#pragma unroll 4
    for (int g = 0; g < 16; ++g) {
        float4 wk4 = *(const float4*)(wrk + g * 4);
        float4 wv4 = *(const float4*)(wrv + g * 4);
#pragma unroll
        for (int rr = 0; rr < 8; ++rr) {
            float4 xv = *(const float4*)(s_act + (wid * 8 + rr) * 68 + g * 4);
            kk[rr] = fmaf(xv.x, wk4.x, fmaf(xv.y, wk4.y, fmaf(xv.z, wk4.z, fmaf(xv.w, wk4.w, kk[rr]))));
            vv[rr] = fmaf(xv.x, wv4.x, fmaf(xv.y, wv4.y, fmaf(xv.z, wv4.z, fmaf(xv.w, wv4.w, vv[rr]))));
        }
    }
#pragma unroll
    for (int rr = 0; rr < 8; ++rr) {
        size_t o = ((size_t)seg * 128 + pos0 + rr) * 64 + lane;
        kvk[o] = kk[rr];
        kvv[o] = vv[rr];
    }
}

// ---------- fused per-plane transformer layer (MFMA, precomputed k/v) ----------
__global__ __launch_bounds__(256, 2) void plane_mfma(
    const float* __restrict__ fin, float* __restrict__ fout,
    const unsigned short* __restrict__ pk,
    const float* __restrict__ kvk, const float* __restrict__ kvv,
    const float* __restrict__ ln1g, const float* __restrict__ ln1b,
    const float* __restrict__ ln2g, const float* __restrict__ ln2b,
    const float* __restrict__ inb, const float* __restrict__ outb,
    const float* __restrict__ fb1, const float* __restrict__ fb2) {
    __shared__ __attribute__((aligned(16))) unsigned short Wb[16384];  // 32 KB weight stage
    __shared__ __attribute__((aligned(16))) unsigned short Ahi[4096];  // 8 KB A-frags
    __shared__ __attribute__((aligned(16))) float Hf[4096];            // 16 KB H-frags / out stage
    unsigned short* Hhi = (unsigned short*)Hf;

    const int tid = threadIdx.x;
    const int wid = tid >> 6, lane = tid & 63;
    const int cg = lane >> 4, cb = lane & 15;
    const int pi = blockIdx.y;
    const int R0 = wid * 16;
    const int rowbase = blockIdx.x * 64;
    const int b = rowbase >> 14;
    const int nn0 = rowbase & (N_ - 1);
    const int i0 = nn0 >> 7, j0 = nn0 & 127;

    // ---- stage Q (hi+lo, 16 KB) into Wb[0:8192]
#pragma unroll
    for (int i = 0; i < 4; ++i)
        *(u16x8*)(Wb + (i * 256 + tid) * 8) = *(const u16x8*)(pk + (i * 256 + tid) * 8);

    float g1[4], b1v[4];
#pragma unroll
    for (int nt = 0; nt < 4; ++nt) { g1[nt] = ln1g[nt * 16 + cb]; b1v[nt] = ln1b[nt * 16 + cb]; }

    // ---- Phase A: load x (kept in regs), LN1 -> A-frags (wave-private LDS rows)
    float x[4][4];
    const float* finp = fin + ((size_t)(pi * B_ + b) * N_ + nn0) * 64;
#pragma unroll
    for (int reg = 0; reg < 4; ++reg) {
        int rloc = R0 + cg * 4 + reg;
#pragma unroll
        for (int nt = 0; nt < 4; ++nt) x[reg][nt] = finp[(size_t)rloc * 64 + nt * 16 + cb];
        float s = x[reg][0] + x[reg][1] + x[reg][2] + x[reg][3];
#pragma unroll
        for (int m = 1; m < 16; m <<= 1) s += __shfl_xor(s, m, 64);
        float mean = s * (1.0f / 64.0f);
        float d0 = x[reg][0] - mean, d1 = x[reg][1] - mean, d2 = x[reg][2] - mean, d3 = x[reg][3] - mean;
        float sq = d0 * d0 + d1 * d1 + d2 * d2 + d3 * d3;
#pragma unroll
        for (int m = 1; m < 16; m <<= 1) sq += __shfl_xor(sq, m, 64);
        float rr = rsqrtf(sq * (1.0f / 64.0f) + 1e-5f);
        storeA4(Ahi, rloc, cb,
                d0 * rr * g1[0] + b1v[0], d1 * rr * g1[1] + b1v[1],
                d2 * rr * g1[2] + b1v[2], d3 * rr * g1[3] + b1v[3]);
    }
    __syncthreads();

    // ---- Phase B: q = xn @ Wq^T + bq  (Wb = Q)
    f32x4 qa[4];
#pragma unroll
    for (int nt = 0; nt < 4; ++nt) { float bq = inb[nt * 16 + cb]; qa[nt] = {bq, bq, bq, bq}; }
#pragma unroll
    for (int ks = 0; ks < 2; ++ks) {
        bf16x8 ah = readFrag(Ahi, R0, lane, ks, 128, 7);
#pragma unroll
        for (int nt = 0; nt < 4; ++nt) {
            bf16x8 bh, bl;
            readB(Wb, 4096, 4, ks, nt, lane, bh, bl);
            qa[nt] = MFMA_B16(ah, bh, qa[nt]);
            qa[nt] = MFMA_B16(ah, bl, qa[nt]);
        }
    }

    // ---- Phase C: attention with precomputed k/v (no barriers, no LDS)
    const float* kvkb = kvk + (size_t)((pi * 2 + b) * 6) * 128 * 64;
    const float* kvvb = kvv + (size_t)((pi * 2 + b) * 6) * 128 * 64;
    float den_[4][4];
    f32x4 oa[4];
#pragma unroll
    for (int nt = 0; nt < 4; ++nt) {
        oa[nt] = {0.f, 0.f, 0.f, 0.f};
#pragma unroll
        for (int reg = 0; reg < 4; ++reg) den_[nt][reg] = 0.f;
    }

    // t = 0..2: k/v depend on j (per-row)
#pragma unroll
    for (int t = 0; t < 3; ++t) {
        float kvr[4][4], vvr[4][4];
#pragma unroll
        for (int reg = 0; reg < 4; ++reg) {
            int pos = j0 + R0 + cg * 4 + reg;
            const float* kr = kvkb + ((size_t)t * 128 + pos) * 64 + cb;
            const float* vr = kvvb + ((size_t)t * 128 + pos) * 64 + cb;
#pragma unroll
            for (int nt = 0; nt < 4; ++nt) {
                kvr[reg][nt] = kr[nt * 16];
                vvr[reg][nt] = vr[nt * 16];
            }
        }
#pragma unroll
        for (int nt = 0; nt < 4; ++nt) {
            float d0 = qa[nt][0] * kvr[0][nt];
            float d1 = qa[nt][1] * kvr[1][nt];
            float d2 = qa[nt][2] * kvr[2][nt];
            float d3 = qa[nt][3] * kvr[3][nt];
#pragma unroll
            for (int m = 1; m < 16; m <<= 1) {
                d0 += __shfl_xor(d0, m, 64);
                d1 += __shfl_xor(d1, m, 64);
                d2 += __shfl_xor(d2, m, 64);
                d3 += __shfl_xor(d3, m, 64);
            }
            float e0 = __expf(d0 * 0.25f), e1 = __expf(d1 * 0.25f);
            float e2 = __expf(d2 * 0.25f), e3 = __expf(d3 * 0.25f);
            den_[nt][0] += e0; den_[nt][1] += e1; den_[nt][2] += e2; den_[nt][3] += e3;
            oa[nt][0] += e0 * vvr[0][nt];
            oa[nt][1] += e1 * vvr[1][nt];
            oa[nt][2] += e2 * vvr[2][nt];
            oa[nt][3] += e3 * vvr[3][nt];
        }
    }
    // t = 3..5: k/v depend on i (block-uniform row i0)
#pragma unroll
    for (int t = 3; t < 6; ++t) {
        float ku[4], vu[4];
        const float* kr = kvkb + ((size_t)t * 128 + i0) * 64 + cb;
        const float* vr = kvvb + ((size_t)t * 128 + i0) * 64 + cb;
#pragma unroll
        for (int nt = 0; nt < 4; ++nt) { ku[nt] = kr[nt * 16]; vu[nt] = vr[nt * 16]; }
#pragma unroll
        for (int nt = 0; nt < 4; ++nt) {
            float d0 = qa[nt][0] * ku[nt];
            float d1 = qa[nt][1] * ku[nt];
            float d2 = qa[nt][2] * ku[nt];
            float d3 = qa[nt][3] * ku[nt];
#pragma unroll
            for (int m = 1; m < 16; m <<= 1) {
                d0 += __shfl_xor(d0, m, 64);
                d1 += __shfl_xor(d1, m, 64);
                d2 += __shfl_xor(d2, m, 64);
                d3 += __shfl_xor(d3, m, 64);
            }
            float e0 = __expf(d0 * 0.25f), e1 = __expf(d1 * 0.25f);
            float e2 = __expf(d2 * 0.25f), e3 = __expf(d3 * 0.25f);
            den_[nt][0] += e0; den_[nt][1] += e1; den_[nt][2] += e2; den_[nt][3] += e3;
            oa[nt][0] += e0 * vu[nt];
            oa[nt][1] += e1 * vu[nt];
            oa[nt][2] += e2 * vu[nt];
            oa[nt][3] += e3 * vu[nt];
        }
    }
    __syncthreads();     // all waves past q-proj; Wb free

    // ---- stage O (16 KB) into Wb[0:8192]; write o/den -> A-frags
#pragma unroll
    for (int i = 0; i < 4; ++i)
        *(u16x8*)(Wb + (i * 256 + tid) * 8) = *(const u16x8*)(pk + 24576 + (i * 256 + tid) * 8);
#pragma unroll
    for (int reg = 0; reg < 4; ++reg) {
        int rloc = R0 + cg * 4 + reg;
        storeA4(Ahi, rloc, cb,
                oa[0][reg] / den_[0][reg], oa[1][reg] / den_[1][reg],
                oa[2][reg] / den_[2][reg], oa[3][reg] / den_[3][reg]);
    }
    __syncthreads();

    // ---- Phase D: out-proj (Wb = O); residual (x in regs); LN2 -> A-frags
    f32x4 ao[4];
#pragma unroll
    for (int nt = 0; nt < 4; ++nt) { float bo_ = outb[nt * 16 + cb]; ao[nt] = {bo_, bo_, bo_, bo_}; }
#pragma unroll
    for (int ks = 0; ks < 2; ++ks) {
        bf16x8 ah = readFrag(Ahi, R0, lane, ks, 128, 7);
#pragma unroll
        for (int nt = 0; nt < 4; ++nt) {
            bf16x8 bh, bl;
            readB(Wb, 4096, 4, ks, nt, lane, bh, bl);
            ao[nt] = MFMA_B16(ah, bh, ao[nt]);
            ao[nt] = MFMA_B16(ah, bl, ao[nt]);
        }
    }
    float g2[4], b2v[4];
#pragma unroll
    for (int nt = 0; nt < 4; ++nt) { g2[nt] = ln2g[nt * 16 + cb]; b2v[nt] = ln2b[nt * 16 + cb]; }
    float x2[4][4];
#pragma unroll
    for (int reg = 0; reg < 4; ++reg) {
        int rloc = R0 + cg * 4 + reg;
#pragma unroll
        for (int nt = 0; nt < 4; ++nt) x2[reg][nt] = x[reg][nt] + ao[nt][reg];
        float s = x2[reg][0] + x2[reg][1] + x2[reg][2] + x2[reg][3];
#pragma unroll
        for (int m = 1; m < 16; m <<= 1) s += __shfl_xor(s, m, 64);
        float mean = s * (1.0f / 64.0f);
        float d0 = x2[reg][0] - mean, d1 = x2[reg][1] - mean, d2 = x2[reg][2] - mean, d3 = x2[reg][3] - mean;
        float sq = d0 * d0 + d1 * d1 + d2 * d2 + d3 * d3;
#pragma unroll
        for (int m = 1; m < 16; m <<= 1) sq += __shfl_xor(sq, m, 64);
        float rr = rsqrtf(sq * (1.0f / 64.0f) + 1e-5f);
        storeA4(Ahi, rloc, cb,
                d0 * rr * g2[0] + b2v[0], d1 * rr * g2[1] + b2v[1],
                d2 * rr * g2[2] + b2v[2], d3 * rr * g2[3] + b2v[3]);
    }
    __syncthreads();     // O reads done; Wb free for FFN staging

    // ---- Phase E: FFN 64->256 (gelu) ->64, 2 chunks of 128 hidden, staged weights
    const unsigned short* pW1 = pk + 2 * OFF_W1;
    const unsigned short* pW2 = pk + 2 * OFF_W2;
    f32x4 ya[4];
#pragma unroll
    for (int nt = 0; nt < 4; ++nt) { float by = fb2[nt * 16 + cb]; ya[nt] = {by, by, by, by}; }

#pragma unroll
    for (int cc = 0; cc < 2; ++cc) {
        // stage W1 chunk cc (32 KB): global tile gt=ks*16+cc*8+n8 -> lds tile lt=ks*8+n8
#pragma unroll
        for (int it = 0; it < 8; ++it) {
            int i = it * 256 + tid;
            int half = i >> 10, j = i & 1023;
            int lt = j >> 6, lr = j & 63;
            int ksl = lt >> 3, n8 = lt & 7;
            int gt = ksl * 16 + cc * 8 + n8;
            *(u16x8*)(Wb + half * 8192 + (lt * 64 + lr) * 8) =
                *(const u16x8*)(pW1 + half * 16384 + (gt * 64 + lr) * 8);
        }
        __syncthreads();

        f32x4 ha[8];
#pragma unroll
        for (int n8 = 0; n8 < 8; ++n8) {
            float hb = fb1[(cc * 8 + n8) * 16 + cb];
            ha[n8] = {hb, hb, hb, hb};
        }
#pragma unroll
        for (int ks = 0; ks < 2; ++ks) {
            bf16x8 ah = readFrag(Ahi, R0, lane, ks, 128, 7);
#pragma unroll
            for (int n8 = 0; n8 < 8; ++n8) {
                bf16x8 bh, bl;
                readB(Wb, 8192, 8, ks, n8, lane, bh, bl);
                ha[n8] = MFMA_B16(ah, bh, ha[n8]);
                ha[n8] = MFMA_B16(ah, bl, ha[n8]);
            }
        }
        // gelu -> H frags (wave-private rows)
#pragma unroll
        for (int reg = 0; reg < 4; ++reg) {
            int rloc = R0 + cg * 4 + reg;
            u16x8 u;
#pragma unroll
            for (int n8 = 0; n8 < 8; ++n8) {
                float h = ha[n8][reg];
                h = 0.5f * h * (1.0f + erff(h * 0.70710678118654752f));
                u[n8] = (unsigned short)rne16(h);
            }
            int bo = (rloc * 256 + cb * 16) ^ ((rloc & 15) << 4);
            *(u16x8*)((char*)Hhi + bo) = u;
        }
        __syncthreads();     // W1 reads done

        // stage W2 chunk cc (32 KB): contiguous tiles [cc*16, cc*16+16)
#pragma unroll
        for (int it = 0; it < 8; ++it) {
            int i = it * 256 + tid;
            int half = i >> 10, j = i & 1023;
            *(u16x8*)(Wb + half * 8192 + j * 8) =
                *(const u16x8*)(pW2 + half * 16384 + cc * 8192 + j * 8);
        }
        __syncthreads();

#pragma unroll
        for (int ks2 = 0; ks2 < 4; ++ks2) {
            bf16x8 ah = readFrag(Hhi, R0, lane, ks2, 256, 15);
#pragma unroll
            for (int nt = 0; nt < 4; ++nt) {
                bf16x8 bh, bl;
                readB(Wb, 8192, 4, ks2, nt, lane, bh, bl);
                ya[nt] = MFMA_B16(ah, bh, ya[nt]);
                ya[nt] = MFMA_B16(ah, bl, ya[nt]);
            }
        }
        __syncthreads();     // W2 reads done before next chunk restage
    }

    // ---- final: x2 + ffn -> Hf (wave-private rows), then coalesced float4 store
#pragma unroll
    for (int reg = 0; reg < 4; ++reg) {
        int rloc = R0 + cg * 4 + reg;
#pragma unroll
        for (int nt = 0; nt < 4; ++nt)
            Hf[rloc * 64 + nt * 16 + cb] = x2[reg][nt] + ya[nt][reg];
    }
    __syncthreads();
    {
        float4* dst4 = (float4*)(fout + ((size_t)(pi * B_ + b) * N_ + nn0) * 64);
        const float4* src4 = (const float4*)Hf;
#pragma unroll
        for (int it = 0; it < 4; ++it) {
            int i = it * 256 + tid;
            dst4[i] = src4[i];
        }
    }
}

// ---------- output transpose ----------
__global__ __launch_bounds__(256) void output_kernel(const float* __restrict__ f,
                                                     float* __restrict__ out) {
    __shared__ float tile[64][65];
    int blk = blockIdx.x;
    int ntile = blk & 255;
    int bp = blk >> 8;
    int b = bp / 3, p = bp - b * 3;
    int n0 = ntile * 64;
    int tr = threadIdx.x >> 6, tc = threadIdx.x & 63;

    const float* src = f + ((size_t)(p * B_ + b) * N_ + n0) * C_;
#pragma unroll
    for (int it = 0; it < 16; ++it) {
        int r = it * 4 + tr;
        tile[r][tc] = src[(size_t)r * C_ + tc];
    }
    __syncthreads();
    float* dst = out + (size_t)(b * 3 + p) * C_ * N_ + n0;
#pragma unroll
    for (int it = 0; it < 16; ++it) {
        int cidx = it * 4 + tr;
        dst[(size_t)cidx * N_ + tc] = tile[tc][cidx];
    }
}

extern "C" void kernel_launch(void* const* d_in, const int* in_sizes, int n_in,
                              void* d_out, int out_size, void* d_ws, size_t ws_size,
                              hipStream_t stream) {
    const float* img_feats = (const float*)d_in[0];
    const float* pts       = (const float*)d_in[1];
    const float* query     = (const float*)d_in[2];
    const float* ln1_g     = (const float*)d_in[3];
    const float* ln1_b     = (const float*)d_in[4];
    const float* ln2_g     = (const float*)d_in[5];
    const float* ln2_b     = (const float*)d_in[6];
    const float* in_w      = (const float*)d_in[7];
    const float* in_b      = (const float*)d_in[8];
    const float* out_w     = (const float*)d_in[9];
    const float* out_b     = (const float*)d_in[10];
    const float* ffn_w1    = (const float*)d_in[11];
    const float* ffn_b1    = (const float*)d_in[12];
    const float* ffn_w2    = (const float*)d_in[13];
    const float* ffn_b2    = (const float*)d_in[14];

    const size_t FEAT_SZ = (size_t)3 * B_ * N_ * C_;  // 6,291,456

    float* ws = (float*)d_ws;
    float* ftr      = ws;                                  // FTR_SZ floats
    int* counts     = (int*)(ftr + FTR_SZ);                // SEG_SZ
    int* offsets    = counts + SEG_SZ;                     // NSEG*OSTRIDE
    int* cursors    = offsets + (size_t)NSEG * OSTRIDE;    // SEG_SZ
    float4* ent     = (float4*)(cursors + SEG_SZ);         // SEG_SZ float4
    float* fA       = (float*)(ent + SEG_SZ);
    float* fB       = fA + FEAT_SZ;
    unsigned short* pk_base = (unsigned short*)(fB + FEAT_SZ);
    // kv tables alias the (dead after gather_splat) counts/offsets region
    float* kvk = (float*)counts;
    float* kvv = kvk + KV_SZ;

    // init plane feats with query tensors
    init_feats<<<(3 * N_ * C_ + 255) / 256, 256, 0, stream>>>(query, fA);

    // ---- splat via binning + strip gather (no float atomics)
    zero_counts<<<(int)(SEG_SZ / 4 + 255) / 256, 256, 0, stream>>>((int4*)counts, (int)(SEG_SZ / 4));
    transpose_feats<<<NBV * 256, 256, 0, stream>>>(img_feats, ftr);
    bin_count<<<(NBV * N_) / 256, 256, 0, stream>>>(pts, counts);
    scan_bins<<<NSEG, 256, 0, stream>>>(counts, offsets, cursors);
    scatter_pts<<<(NBV * N_) / 256, 256, 0, stream>>>(pts, cursors, ent);
    gather_splat<<<dim3(2048, 3, B_), 512, 0, stream>>>(ftr, offsets, ent, fA);

    // pack weights
    for (int l = 0; l < NL_; ++l) {
        pack_layer<<<(PK_ELEMS + 255) / 256, 256, 0, stream>>>(
            in_w + (size_t)l * 3 * C_ * C_, out_w + (size_t)l * C_ * C_,
            ffn_w1 + (size_t)l * 4 * C_ * C_, ffn_w2 + (size_t)l * C_ * 4 * C_,
            pk_base + (size_t)l * LAYER_PK);
    }

    dim3 pgrid((B_ * N_) / 64, 3);
    for (int l = 0; l < NL_; ++l) {
        const float* fin = (l == 0) ? fA : fB;
        float* fout      = (l == 0) ? fB : fA;
        ctx_kv<<<144, 256, 0, stream>>>(fin, ln1_g + l * C_, ln1_b + l * C_,
                                        in_w + (size_t)l * 3 * C_ * C_, in_b + l * 3 * C_,
                                        kvk, kvv);
        plane_mfma<<<pgrid, 256, 0, stream>>>(
            fin, fout, pk_base + (size_t)l * LAYER_PK, kvk, kvv,
            ln1_g + l * C_, ln1_b + l * C_,
            ln2_g + l * C_, ln2_b + l * C_,
            in_b + l * 3 * C_, out_b + l * C_,
            ffn_b1 + l * 4 * C_, ffn_b2 + l * C_);
    }

    output_kernel<<<B_ * 3 * (N_ / 64), 256, 0, stream>>>(fA, (float*)d_out);
}